// Round 12
// baseline (400.451 us; speedup 1.0000x reference)
//
#include <hip/hip_runtime.h>
#include <math.h>

typedef unsigned short ushort_t;
typedef unsigned int uint_t;
typedef __attribute__((ext_vector_type(8))) short bf16x8;
typedef __attribute__((ext_vector_type(4))) float f32x4;

#define FSTRIDE ((size_t)16384 * 320)
#define TSTRIDE ((size_t)16384 * 64)

// ---------- bf16 helpers ----------
__device__ inline ushort_t f2bf(float f) {
    union { float f; uint_t u; } x; x.f = f;
    uint_t r = x.u + 0x7fffu + ((x.u >> 16) & 1u);
    return (ushort_t)(r >> 16);
}
__device__ inline float bf2f(ushort_t h) {
    union { uint_t u; float f; } x; x.u = ((uint_t)h) << 16;
    return x.f;
}
__device__ inline float bflo(uint_t u) {
    union { uint_t u; float f; } x; x.u = u << 16; return x.f;
}
__device__ inline float bfhi(uint_t u) {
    union { uint_t u; float f; } x; x.u = u & 0xffff0000u; return x.f;
}

// ---------- fused weight transform: 6 conv layers, OIHW fp32 -> [tap][co][ci] bf16 ----------
struct WT6 {
    const float* src[6];
    ushort_t* dst[6];
    int co[6], ci[6];
    int off[6];
};
__global__ void wtrans6_k(WT6 a)
{
    int b = blockIdx.x, seg = 0;
#pragma unroll
    for (int s = 1; s < 6; ++s) if (b >= a.off[s]) seg = s;
    int idx = (b - a.off[seg]) * 256 + threadIdx.x;
    int CO = a.co[seg], CI = a.ci[seg];
    if (idx >= CO * CI * 9) return;
    int tap = idx % 9;
    int rem = idx / 9;
    int ci = rem % CI;
    int co = rem / CI;
    a.dst[seg][((size_t)tap * CO + co) * CI + ci] = f2bf(a.src[seg][idx]);
}

// ---------- conv0: 3->64 @128x128, NCHW fp32 in; writes F cols 0..63 AND compact t0 ----------
__global__ __launch_bounds__(256) void conv0_k(const float* __restrict__ x0, const float* __restrict__ x1,
                                               const float* __restrict__ w,
                                               const float* __restrict__ b, ushort_t* __restrict__ F,
                                               ushort_t* __restrict__ t0)
{
    const float* x = blockIdx.y ? x1 : x0;
    F += (size_t)blockIdx.y * FSTRIDE;
    t0 += (size_t)blockIdx.y * TSTRIDE;
    int co = threadIdx.x & 63;
    int p = blockIdx.x * 4 + (threadIdx.x >> 6);
    int y = p >> 7, xx = p & 127;
    float acc = b[co];
#pragma unroll
    for (int ci = 0; ci < 3; ++ci) {
#pragma unroll
        for (int t = 0; t < 9; ++t) {
            int dy = t / 3 - 1, dx = t % 3 - 1;
            int yy = y + dy, xc = xx + dx;
            if ((unsigned)yy < 128u && (unsigned)xc < 128u) {
                acc += x[ci * 16384 + yy * 128 + xc] * w[co * 27 + ci * 9 + t];
            }
        }
    }
    ushort_t r = f2bf(fmaxf(acc, 0.f));
    F[(size_t)p * 320 + co] = r;
    t0[(size_t)p * 64 + co] = r;
}

// ---------- implicit-GEMM MFMA conv 3x3 pad=1: NHWC bf16, relu (4-wave, batched) ----------
template<int CI>
__global__ __launch_bounds__(256) void conv_mfma_k(
    const ushort_t* __restrict__ in, int ldin, int inoff, size_t inImgStride,
    const ushort_t* __restrict__ wT, const float* __restrict__ bias,
    ushort_t* __restrict__ out, int ldout, int outoff, size_t outImgStride,
    int H, int W, int CO)
{
    in += (size_t)blockIdx.z * inImgStride;
    out += (size_t)blockIdx.z * outImgStride;
    const int tid = threadIdx.x;
    const int lane = tid & 63, wid = tid >> 6;
    const int wr = wid >> 1, wc = wid & 1;
    const int m0 = blockIdx.x * 64;
    const int n0 = blockIdx.y * 64;
    const int fr = lane & 15;
    const int fo = (lane >> 4) << 3;

    size_t abase[2];
    unsigned vmask[2];
#pragma unroll
    for (int mi = 0; mi < 2; ++mi) {
        int p = m0 + wr * 32 + mi * 16 + fr;
        int y = p / W, x = p % W;
        abase[mi] = (size_t)p * ldin + inoff + fo;
        unsigned vm = 0;
#pragma unroll
        for (int t = 0; t < 9; ++t) {
            int dy = t / 3 - 1, dx = t % 3 - 1;
            if ((unsigned)(y + dy) < (unsigned)H && (unsigned)(x + dx) < (unsigned)W) vm |= 1u << t;
        }
        vmask[mi] = vm;
    }

    f32x4 zero = {0.f, 0.f, 0.f, 0.f};
    f32x4 acc[2][2] = {{zero, zero}, {zero, zero}};
    const bf16x8 zz = {0, 0, 0, 0, 0, 0, 0, 0};

    for (int t = 0; t < 9; ++t) {
        int toff = ((t / 3 - 1) * W + (t % 3 - 1)) * ldin;
        bool v0 = (vmask[0] >> t) & 1u;
        bool v1 = (vmask[1] >> t) & 1u;
        const ushort_t* wp0 = wT + ((size_t)(t * CO + n0 + wc * 32 + fr)) * CI + fo;
        const ushort_t* wp1 = wp0 + (size_t)16 * CI;
#pragma unroll
        for (int kc = 0; kc < CI / 32; ++kc) {
            int k0 = kc * 32;
            bf16x8 a0 = v0 ? *(const bf16x8*)(in + abase[0] + toff + k0) : zz;
            bf16x8 a1 = v1 ? *(const bf16x8*)(in + abase[1] + toff + k0) : zz;
            bf16x8 b0 = *(const bf16x8*)(wp0 + k0);
            bf16x8 b1 = *(const bf16x8*)(wp1 + k0);
            acc[0][0] = __builtin_amdgcn_mfma_f32_16x16x32_bf16(b0, a0, acc[0][0], 0, 0, 0);
            acc[0][1] = __builtin_amdgcn_mfma_f32_16x16x32_bf16(b1, a0, acc[0][1], 0, 0, 0);
            acc[1][0] = __builtin_amdgcn_mfma_f32_16x16x32_bf16(b0, a1, acc[1][0], 0, 0, 0);
            acc[1][1] = __builtin_amdgcn_mfma_f32_16x16x32_bf16(b1, a1, acc[1][1], 0, 0, 0);
        }
    }

#pragma unroll
    for (int mi = 0; mi < 2; ++mi) {
#pragma unroll
        for (int ni = 0; ni < 2; ++ni) {
            int pix = m0 + wr * 32 + mi * 16 + (lane & 15);
            int ch = n0 + wc * 32 + ni * 16 + ((lane >> 4) << 2);
            float4 bv = *(const float4*)(bias + ch);
            float r0 = fmaxf(acc[mi][ni][0] + bv.x, 0.f);
            float r1 = fmaxf(acc[mi][ni][1] + bv.y, 0.f);
            float r2 = fmaxf(acc[mi][ni][2] + bv.z, 0.f);
            float r3 = fmaxf(acc[mi][ni][3] + bv.w, 0.f);
            uint2 pk;
            pk.x = (uint_t)f2bf(r0) | ((uint_t)f2bf(r1) << 16);
            pk.y = (uint_t)f2bf(r2) | ((uint_t)f2bf(r3) << 16);
            *(uint2*)(out + (size_t)pix * ldout + outoff + ch) = pk;
        }
    }
}

// ---------- 2-wave split-tap variant (32x32 tile) for deep low-res layers ----------
template<int CI>
__global__ __launch_bounds__(128) void conv_mfma2w_k(
    const ushort_t* __restrict__ in, int ldin, size_t inImgStride,
    const ushort_t* __restrict__ wT, const float* __restrict__ bias,
    ushort_t* __restrict__ out, int ldout, size_t outImgStride,
    int H, int W, int CO)
{
    __shared__ float red[64][17];
    in += (size_t)blockIdx.z * inImgStride;
    out += (size_t)blockIdx.z * outImgStride;
    const int lane = threadIdx.x & 63;
    const int wv = threadIdx.x >> 6;
    const int m0 = blockIdx.x * 32;
    const int n0 = blockIdx.y * 32;
    const int fr = lane & 15;
    const int fo = (lane >> 4) << 3;

    size_t abase[2];
    unsigned vmask[2];
#pragma unroll
    for (int mi = 0; mi < 2; ++mi) {
        int p = m0 + mi * 16 + fr;
        int y = p / W, x = p % W;
        abase[mi] = (size_t)p * ldin + fo;
        unsigned vm = 0;
#pragma unroll
        for (int t = 0; t < 9; ++t) {
            int dy = t / 3 - 1, dx = t % 3 - 1;
            if ((unsigned)(y + dy) < (unsigned)H && (unsigned)(x + dx) < (unsigned)W) vm |= 1u << t;
        }
        vmask[mi] = vm;
    }

    f32x4 zero = {0.f, 0.f, 0.f, 0.f};
    f32x4 acc[2][2] = {{zero, zero}, {zero, zero}};
    const bf16x8 zz = {0, 0, 0, 0, 0, 0, 0, 0};

    const int tb = wv ? 5 : 0;
    const int te = wv ? 9 : 5;
    for (int t = tb; t < te; ++t) {
        int toff = ((t / 3 - 1) * W + (t % 3 - 1)) * ldin;
        bool v0 = (vmask[0] >> t) & 1u;
        bool v1 = (vmask[1] >> t) & 1u;
        const ushort_t* wp0 = wT + ((size_t)(t * CO + n0 + fr)) * CI + fo;
        const ushort_t* wp1 = wp0 + (size_t)16 * CI;
#pragma unroll
        for (int kc = 0; kc < CI / 32; ++kc) {
            int k0 = kc * 32;
            bf16x8 a0 = v0 ? *(const bf16x8*)(in + abase[0] + toff + k0) : zz;
            bf16x8 a1 = v1 ? *(const bf16x8*)(in + abase[1] + toff + k0) : zz;
            bf16x8 b0 = *(const bf16x8*)(wp0 + k0);
            bf16x8 b1 = *(const bf16x8*)(wp1 + k0);
            acc[0][0] = __builtin_amdgcn_mfma_f32_16x16x32_bf16(b0, a0, acc[0][0], 0, 0, 0);
            acc[0][1] = __builtin_amdgcn_mfma_f32_16x16x32_bf16(b1, a0, acc[0][1], 0, 0, 0);
            acc[1][0] = __builtin_amdgcn_mfma_f32_16x16x32_bf16(b0, a1, acc[1][0], 0, 0, 0);
            acc[1][1] = __builtin_amdgcn_mfma_f32_16x16x32_bf16(b1, a1, acc[1][1], 0, 0, 0);
        }
    }

    if (wv == 1) {
#pragma unroll
        for (int mi = 0; mi < 2; ++mi)
#pragma unroll
            for (int ni = 0; ni < 2; ++ni)
#pragma unroll
                for (int r = 0; r < 4; ++r)
                    red[lane][mi * 8 + ni * 4 + r] = acc[mi][ni][r];
    }
    __syncthreads();
    if (wv == 0) {
#pragma unroll
        for (int mi = 0; mi < 2; ++mi) {
#pragma unroll
            for (int ni = 0; ni < 2; ++ni) {
                int pix = m0 + mi * 16 + (lane & 15);
                int ch = n0 + ni * 16 + ((lane >> 4) << 2);
                float4 bv = *(const float4*)(bias + ch);
                float r0 = fmaxf(acc[mi][ni][0] + red[lane][mi * 8 + ni * 4 + 0] + bv.x, 0.f);
                float r1 = fmaxf(acc[mi][ni][1] + red[lane][mi * 8 + ni * 4 + 1] + bv.y, 0.f);
                float r2 = fmaxf(acc[mi][ni][2] + red[lane][mi * 8 + ni * 4 + 2] + bv.z, 0.f);
                float r3 = fmaxf(acc[mi][ni][3] + red[lane][mi * 8 + ni * 4 + 3] + bv.w, 0.f);
                uint2 pk;
                pk.x = (uint_t)f2bf(r0) | ((uint_t)f2bf(r1) << 16);
                pk.y = (uint_t)f2bf(r2) | ((uint_t)f2bf(r3) << 16);
                *(uint2*)(out + (size_t)pix * ldout + ch) = pk;
            }
        }
    }
}

// ---------- 2x2 maxpool NHWC bf16 (batched via blockIdx.y) ----------
__global__ void maxpool_nhwc_k(const ushort_t* __restrict__ in, ushort_t* __restrict__ out,
                               int C, int Hi, int Wi)
{
    in += (size_t)blockIdx.y * TSTRIDE;
    out += (size_t)blockIdx.y * TSTRIDE;
    int idx = blockIdx.x * 256 + threadIdx.x;
    int CG = C >> 3;
    int Wo = Wi >> 1, Ho = Hi >> 1;
    if (idx >= Ho * Wo * CG) return;
    int cg = idx % CG;
    int p = idx / CG;
    int y = p / Wo, x = p % Wo;
    const ushort_t* ip = in + ((size_t)(2 * y) * Wi + 2 * x) * C + cg * 8;
    bf16x8 v0 = *(const bf16x8*)(ip);
    bf16x8 v1 = *(const bf16x8*)(ip + C);
    bf16x8 v2 = *(const bf16x8*)(ip + (size_t)Wi * C);
    bf16x8 v3 = *(const bf16x8*)(ip + (size_t)Wi * C + C);
    bf16x8 r;
#pragma unroll
    for (int j = 0; j < 8; ++j) {
        float m = fmaxf(fmaxf(bf2f((ushort_t)v0[j]), bf2f((ushort_t)v1[j])),
                        fmaxf(bf2f((ushort_t)v2[j]), bf2f((ushort_t)v3[j])));
        r[j] = (short)f2bf(m);
    }
    *(bf16x8*)(out + (size_t)p * C + cg * 8) = r;
}

// ---------- bicubic weights (align_corners=True), PyTorch A=-0.75 ----------
__device__ inline void cubw(float t, float* w) {
    float x0 = 1.f + t, x2 = 1.f - t, x3 = 2.f - t;
    w[0] = ((-0.75f*x0 + 3.75f)*x0 - 6.f)*x0 + 3.f;
    w[1] = (1.25f*t - 2.25f)*t*t + 1.f;
    w[2] = (1.25f*x2 - 2.25f)*x2*x2 + 1.f;
    w[3] = ((-0.75f*x3 + 3.75f)*x3 - 6.f)*x3 + 3.f;
}

// ---------- fused: bicubic 32->128 + L2 norm; img0 additionally 2x2-mean-pools into Abuf ----------
__global__ __launch_bounds__(256) void upnorm_k(const ushort_t* __restrict__ in, ushort_t* __restrict__ F,
                                                ushort_t* __restrict__ Abuf)
{
    __shared__ float sm[4][320];
    in += (size_t)blockIdx.y * TSTRIDE;
    F += (size_t)blockIdx.y * FSTRIDE;
    int wid = threadIdx.x >> 6, lane = threadIdx.x & 63;
    int pb = blockIdx.x;
    int py = pb >> 6, px = pb & 63;
    int p = (2 * py + (wid >> 1)) * 128 + 2 * px + (wid & 1);
    int Y = p >> 7, X = p & 127;
    float sy = (float)Y * (31.f / 127.f);
    float sx = (float)X * (31.f / 127.f);
    int fy = (int)floorf(sy), fx = (int)floorf(sx);
    float ty = sy - (float)fy, tx = sx - (float)fx;
    float wy[4], wx[4];
    cubw(ty, wy); cubw(tx, wx);
    float a0 = 0.f, a1 = 0.f, a2 = 0.f, a3 = 0.f;
#pragma unroll
    for (int i = 0; i < 4; ++i) {
        int yy = min(max(fy - 1 + i, 0), 31);
#pragma unroll
        for (int j = 0; j < 4; ++j) {
            int xx = min(max(fx - 1 + j, 0), 31);
            float w = wy[i] * wx[j];
            uint2 v = *(const uint2*)(in + ((size_t)yy * 32 + xx) * 256 + lane * 4);
            a0 += w * bflo(v.x); a1 += w * bfhi(v.x);
            a2 += w * bflo(v.y); a3 += w * bfhi(v.y);
        }
    }
    float v0 = bf2f(f2bf(a0)), v1 = bf2f(f2bf(a1)), v2 = bf2f(f2bf(a2)), v3 = bf2f(f2bf(a3));
    float c0 = bf2f(F[(size_t)p * 320 + lane]);
    float ss = c0 * c0 + v0 * v0 + v1 * v1 + v2 * v2 + v3 * v3;
#pragma unroll
    for (int off = 32; off > 0; off >>= 1) ss += __shfl_xor(ss, off);
    float inv = 1.f / (1e-8f + sqrtf(ss));
    if (blockIdx.y == 1) {
        F[(size_t)p * 320 + lane] = f2bf(c0 * inv);
        uint2 pk;
        pk.x = (uint_t)f2bf(v0 * inv) | ((uint_t)f2bf(v1 * inv) << 16);
        pk.y = (uint_t)f2bf(v2 * inv) | ((uint_t)f2bf(v3 * inv) << 16);
        *(uint2*)(F + (size_t)p * 320 + 64 + lane * 4) = pk;
    } else {
        sm[wid][lane] = bf2f(f2bf(c0 * inv));
        sm[wid][64 + lane * 4 + 0] = bf2f(f2bf(v0 * inv));
        sm[wid][64 + lane * 4 + 1] = bf2f(f2bf(v1 * inv));
        sm[wid][64 + lane * 4 + 2] = bf2f(f2bf(v2 * inv));
        sm[wid][64 + lane * 4 + 3] = bf2f(f2bf(v3 * inv));
        __syncthreads();
        for (int ch = threadIdx.x; ch < 320; ch += 256) {
            float a = 0.25f * (sm[0][ch] + sm[1][ch] + sm[2][ch] + sm[3][ch]);
            Abuf[(size_t)pb * 320 + ch] = f2bf(a);
        }
    }
}

// ---------- correlation GEMM, A-panel-resident / zero-barrier main loop ----------
// Block = 64 A-rows (LDS-resident, staged once) x 2048 B-cols (16 n-tiles).
// B read directly from global (L2-resident per XCD via chunked swizzle).
// No barriers in n/K loops. int8 dist out; fused softmax partials.
__global__ __launch_bounds__(256) void gemm_corr_k(
    const ushort_t* __restrict__ A, const ushort_t* __restrict__ B, char* __restrict__ D8,
    const float* __restrict__ coefr, const float* __restrict__ coeft,
    float* __restrict__ rpsum, float* __restrict__ cpsum)
{
    __shared__ ushort_t lA[64 * 328];     // padded stride 328 breaks bank pattern
    __shared__ float rl[4][64];
    const int tid = threadIdx.x;
    const int lane = tid & 63;
    const int wv = tid >> 6;              // wave 0..3 -> its 32-col n-subrange
    const int fr = lane & 15;
    const int fo = (lane >> 4) << 3;
    const int ng = (lane >> 4) << 2;

    // XCD-chunked bijective swizzle (512 = 8 x 64): XCD x hosts n-chunk x.
    int bid = blockIdx.x;
    int swz = (bid & 7) * 64 + (bid >> 3);
    const int mb = swz & 63;              // m-block: rows mb*64..+63
    const int nc = swz >> 6;              // n-chunk: cols nc*2048..+2047

    // stage A panel [64][320] -> LDS [64][328] (once)
#pragma unroll
    for (int i = 0; i < 10; ++i) {
        int e = (i * 256 + tid) * 8;
        int row = e / 320, col = e % 320;
        uint4 v = *(const uint4*)(A + ((size_t)(mb * 64 + row)) * 320 + col);
        *(uint4*)&lA[row * 328 + col] = v;
    }
    __syncthreads();

    const float s = 1.0f / 320.0f;
    const float cr = coefr[0], ct = coeft[0];
    const bool sameCoef = (cr == ct);
    float rpx0 = 0.f, rpx1 = 0.f, rpx2 = 0.f, rpx3 = 0.f;

    for (int it = 0; it < 16; ++it) {
        const int n0 = nc * 2048 + it * 128 + wv * 32;
        const ushort_t* Bg0 = B + (size_t)(n0 + fr) * 320 + fo;
        const ushort_t* Bg1 = Bg0 + (size_t)16 * 320;

        f32x4 zero = {0.f, 0.f, 0.f, 0.f};
        f32x4 acc[4][2];
#pragma unroll
        for (int mi = 0; mi < 4; ++mi) { acc[mi][0] = zero; acc[mi][1] = zero; }

#pragma unroll
        for (int kk = 0; kk < 10; ++kk) {
            const int k0 = kk * 32;
            bf16x8 b0 = *(const bf16x8*)(Bg0 + k0);
            bf16x8 b1 = *(const bf16x8*)(Bg1 + k0);
#pragma unroll
            for (int mi = 0; mi < 4; ++mi) {
                bf16x8 af = *(const bf16x8*)&lA[(mi * 16 + fr) * 328 + k0 + fo];
                acc[mi][0] = __builtin_amdgcn_mfma_f32_16x16x32_bf16(b0, af, acc[mi][0], 0, 0, 0);
                acc[mi][1] = __builtin_amdgcn_mfma_f32_16x16x32_bf16(b1, af, acc[mi][1], 0, 0, 0);
            }
        }

        // epilogue for this n-tile
        float cpx[2][4];
#pragma unroll
        for (int nf = 0; nf < 2; ++nf)
#pragma unroll
            for (int r = 0; r < 4; ++r) cpx[nf][r] = 0.f;

#pragma unroll
        for (int mi = 0; mi < 4; ++mi) {
            int m = mb * 64 + mi * 16 + (lane & 15);
            char* drow = D8 + (size_t)m * 16384;
#pragma unroll
            for (int nf = 0; nf < 2; ++nf) {
                int n = n0 + nf * 16 + ng;
                float d0 = acc[mi][nf][0] * s;
                float d1 = acc[mi][nf][1] * s;
                float d2 = acc[mi][nf][2] * s;
                float d3 = acc[mi][nf][3] * s;
                int q0 = __float2int_rn(fminf(fmaxf(d0 * 40640.f, -127.f), 127.f));
                int q1 = __float2int_rn(fminf(fmaxf(d1 * 40640.f, -127.f), 127.f));
                int q2 = __float2int_rn(fminf(fmaxf(d2 * 40640.f, -127.f), 127.f));
                int q3 = __float2int_rn(fminf(fmaxf(d3 * 40640.f, -127.f), 127.f));
                uint_t pk8 = (uint_t)(q0 & 255) | ((uint_t)(q1 & 255) << 8)
                           | ((uint_t)(q2 & 255) << 16) | ((uint_t)(q3 & 255) << 24);
                *(uint_t*)(drow + n) = pk8;
                float e0 = __expf(cr * d0), e1 = __expf(cr * d1);
                float e2 = __expf(cr * d2), e3 = __expf(cr * d3);
                cpx[nf][0] += e0; cpx[nf][1] += e1; cpx[nf][2] += e2; cpx[nf][3] += e3;
                float re;
                if (sameCoef) re = e0 + e1 + e2 + e3;
                else re = __expf(ct * d0) + __expf(ct * d1) + __expf(ct * d2) + __expf(ct * d3);
                if (mi == 0) rpx0 += re; else if (mi == 1) rpx1 += re;
                else if (mi == 2) rpx2 += re; else rpx3 += re;
            }
        }
        // column partials: reduce across the 16 m-lanes; cols are wave-private
#pragma unroll
        for (int nf = 0; nf < 2; ++nf)
#pragma unroll
            for (int r = 0; r < 4; ++r) {
                cpx[nf][r] += __shfl_xor(cpx[nf][r], 1);
                cpx[nf][r] += __shfl_xor(cpx[nf][r], 2);
                cpx[nf][r] += __shfl_xor(cpx[nf][r], 4);
                cpx[nf][r] += __shfl_xor(cpx[nf][r], 8);
            }
        if ((lane & 15) == 0) {
            int g = lane >> 4;
#pragma unroll
            for (int nf = 0; nf < 2; ++nf)
#pragma unroll
                for (int r = 0; r < 4; ++r)
                    cpsum[(size_t)mb * 16384 + n0 + nf * 16 + g * 4 + r] = cpx[nf][r];
        }
    }

    // row partials: reduce over the 4 n-groups, then across waves (one barrier)
    rpx0 += __shfl_xor(rpx0, 16); rpx0 += __shfl_xor(rpx0, 32);
    rpx1 += __shfl_xor(rpx1, 16); rpx1 += __shfl_xor(rpx1, 32);
    rpx2 += __shfl_xor(rpx2, 16); rpx2 += __shfl_xor(rpx2, 32);
    rpx3 += __shfl_xor(rpx3, 16); rpx3 += __shfl_xor(rpx3, 32);
    if (lane < 16) {
        rl[wv][0 * 16 + lane] = rpx0;
        rl[wv][1 * 16 + lane] = rpx1;
        rl[wv][2 * 16 + lane] = rpx2;
        rl[wv][3 * 16 + lane] = rpx3;
    }
    __syncthreads();
    if (tid < 64) {
        float rsum = rl[0][tid] + rl[1][tid] + rl[2][tid] + rl[3][tid];
        rpsum[(size_t)nc * 4096 + mb * 64 + tid] = rsum;
    }
}

// ---------- fused finalize: lc[j] = -0.5*log(colsum); invr[m] = rsqrt(rowsum) ----------
__global__ void finboth_k(const float* __restrict__ cpsum, const float* __restrict__ rpsum,
                          float* __restrict__ lc, float* __restrict__ invr)
{
    int b = blockIdx.x;
    if (b < 64) {
        int j = b * 256 + threadIdx.x;
        float s = 0.f;
#pragma unroll
        for (int k = 0; k < 64; ++k) s += cpsum[(size_t)k * 16384 + j];
        lc[j] = -0.5f * __logf(s);
    } else {
        int m = (b - 64) * 256 + threadIdx.x;
        float s = 0.f;
#pragma unroll
        for (int k = 0; k < 8; ++k) s += rpsum[(size_t)k * 4096 + m];
        invr[m] = rsqrtf(s);
    }
}

// ---------- per-row top-5 on int8 dist, key space, early reject (one wave/row) ----------
#define INS5(w_) { float w = (w_); float mx; \
    mx = fmaxf(w, t0); w = fminf(w, t0); t0 = mx; \
    mx = fmaxf(w, t1); w = fminf(w, t1); t1 = mx; \
    mx = fmaxf(w, t2); w = fminf(w, t2); t2 = mx; \
    mx = fmaxf(w, t3); w = fminf(w, t3); t3 = mx; \
    t4 = fmaxf(w, t4); }
#define SB(w, sft) ((float)(int)(signed char)(((w) >> (sft)) & 0xffu))

__global__ __launch_bounds__(256) void row_topk_k(
    const char* __restrict__ D8, const float* __restrict__ lc,
    const float* __restrict__ invr,
    const float* __restrict__ coefr, const float* __restrict__ coeft,
    float* __restrict__ conf5)
{
    int wid = threadIdx.x >> 6, lane = threadIdx.x & 63;
    int row = blockIdx.x * 4 + wid;
    float hc = 0.5f * (coefr[0] + coeft[0]);
    float hq = hc * (1.0f / 40640.f);
    const char* rp = D8 + (size_t)row * 16384;

    float t0 = -1e30f, t1 = -1e30f, t2 = -1e30f, t3 = -1e30f, t4 = -1e30f;
    for (int i = 0; i < 16; ++i) {
        int cw = i * 64 + lane;
        uint4 u = *(const uint4*)(rp + cw * 16);
        int col = cw * 16;
        float4 l0 = *(const float4*)(lc + col);
        float4 l1 = *(const float4*)(lc + col + 4);
        float4 l2 = *(const float4*)(lc + col + 8);
        float4 l3 = *(const float4*)(lc + col + 12);
        float k0  = fmaf(hq, SB(u.x, 0),  l0.x);
        float k1  = fmaf(hq, SB(u.x, 8),  l0.y);
        float k2  = fmaf(hq, SB(u.x, 16), l0.z);
        float k3  = fmaf(hq, SB(u.x, 24), l0.w);
        float k4  = fmaf(hq, SB(u.y, 0),  l1.x);
        float k5  = fmaf(hq, SB(u.y, 8),  l1.y);
        float k6  = fmaf(hq, SB(u.y, 16), l1.z);
        float k7  = fmaf(hq, SB(u.y, 24), l1.w);
        float k8  = fmaf(hq, SB(u.z, 0),  l2.x);
        float k9  = fmaf(hq, SB(u.z, 8),  l2.y);
        float k10 = fmaf(hq, SB(u.z, 16), l2.z);
        float k11 = fmaf(hq, SB(u.z, 24), l2.w);
        float k12 = fmaf(hq, SB(u.w, 0),  l3.x);
        float k13 = fmaf(hq, SB(u.w, 8),  l3.y);
        float k14 = fmaf(hq, SB(u.w, 16), l3.z);
        float k15 = fmaf(hq, SB(u.w, 24), l3.w);
        float ma = fmaxf(fmaxf(fmaxf(k0, k1), fmaxf(k2, k3)),
                         fmaxf(fmaxf(k4, k5), fmaxf(k6, k7)));
        float mb = fmaxf(fmaxf(fmaxf(k8, k9), fmaxf(k10, k11)),
                         fmaxf(fmaxf(k12, k13), fmaxf(k14, k15)));
        if (fmaxf(ma, mb) > t4) {
            INS5(k0);  INS5(k1);  INS5(k2);  INS5(k3);
            INS5(k4);  INS5(k5);  INS5(k6);  INS5(k7);
            INS5(k8);  INS5(k9);  INS5(k10); INS5(k11);
            INS5(k12); INS5(k13); INS5(k14); INS5(k15);
        }
    }
#pragma unroll
    for (int off = 1; off < 64; off <<= 1) {
        float o0 = __shfl_xor(t0, off), o1 = __shfl_xor(t1, off), o2 = __shfl_xor(t2, off);
        float o3 = __shfl_xor(t3, off), o4 = __shfl_xor(t4, off);
        INS5(o0); INS5(o1); INS5(o2); INS5(o3); INS5(o4);
    }
    if (lane == 0) {
        float iv = invr[row];
        conf5[0 * 4096 + row] = __expf(t0) * iv;
        conf5[1 * 4096 + row] = __expf(t1) * iv;
        conf5[2 * 4096 + row] = __expf(t2) * iv;
        conf5[3 * 4096 + row] = __expf(t3) * iv;
        conf5[4 * 4096 + row] = __expf(t4) * iv;
    }
}

// ---------- fp32 3x3 conv (head conv1, NCHW) ----------
__global__ void conv3x3_k(const float* __restrict__ in, const float* __restrict__ wgt,
                          const float* __restrict__ bias, float* __restrict__ out,
                          int Cin, int H, int W, int relu)
{
    int p = blockIdx.x * 256 + threadIdx.x;
    int HW = H * W;
    if (p >= HW) return;
    int co0 = blockIdx.y * 8;
    int y = p / W, x = p - y * W;
    float acc0 = bias[co0+0], acc1 = bias[co0+1], acc2 = bias[co0+2], acc3 = bias[co0+3];
    float acc4 = bias[co0+4], acc5 = bias[co0+5], acc6 = bias[co0+6], acc7 = bias[co0+7];
    bool ym = y > 0, yp = y < H-1, xm = x > 0, xp = x < W-1;
    for (int ci = 0; ci < Cin; ++ci) {
        const float* ip = in + (size_t)ci * HW + p;
        float v0 = (ym && xm) ? ip[-W-1] : 0.f;
        float v1 = (ym)       ? ip[-W]   : 0.f;
        float v2 = (ym && xp) ? ip[-W+1] : 0.f;
        float v3 = (xm)       ? ip[-1]   : 0.f;
        float v4 =              ip[0];
        float v5 = (xp)       ? ip[1]    : 0.f;
        float v6 = (yp && xm) ? ip[W-1]  : 0.f;
        float v7 = (yp)       ? ip[W]    : 0.f;
        float v8 = (yp && xp) ? ip[W+1]  : 0.f;
        const float* wp = wgt + ((size_t)co0 * Cin + ci) * 9;
        size_t ws = (size_t)Cin * 9;
#define CACC(q, a) { const float* wq = wp + q * ws; \
        a += wq[0]*v0 + wq[1]*v1 + wq[2]*v2 + wq[3]*v3 + wq[4]*v4 \
           + wq[5]*v5 + wq[6]*v6 + wq[7]*v7 + wq[8]*v8; }
        CACC(0, acc0) CACC(1, acc1) CACC(2, acc2) CACC(3, acc3)
        CACC(4, acc4) CACC(5, acc5) CACC(6, acc6) CACC(7, acc7)
#undef CACC
    }
#define CW(q, a) { float r = a; if (relu) r = fmaxf(r, 0.f); out[(size_t)(co0+q)*HW + p] = r; }
    CW(0, acc0) CW(1, acc1) CW(2, acc2) CW(3, acc3)
    CW(4, acc4) CW(5, acc5) CW(6, acc6) CW(7, acc7)
#undef CW
}

// ---------- head conv2 (8->8, relu) fused with 1x1 (8->1) ----------
__global__ void head2_k(const float* __restrict__ in, const float* __restrict__ wgt,
                        const float* __restrict__ bias, const float* __restrict__ w3,
                        const float* __restrict__ b3, float* __restrict__ out64)
{
    int p = blockIdx.x * 256 + threadIdx.x;
    int y = p >> 6, x = p & 63;
    float acc[8];
#pragma unroll
    for (int c = 0; c < 8; ++c) acc[c] = bias[c];
    bool ym = y > 0, yp = y < 63, xm = x > 0, xp = x < 63;
#pragma unroll
    for (int ci = 0; ci < 8; ++ci) {
        const float* ip = in + ci * 4096 + p;
        float v0 = (ym && xm) ? ip[-65] : 0.f;
        float v1 = (ym)       ? ip[-64] : 0.f;
        float v2 = (ym && xp) ? ip[-63] : 0.f;
        float v3 = (xm)       ? ip[-1]  : 0.f;
        float v4 =              ip[0];
        float v5 = (xp)       ? ip[1]   : 0.f;
        float v6 = (yp && xm) ? ip[63]  : 0.f;
        float v7 = (yp)       ? ip[64]  : 0.f;
        float v8 = (yp && xp) ? ip[65]  : 0.f;
#pragma unroll
        for (int co = 0; co < 8; ++co) {
            const float* wq = wgt + ((size_t)co * 8 + ci) * 9;
            acc[co] += wq[0]*v0 + wq[1]*v1 + wq[2]*v2 + wq[3]*v3 + wq[4]*v4
                     + wq[5]*v5 + wq[6]*v6 + wq[7]*v7 + wq[8]*v8;
        }
    }
    float o = b3[0];
#pragma unroll
    for (int c = 0; c < 8; ++c) o += w3[c] * fmaxf(acc[c], 0.f);
    out64[p] = o;
}

// ---------- fp32 bicubic (final output) ----------
__global__ void bicubic_k(const float* __restrict__ in, float* __restrict__ out,
                          int C, int Hin, int Win, int Hout, int Wout)
{
    int idx = blockIdx.x * 256 + threadIdx.x;
    int total = C * Hout * Wout;
    if (idx >= total) return;
    int X = idx % Wout;
    int Y = (idx / Wout) % Hout;
    int c = idx / (Wout * Hout);
    float sy = (float)Y * (float)(Hin - 1) / (float)(Hout - 1);
    float sx = (float)X * (float)(Win - 1) / (float)(Wout - 1);
    int fy = (int)floorf(sy), fx = (int)floorf(sx);
    float ty = sy - (float)fy, tx = sx - (float)fx;
    float wy[4], wx[4];
    cubw(ty, wy); cubw(tx, wx);
    const float* ip = in + (size_t)c * Hin * Win;
    float acc = 0.f;
#pragma unroll
    for (int i = 0; i < 4; ++i) {
        int yy = min(max(fy - 1 + i, 0), Hin - 1);
        float ra = 0.f;
#pragma unroll
        for (int j = 0; j < 4; ++j) {
            int xx = min(max(fx - 1 + j, 0), Win - 1);
            ra += wx[j] * ip[yy * Win + xx];
        }
        acc += wy[i] * ra;
    }
    out[idx] = acc;
}

// ---------- host ----------
extern "C" void kernel_launch(void* const* d_in, const int* in_sizes, int n_in,
                              void* d_out, int out_size, void* d_ws, size_t ws_size,
                              hipStream_t stream)
{
    const float* x_ref = (const float*)d_in[0];
    const float* x_tem = (const float*)d_in[1];
    const float* w0  = (const float*)d_in[2];   const float* b0  = (const float*)d_in[3];
    const float* w2  = (const float*)d_in[4];   const float* b2  = (const float*)d_in[5];
    const float* w5  = (const float*)d_in[6];   const float* b5  = (const float*)d_in[7];
    const float* w7  = (const float*)d_in[8];   const float* b7  = (const float*)d_in[9];
    const float* w10 = (const float*)d_in[10];  const float* b10 = (const float*)d_in[11];
    const float* w12 = (const float*)d_in[12];  const float* b12 = (const float*)d_in[13];
    const float* w14 = (const float*)d_in[14];  const float* b14 = (const float*)d_in[15];
    const float* coefr = (const float*)d_in[16];
    const float* coeft = (const float*)d_in[17];
    const float* fw1 = (const float*)d_in[18];  const float* fb1 = (const float*)d_in[19];
    const float* fw2 = (const float*)d_in[20];  const float* fb2 = (const float*)d_in[21];
    const float* fw3 = (const float*)d_in[22];  const float* fb3 = (const float*)d_in[23];
    float* out = (float*)d_out;

    char* wsp = (char*)d_ws;
    auto alloc = [&](size_t bytes) { char* p = wsp; wsp += (bytes + 255) & ~(size_t)255; return p; };
    ushort_t* F     = (ushort_t*)alloc(2 * FSTRIDE * 2);
    ushort_t* t0    = (ushort_t*)alloc(2 * TSTRIDE * 2);
    ushort_t* t1    = (ushort_t*)alloc(2 * TSTRIDE * 2);
    ushort_t* t2    = (ushort_t*)alloc(2 * TSTRIDE * 2);
    ushort_t* wT2   = (ushort_t*)alloc((size_t)64 * 64 * 9 * 2);
    ushort_t* wT5   = (ushort_t*)alloc((size_t)128 * 64 * 9 * 2);
    ushort_t* wT7   = (ushort_t*)alloc((size_t)128 * 128 * 9 * 2);
    ushort_t* wT10  = (ushort_t*)alloc((size_t)256 * 128 * 9 * 2);
    ushort_t* wT12  = (ushort_t*)alloc((size_t)256 * 256 * 9 * 2);
    ushort_t* wT14  = (ushort_t*)alloc((size_t)256 * 256 * 9 * 2);
    ushort_t* Abuf  = (ushort_t*)alloc((size_t)4096 * 320 * 2);
    char*     dist8 = (char*)alloc((size_t)4096 * 16384);
    float*    rpsum = (float*)alloc((size_t)8 * 4096 * 4);
    float*    cpsum = (float*)alloc((size_t)64 * 16384 * 4);
    float*    lc    = (float*)alloc(16384 * 4);
    float*    invr  = (float*)alloc(4096 * 4);
    float*    conf5 = (float*)alloc(5 * 4096 * 4);
    float*    h1    = (float*)alloc(8 * 4096 * 4);
    float*    out64 = (float*)alloc(4096 * 4);
    (void)ws_size; (void)n_in; (void)in_sizes; (void)out_size;

    // fused weight transforms
    WT6 wt;
    wt.src[0] = w2;  wt.dst[0] = wT2;  wt.co[0] = 64;  wt.ci[0] = 64;
    wt.src[1] = w5;  wt.dst[1] = wT5;  wt.co[1] = 128; wt.ci[1] = 64;
    wt.src[2] = w7;  wt.dst[2] = wT7;  wt.co[2] = 128; wt.ci[2] = 128;
    wt.src[3] = w10; wt.dst[3] = wT10; wt.co[3] = 256; wt.ci[3] = 128;
    wt.src[4] = w12; wt.dst[4] = wT12; wt.co[4] = 256; wt.ci[4] = 256;
    wt.src[5] = w14; wt.dst[5] = wT14; wt.co[5] = 256; wt.ci[5] = 256;
    int nblk = 0;
    for (int s = 0; s < 6; ++s) { wt.off[s] = nblk; nblk += (wt.co[s] * wt.ci[s] * 9 + 255) / 256; }
    wtrans6_k<<<nblk, 256, 0, stream>>>(wt);

    // batched feature extraction
    conv0_k<<<dim3(4096, 2), 256, 0, stream>>>(x_ref, x_tem, w0, b0, F, t0);
    conv_mfma_k<64><<<dim3(256, 1, 2), 256, 0, stream>>>(t0, 64, 0, TSTRIDE, wT2, b2, t1, 64, 0, TSTRIDE, 128, 128, 64);
    maxpool_nhwc_k<<<dim3(128, 2), 256, 0, stream>>>(t1, t2, 64, 128, 128);
    conv_mfma_k<64><<<dim3(64, 2, 2), 256, 0, stream>>>(t2, 64, 0, TSTRIDE, wT5, b5, t1, 128, 0, TSTRIDE, 64, 64, 128);
    conv_mfma_k<128><<<dim3(64, 2, 2), 256, 0, stream>>>(t1, 128, 0, TSTRIDE, wT7, b7, t2, 128, 0, TSTRIDE, 64, 64, 128);
    maxpool_nhwc_k<<<dim3(64, 2), 256, 0, stream>>>(t2, t1, 128, 64, 64);
    conv_mfma2w_k<128><<<dim3(32, 8, 2), 128, 0, stream>>>(t1, 128, TSTRIDE, wT10, b10, t2, 256, TSTRIDE, 32, 32, 256);
    conv_mfma2w_k<256><<<dim3(32, 8, 2), 128, 0, stream>>>(t2, 256, TSTRIDE, wT12, b12, t1, 256, TSTRIDE, 32, 32, 256);
    conv_mfma2w_k<256><<<dim3(32, 8, 2), 128, 0, stream>>>(t1, 256, TSTRIDE, wT14, b14, t2, 256, TSTRIDE, 32, 32, 256);
    upnorm_k<<<dim3(4096, 2), 256, 0, stream>>>(t2, F, Abuf);

    gemm_corr_k<<<512, 256, 0, stream>>>(Abuf, F + FSTRIDE, dist8, coefr, coeft, rpsum, cpsum);

    finboth_k<<<80, 256, 0, stream>>>(cpsum, rpsum, lc, invr);

    row_topk_k<<<1024, 256, 0, stream>>>(dist8, lc, invr, coefr, coeft, conf5);

    conv3x3_k<<<dim3(16, 1), 256, 0, stream>>>(conf5, fw1, fb1, h1, 5, 64, 64, 1);
    head2_k<<<16, 256, 0, stream>>>(h1, fw2, fb2, fw3, fb3, out64);
    bicubic_k<<<64, 256, 0, stream>>>(out64, out, 1, 64, 64, 128, 128);
}

// Round 13
// 381.663 us; speedup vs baseline: 1.0492x; 1.0492x over previous
//
#include <hip/hip_runtime.h>
#include <math.h>

typedef unsigned short ushort_t;
typedef unsigned int uint_t;
typedef __attribute__((ext_vector_type(8))) short bf16x8;
typedef __attribute__((ext_vector_type(4))) float f32x4;

#define FSTRIDE ((size_t)16384 * 320)
#define TSTRIDE ((size_t)16384 * 64)

// ---------- bf16 helpers ----------
__device__ inline ushort_t f2bf(float f) {
    union { float f; uint_t u; } x; x.f = f;
    uint_t r = x.u + 0x7fffu + ((x.u >> 16) & 1u);
    return (ushort_t)(r >> 16);
}
__device__ inline float bf2f(ushort_t h) {
    union { uint_t u; float f; } x; x.u = ((uint_t)h) << 16;
    return x.f;
}
__device__ inline float bflo(uint_t u) {
    union { uint_t u; float f; } x; x.u = u << 16; return x.f;
}
__device__ inline float bfhi(uint_t u) {
    union { uint_t u; float f; } x; x.u = u & 0xffff0000u; return x.f;
}

// ---------- fused weight transform: 6 conv layers, OIHW fp32 -> [tap][co][ci] bf16 ----------
struct WT6 {
    const float* src[6];
    ushort_t* dst[6];
    int co[6], ci[6];
    int off[6];
};
__global__ void wtrans6_k(WT6 a)
{
    int b = blockIdx.x, seg = 0;
#pragma unroll
    for (int s = 1; s < 6; ++s) if (b >= a.off[s]) seg = s;
    int idx = (b - a.off[seg]) * 256 + threadIdx.x;
    int CO = a.co[seg], CI = a.ci[seg];
    if (idx >= CO * CI * 9) return;
    int tap = idx % 9;
    int rem = idx / 9;
    int ci = rem % CI;
    int co = rem / CI;
    a.dst[seg][((size_t)tap * CO + co) * CI + ci] = f2bf(a.src[seg][idx]);
}

// ---------- conv0: 3->64 @128x128, NCHW fp32 in; writes F cols 0..63 AND compact t0 ----------
__global__ __launch_bounds__(256) void conv0_k(const float* __restrict__ x0, const float* __restrict__ x1,
                                               const float* __restrict__ w,
                                               const float* __restrict__ b, ushort_t* __restrict__ F,
                                               ushort_t* __restrict__ t0)
{
    const float* x = blockIdx.y ? x1 : x0;
    F += (size_t)blockIdx.y * FSTRIDE;
    t0 += (size_t)blockIdx.y * TSTRIDE;
    int co = threadIdx.x & 63;
    int p = blockIdx.x * 4 + (threadIdx.x >> 6);
    int y = p >> 7, xx = p & 127;
    float acc = b[co];
#pragma unroll
    for (int ci = 0; ci < 3; ++ci) {
#pragma unroll
        for (int t = 0; t < 9; ++t) {
            int dy = t / 3 - 1, dx = t % 3 - 1;
            int yy = y + dy, xc = xx + dx;
            if ((unsigned)yy < 128u && (unsigned)xc < 128u) {
                acc += x[ci * 16384 + yy * 128 + xc] * w[co * 27 + ci * 9 + t];
            }
        }
    }
    ushort_t r = f2bf(fmaxf(acc, 0.f));
    F[(size_t)p * 320 + co] = r;
    t0[(size_t)p * 64 + co] = r;
}

// ---------- implicit-GEMM MFMA conv 3x3 pad=1: NHWC bf16, relu (4-wave, batched) ----------
template<int CI>
__global__ __launch_bounds__(256) void conv_mfma_k(
    const ushort_t* __restrict__ in, int ldin, int inoff, size_t inImgStride,
    const ushort_t* __restrict__ wT, const float* __restrict__ bias,
    ushort_t* __restrict__ out, int ldout, int outoff, size_t outImgStride,
    int H, int W, int CO)
{
    in += (size_t)blockIdx.z * inImgStride;
    out += (size_t)blockIdx.z * outImgStride;
    const int tid = threadIdx.x;
    const int lane = tid & 63, wid = tid >> 6;
    const int wr = wid >> 1, wc = wid & 1;
    const int m0 = blockIdx.x * 64;
    const int n0 = blockIdx.y * 64;
    const int fr = lane & 15;
    const int fo = (lane >> 4) << 3;

    size_t abase[2];
    unsigned vmask[2];
#pragma unroll
    for (int mi = 0; mi < 2; ++mi) {
        int p = m0 + wr * 32 + mi * 16 + fr;
        int y = p / W, x = p % W;
        abase[mi] = (size_t)p * ldin + inoff + fo;
        unsigned vm = 0;
#pragma unroll
        for (int t = 0; t < 9; ++t) {
            int dy = t / 3 - 1, dx = t % 3 - 1;
            if ((unsigned)(y + dy) < (unsigned)H && (unsigned)(x + dx) < (unsigned)W) vm |= 1u << t;
        }
        vmask[mi] = vm;
    }

    f32x4 zero = {0.f, 0.f, 0.f, 0.f};
    f32x4 acc[2][2] = {{zero, zero}, {zero, zero}};
    const bf16x8 zz = {0, 0, 0, 0, 0, 0, 0, 0};

    for (int t = 0; t < 9; ++t) {
        int toff = ((t / 3 - 1) * W + (t % 3 - 1)) * ldin;
        bool v0 = (vmask[0] >> t) & 1u;
        bool v1 = (vmask[1] >> t) & 1u;
        const ushort_t* wp0 = wT + ((size_t)(t * CO + n0 + wc * 32 + fr)) * CI + fo;
        const ushort_t* wp1 = wp0 + (size_t)16 * CI;
#pragma unroll
        for (int kc = 0; kc < CI / 32; ++kc) {
            int k0 = kc * 32;
            bf16x8 a0 = v0 ? *(const bf16x8*)(in + abase[0] + toff + k0) : zz;
            bf16x8 a1 = v1 ? *(const bf16x8*)(in + abase[1] + toff + k0) : zz;
            bf16x8 b0 = *(const bf16x8*)(wp0 + k0);
            bf16x8 b1 = *(const bf16x8*)(wp1 + k0);
            acc[0][0] = __builtin_amdgcn_mfma_f32_16x16x32_bf16(b0, a0, acc[0][0], 0, 0, 0);
            acc[0][1] = __builtin_amdgcn_mfma_f32_16x16x32_bf16(b1, a0, acc[0][1], 0, 0, 0);
            acc[1][0] = __builtin_amdgcn_mfma_f32_16x16x32_bf16(b0, a1, acc[1][0], 0, 0, 0);
            acc[1][1] = __builtin_amdgcn_mfma_f32_16x16x32_bf16(b1, a1, acc[1][1], 0, 0, 0);
        }
    }

#pragma unroll
    for (int mi = 0; mi < 2; ++mi) {
#pragma unroll
        for (int ni = 0; ni < 2; ++ni) {
            int pix = m0 + wr * 32 + mi * 16 + (lane & 15);
            int ch = n0 + wc * 32 + ni * 16 + ((lane >> 4) << 2);
            float4 bv = *(const float4*)(bias + ch);
            float r0 = fmaxf(acc[mi][ni][0] + bv.x, 0.f);
            float r1 = fmaxf(acc[mi][ni][1] + bv.y, 0.f);
            float r2 = fmaxf(acc[mi][ni][2] + bv.z, 0.f);
            float r3 = fmaxf(acc[mi][ni][3] + bv.w, 0.f);
            uint2 pk;
            pk.x = (uint_t)f2bf(r0) | ((uint_t)f2bf(r1) << 16);
            pk.y = (uint_t)f2bf(r2) | ((uint_t)f2bf(r3) << 16);
            *(uint2*)(out + (size_t)pix * ldout + outoff + ch) = pk;
        }
    }
}

// ---------- 2-wave split-tap variant (32x32 tile) for deep low-res layers ----------
template<int CI>
__global__ __launch_bounds__(128) void conv_mfma2w_k(
    const ushort_t* __restrict__ in, int ldin, size_t inImgStride,
    const ushort_t* __restrict__ wT, const float* __restrict__ bias,
    ushort_t* __restrict__ out, int ldout, size_t outImgStride,
    int H, int W, int CO)
{
    __shared__ float red[64][17];
    in += (size_t)blockIdx.z * inImgStride;
    out += (size_t)blockIdx.z * outImgStride;
    const int lane = threadIdx.x & 63;
    const int wv = threadIdx.x >> 6;
    const int m0 = blockIdx.x * 32;
    const int n0 = blockIdx.y * 32;
    const int fr = lane & 15;
    const int fo = (lane >> 4) << 3;

    size_t abase[2];
    unsigned vmask[2];
#pragma unroll
    for (int mi = 0; mi < 2; ++mi) {
        int p = m0 + mi * 16 + fr;
        int y = p / W, x = p % W;
        abase[mi] = (size_t)p * ldin + fo;
        unsigned vm = 0;
#pragma unroll
        for (int t = 0; t < 9; ++t) {
            int dy = t / 3 - 1, dx = t % 3 - 1;
            if ((unsigned)(y + dy) < (unsigned)H && (unsigned)(x + dx) < (unsigned)W) vm |= 1u << t;
        }
        vmask[mi] = vm;
    }

    f32x4 zero = {0.f, 0.f, 0.f, 0.f};
    f32x4 acc[2][2] = {{zero, zero}, {zero, zero}};
    const bf16x8 zz = {0, 0, 0, 0, 0, 0, 0, 0};

    const int tb = wv ? 5 : 0;
    const int te = wv ? 9 : 5;
    for (int t = tb; t < te; ++t) {
        int toff = ((t / 3 - 1) * W + (t % 3 - 1)) * ldin;
        bool v0 = (vmask[0] >> t) & 1u;
        bool v1 = (vmask[1] >> t) & 1u;
        const ushort_t* wp0 = wT + ((size_t)(t * CO + n0 + fr)) * CI + fo;
        const ushort_t* wp1 = wp0 + (size_t)16 * CI;
#pragma unroll
        for (int kc = 0; kc < CI / 32; ++kc) {
            int k0 = kc * 32;
            bf16x8 a0 = v0 ? *(const bf16x8*)(in + abase[0] + toff + k0) : zz;
            bf16x8 a1 = v1 ? *(const bf16x8*)(in + abase[1] + toff + k0) : zz;
            bf16x8 b0 = *(const bf16x8*)(wp0 + k0);
            bf16x8 b1 = *(const bf16x8*)(wp1 + k0);
            acc[0][0] = __builtin_amdgcn_mfma_f32_16x16x32_bf16(b0, a0, acc[0][0], 0, 0, 0);
            acc[0][1] = __builtin_amdgcn_mfma_f32_16x16x32_bf16(b1, a0, acc[0][1], 0, 0, 0);
            acc[1][0] = __builtin_amdgcn_mfma_f32_16x16x32_bf16(b0, a1, acc[1][0], 0, 0, 0);
            acc[1][1] = __builtin_amdgcn_mfma_f32_16x16x32_bf16(b1, a1, acc[1][1], 0, 0, 0);
        }
    }

    if (wv == 1) {
#pragma unroll
        for (int mi = 0; mi < 2; ++mi)
#pragma unroll
            for (int ni = 0; ni < 2; ++ni)
#pragma unroll
                for (int r = 0; r < 4; ++r)
                    red[lane][mi * 8 + ni * 4 + r] = acc[mi][ni][r];
    }
    __syncthreads();
    if (wv == 0) {
#pragma unroll
        for (int mi = 0; mi < 2; ++mi) {
#pragma unroll
            for (int ni = 0; ni < 2; ++ni) {
                int pix = m0 + mi * 16 + (lane & 15);
                int ch = n0 + ni * 16 + ((lane >> 4) << 2);
                float4 bv = *(const float4*)(bias + ch);
                float r0 = fmaxf(acc[mi][ni][0] + red[lane][mi * 8 + ni * 4 + 0] + bv.x, 0.f);
                float r1 = fmaxf(acc[mi][ni][1] + red[lane][mi * 8 + ni * 4 + 1] + bv.y, 0.f);
                float r2 = fmaxf(acc[mi][ni][2] + red[lane][mi * 8 + ni * 4 + 2] + bv.z, 0.f);
                float r3 = fmaxf(acc[mi][ni][3] + red[lane][mi * 8 + ni * 4 + 3] + bv.w, 0.f);
                uint2 pk;
                pk.x = (uint_t)f2bf(r0) | ((uint_t)f2bf(r1) << 16);
                pk.y = (uint_t)f2bf(r2) | ((uint_t)f2bf(r3) << 16);
                *(uint2*)(out + (size_t)pix * ldout + ch) = pk;
            }
        }
    }
}

// ---------- 2x2 maxpool NHWC bf16 (batched via blockIdx.y) ----------
__global__ void maxpool_nhwc_k(const ushort_t* __restrict__ in, ushort_t* __restrict__ out,
                               int C, int Hi, int Wi)
{
    in += (size_t)blockIdx.y * TSTRIDE;
    out += (size_t)blockIdx.y * TSTRIDE;
    int idx = blockIdx.x * 256 + threadIdx.x;
    int CG = C >> 3;
    int Wo = Wi >> 1, Ho = Hi >> 1;
    if (idx >= Ho * Wo * CG) return;
    int cg = idx % CG;
    int p = idx / CG;
    int y = p / Wo, x = p % Wo;
    const ushort_t* ip = in + ((size_t)(2 * y) * Wi + 2 * x) * C + cg * 8;
    bf16x8 v0 = *(const bf16x8*)(ip);
    bf16x8 v1 = *(const bf16x8*)(ip + C);
    bf16x8 v2 = *(const bf16x8*)(ip + (size_t)Wi * C);
    bf16x8 v3 = *(const bf16x8*)(ip + (size_t)Wi * C + C);
    bf16x8 r;
#pragma unroll
    for (int j = 0; j < 8; ++j) {
        float m = fmaxf(fmaxf(bf2f((ushort_t)v0[j]), bf2f((ushort_t)v1[j])),
                        fmaxf(bf2f((ushort_t)v2[j]), bf2f((ushort_t)v3[j])));
        r[j] = (short)f2bf(m);
    }
    *(bf16x8*)(out + (size_t)p * C + cg * 8) = r;
}

// ---------- bicubic weights (align_corners=True), PyTorch A=-0.75 ----------
__device__ inline void cubw(float t, float* w) {
    float x0 = 1.f + t, x2 = 1.f - t, x3 = 2.f - t;
    w[0] = ((-0.75f*x0 + 3.75f)*x0 - 6.f)*x0 + 3.f;
    w[1] = (1.25f*t - 2.25f)*t*t + 1.f;
    w[2] = (1.25f*x2 - 2.25f)*x2*x2 + 1.f;
    w[3] = ((-0.75f*x3 + 3.75f)*x3 - 6.f)*x3 + 3.f;
}

// ---------- fused: bicubic 32->128 + L2 norm; img0 additionally 2x2-mean-pools into Abuf ----------
__global__ __launch_bounds__(256) void upnorm_k(const ushort_t* __restrict__ in, ushort_t* __restrict__ F,
                                                ushort_t* __restrict__ Abuf)
{
    __shared__ float sm[4][320];
    in += (size_t)blockIdx.y * TSTRIDE;
    F += (size_t)blockIdx.y * FSTRIDE;
    int wid = threadIdx.x >> 6, lane = threadIdx.x & 63;
    int pb = blockIdx.x;
    int py = pb >> 6, px = pb & 63;
    int p = (2 * py + (wid >> 1)) * 128 + 2 * px + (wid & 1);
    int Y = p >> 7, X = p & 127;
    float sy = (float)Y * (31.f / 127.f);
    float sx = (float)X * (31.f / 127.f);
    int fy = (int)floorf(sy), fx = (int)floorf(sx);
    float ty = sy - (float)fy, tx = sx - (float)fx;
    float wy[4], wx[4];
    cubw(ty, wy); cubw(tx, wx);
    float a0 = 0.f, a1 = 0.f, a2 = 0.f, a3 = 0.f;
#pragma unroll
    for (int i = 0; i < 4; ++i) {
        int yy = min(max(fy - 1 + i, 0), 31);
#pragma unroll
        for (int j = 0; j < 4; ++j) {
            int xx = min(max(fx - 1 + j, 0), 31);
            float w = wy[i] * wx[j];
            uint2 v = *(const uint2*)(in + ((size_t)yy * 32 + xx) * 256 + lane * 4);
            a0 += w * bflo(v.x); a1 += w * bfhi(v.x);
            a2 += w * bflo(v.y); a3 += w * bfhi(v.y);
        }
    }
    float v0 = bf2f(f2bf(a0)), v1 = bf2f(f2bf(a1)), v2 = bf2f(f2bf(a2)), v3 = bf2f(f2bf(a3));
    float c0 = bf2f(F[(size_t)p * 320 + lane]);
    float ss = c0 * c0 + v0 * v0 + v1 * v1 + v2 * v2 + v3 * v3;
#pragma unroll
    for (int off = 32; off > 0; off >>= 1) ss += __shfl_xor(ss, off);
    float inv = 1.f / (1e-8f + sqrtf(ss));
    if (blockIdx.y == 1) {
        F[(size_t)p * 320 + lane] = f2bf(c0 * inv);
        uint2 pk;
        pk.x = (uint_t)f2bf(v0 * inv) | ((uint_t)f2bf(v1 * inv) << 16);
        pk.y = (uint_t)f2bf(v2 * inv) | ((uint_t)f2bf(v3 * inv) << 16);
        *(uint2*)(F + (size_t)p * 320 + 64 + lane * 4) = pk;
    } else {
        sm[wid][lane] = bf2f(f2bf(c0 * inv));
        sm[wid][64 + lane * 4 + 0] = bf2f(f2bf(v0 * inv));
        sm[wid][64 + lane * 4 + 1] = bf2f(f2bf(v1 * inv));
        sm[wid][64 + lane * 4 + 2] = bf2f(f2bf(v2 * inv));
        sm[wid][64 + lane * 4 + 3] = bf2f(f2bf(v3 * inv));
        __syncthreads();
        for (int ch = threadIdx.x; ch < 320; ch += 256) {
            float a = 0.25f * (sm[0][ch] + sm[1][ch] + sm[2][ch] + sm[3][ch]);
            Abuf[(size_t)pb * 320 + ch] = f2bf(a);
        }
    }
}

// ---------- correlation GEMM + fused softmax-denominator partials ----------
// r10 named ping-pong structure (best measured). Grid m-fastest: consecutive
// blocks share the B-tile -> B L2-resident per XCD; whole A L2-resident.
__global__ __launch_bounds__(256) void gemm_corr_k(
    const ushort_t* __restrict__ A, const ushort_t* __restrict__ B, char* __restrict__ D8,
    const float* __restrict__ coefr, const float* __restrict__ coeft,
    float* __restrict__ rpsum, float* __restrict__ cpsum)
{
    __shared__ ushort_t lA[128 * 32];
    __shared__ ushort_t lB[128 * 32];
    __shared__ float cl[2][128];
    __shared__ float rl[2][128];
    const int tid = threadIdx.x;
    const int lane = tid & 63;
    const int wid = tid >> 6;
    const int wr = wid >> 1, wc = wid & 1;
    const int m0 = blockIdx.x * 128, n0 = blockIdx.y * 128;   // m-fastest
    const int fr = lane & 15;
    const int fo = (lane >> 4) << 3;
    const int srow = tid >> 2;
    const int scol = (tid & 3) << 3;

    const ushort_t* Ag0 = A + (size_t)(m0 + srow) * 320 + scol;
    const ushort_t* Ag1 = Ag0 + (size_t)64 * 320;
    const ushort_t* Bg0 = B + (size_t)(n0 + srow) * 320 + scol;
    const ushort_t* Bg1 = Bg0 + (size_t)64 * 320;

    f32x4 zero = {0.f, 0.f, 0.f, 0.f};
    f32x4 acc[4][4];
#pragma unroll
    for (int i = 0; i < 4; ++i)
#pragma unroll
        for (int j = 0; j < 4; ++j) acc[i][j] = zero;

    uint4 pA0, pA1, pB0, pB1;
    uint4 qA0, qA1, qB0, qB1;
    pA0 = *(const uint4*)(Ag0);
    pA1 = *(const uint4*)(Ag1);
    pB0 = *(const uint4*)(Bg0);
    pB1 = *(const uint4*)(Bg1);

#define DSWRITE(rA0, rA1, rB0, rB1) { \
        *(uint4*)&lA[srow * 32 + scol] = rA0; \
        *(uint4*)&lA[(64 + srow) * 32 + scol] = rA1; \
        *(uint4*)&lB[srow * 32 + scol] = rB0; \
        *(uint4*)&lB[(64 + srow) * 32 + scol] = rB1; }

#define GLOAD(rA0, rA1, rB0, rB1, kk) { \
        rA0 = *(const uint4*)(Ag0 + (kk)); \
        rA1 = *(const uint4*)(Ag1 + (kk)); \
        rB0 = *(const uint4*)(Bg0 + (kk)); \
        rB1 = *(const uint4*)(Bg1 + (kk)); }

#define COMPUTE() { \
        bf16x8 af[4], bfr[4]; \
        _Pragma("unroll") \
        for (int mi = 0; mi < 4; ++mi) \
            af[mi] = *(const bf16x8*)&lA[(wr * 64 + mi * 16 + fr) * 32 + fo]; \
        _Pragma("unroll") \
        for (int ni = 0; ni < 4; ++ni) \
            bfr[ni] = *(const bf16x8*)&lB[(wc * 64 + ni * 16 + fr) * 32 + fo]; \
        _Pragma("unroll") \
        for (int mi = 0; mi < 4; ++mi) \
            _Pragma("unroll") \
            for (int ni = 0; ni < 4; ++ni) \
                acc[mi][ni] = __builtin_amdgcn_mfma_f32_16x16x32_bf16(bfr[ni], af[mi], acc[mi][ni], 0, 0, 0); }

#pragma unroll
    for (int tt = 0; tt < 5; ++tt) {
        __syncthreads();
        DSWRITE(pA0, pA1, pB0, pB1)
        GLOAD(qA0, qA1, qB0, qB1, 32 * (2 * tt + 1))
        __syncthreads();
        COMPUTE()
        __syncthreads();
        DSWRITE(qA0, qA1, qB0, qB1)
        if (tt < 4) { GLOAD(pA0, pA1, pB0, pB1, 32 * (2 * tt + 2)) }
        __syncthreads();
        COMPUTE()
    }
#undef DSWRITE
#undef GLOAD
#undef COMPUTE

    const float s = 1.0f / 320.0f;
    const float cr = coefr[0], ct = coeft[0];
    const bool sameCoef = (cr == ct);
    float rpx[4] = {0.f, 0.f, 0.f, 0.f};
    float cpx[4][4];
#pragma unroll
    for (int ni = 0; ni < 4; ++ni)
#pragma unroll
        for (int r = 0; r < 4; ++r) cpx[ni][r] = 0.f;

    const int mrow = lane & 15;
    const int ng = (lane >> 4) << 2;
#pragma unroll
    for (int mi = 0; mi < 4; ++mi) {
        int m = m0 + wr * 64 + mi * 16 + mrow;
        char* drow = D8 + (size_t)m * 16384;
#pragma unroll
        for (int ni = 0; ni < 4; ++ni) {
            int n = n0 + wc * 64 + ni * 16 + ng;
            float d0 = acc[mi][ni][0] * s;
            float d1 = acc[mi][ni][1] * s;
            float d2 = acc[mi][ni][2] * s;
            float d3 = acc[mi][ni][3] * s;
            int q0 = __float2int_rn(fminf(fmaxf(d0 * 40640.f, -127.f), 127.f));
            int q1 = __float2int_rn(fminf(fmaxf(d1 * 40640.f, -127.f), 127.f));
            int q2 = __float2int_rn(fminf(fmaxf(d2 * 40640.f, -127.f), 127.f));
            int q3 = __float2int_rn(fminf(fmaxf(d3 * 40640.f, -127.f), 127.f));
            uint_t pk8 = (uint_t)(q0 & 255) | ((uint_t)(q1 & 255) << 8)
                       | ((uint_t)(q2 & 255) << 16) | ((uint_t)(q3 & 255) << 24);
            *(uint_t*)(drow + n) = pk8;
            float e0 = __expf(cr * d0), e1 = __expf(cr * d1);
            float e2 = __expf(cr * d2), e3 = __expf(cr * d3);
            cpx[ni][0] += e0; cpx[ni][1] += e1; cpx[ni][2] += e2; cpx[ni][3] += e3;
            if (sameCoef) {
                rpx[mi] += e0 + e1 + e2 + e3;
            } else {
                rpx[mi] += __expf(ct * d0) + __expf(ct * d1) + __expf(ct * d2) + __expf(ct * d3);
            }
        }
    }
#pragma unroll
    for (int mi = 0; mi < 4; ++mi) {
        rpx[mi] += __shfl_xor(rpx[mi], 16);
        rpx[mi] += __shfl_xor(rpx[mi], 32);
    }
    if (lane < 16) {
#pragma unroll
        for (int mi = 0; mi < 4; ++mi)
            rl[wc][wr * 64 + mi * 16 + lane] = rpx[mi];
    }
#pragma unroll
    for (int ni = 0; ni < 4; ++ni)
#pragma unroll
        for (int r = 0; r < 4; ++r) {
            cpx[ni][r] += __shfl_xor(cpx[ni][r], 1);
            cpx[ni][r] += __shfl_xor(cpx[ni][r], 2);
            cpx[ni][r] += __shfl_xor(cpx[ni][r], 4);
            cpx[ni][r] += __shfl_xor(cpx[ni][r], 8);
        }
    if ((lane & 15) == 0) {
        int g = lane >> 4;
#pragma unroll
        for (int ni = 0; ni < 4; ++ni)
#pragma unroll
            for (int r = 0; r < 4; ++r)
                cl[wr][wc * 64 + ni * 16 + g * 4 + r] = cpx[ni][r];
    }
    __syncthreads();
    if (tid < 128) {
        cpsum[(size_t)blockIdx.x * 16384 + n0 + tid] = cl[0][tid] + cl[1][tid];
        rpsum[(size_t)blockIdx.y * 4096 + m0 + tid] = rl[0][tid] + rl[1][tid];
    }
}

// ---------- fused finalize: lc[j] = -0.5*log(colsum); invr[m] = rsqrt(rowsum) ----------
__global__ void finboth_k(const float* __restrict__ cpsum, const float* __restrict__ rpsum,
                          float* __restrict__ lc, float* __restrict__ invr)
{
    int b = blockIdx.x;
    if (b < 64) {
        int j = b * 256 + threadIdx.x;
        float s = 0.f;
#pragma unroll
        for (int k = 0; k < 32; ++k) s += cpsum[(size_t)k * 16384 + j];
        lc[j] = -0.5f * __logf(s);
    } else {
        int m = (b - 64) * 256 + threadIdx.x;
        float s = 0.f;
#pragma unroll
        for (int k = 0; k < 128; ++k) s += rpsum[(size_t)k * 4096 + m];
        invr[m] = rsqrtf(s);
    }
}

// ---------- per-row top-5 on int8 dist, key space, early reject (one wave/row) ----------
#define INS5(w_) { float w = (w_); float mx; \
    mx = fmaxf(w, t0); w = fminf(w, t0); t0 = mx; \
    mx = fmaxf(w, t1); w = fminf(w, t1); t1 = mx; \
    mx = fmaxf(w, t2); w = fminf(w, t2); t2 = mx; \
    mx = fmaxf(w, t3); w = fminf(w, t3); t3 = mx; \
    t4 = fmaxf(w, t4); }
#define SB(w, sft) ((float)(int)(signed char)(((w) >> (sft)) & 0xffu))

__global__ __launch_bounds__(256) void row_topk_k(
    const char* __restrict__ D8, const float* __restrict__ lc,
    const float* __restrict__ invr,
    const float* __restrict__ coefr, const float* __restrict__ coeft,
    float* __restrict__ conf5)
{
    int wid = threadIdx.x >> 6, lane = threadIdx.x & 63;
    int row = blockIdx.x * 4 + wid;
    float hc = 0.5f * (coefr[0] + coeft[0]);
    float hq = hc * (1.0f / 40640.f);
    const char* rp = D8 + (size_t)row * 16384;

    float t0 = -1e30f, t1 = -1e30f, t2 = -1e30f, t3 = -1e30f, t4 = -1e30f;
    for (int i = 0; i < 16; ++i) {
        int cw = i * 64 + lane;
        uint4 u = *(const uint4*)(rp + cw * 16);
        int col = cw * 16;
        float4 l0 = *(const float4*)(lc + col);
        float4 l1 = *(const float4*)(lc + col + 4);
        float4 l2 = *(const float4*)(lc + col + 8);
        float4 l3 = *(const float4*)(lc + col + 12);
        float k0  = fmaf(hq, SB(u.x, 0),  l0.x);
        float k1  = fmaf(hq, SB(u.x, 8),  l0.y);
        float k2  = fmaf(hq, SB(u.x, 16), l0.z);
        float k3  = fmaf(hq, SB(u.x, 24), l0.w);
        float k4  = fmaf(hq, SB(u.y, 0),  l1.x);
        float k5  = fmaf(hq, SB(u.y, 8),  l1.y);
        float k6  = fmaf(hq, SB(u.y, 16), l1.z);
        float k7  = fmaf(hq, SB(u.y, 24), l1.w);
        float k8  = fmaf(hq, SB(u.z, 0),  l2.x);
        float k9  = fmaf(hq, SB(u.z, 8),  l2.y);
        float k10 = fmaf(hq, SB(u.z, 16), l2.z);
        float k11 = fmaf(hq, SB(u.z, 24), l2.w);
        float k12 = fmaf(hq, SB(u.w, 0),  l3.x);
        float k13 = fmaf(hq, SB(u.w, 8),  l3.y);
        float k14 = fmaf(hq, SB(u.w, 16), l3.z);
        float k15 = fmaf(hq, SB(u.w, 24), l3.w);
        float ma = fmaxf(fmaxf(fmaxf(k0, k1), fmaxf(k2, k3)),
                         fmaxf(fmaxf(k4, k5), fmaxf(k6, k7)));
        float mb = fmaxf(fmaxf(fmaxf(k8, k9), fmaxf(k10, k11)),
                         fmaxf(fmaxf(k12, k13), fmaxf(k14, k15)));
        if (fmaxf(ma, mb) > t4) {
            INS5(k0);  INS5(k1);  INS5(k2);  INS5(k3);
            INS5(k4);  INS5(k5);  INS5(k6);  INS5(k7);
            INS5(k8);  INS5(k9);  INS5(k10); INS5(k11);
            INS5(k12); INS5(k13); INS5(k14); INS5(k15);
        }
    }
#pragma unroll
    for (int off = 1; off < 64; off <<= 1) {
        float o0 = __shfl_xor(t0, off), o1 = __shfl_xor(t1, off), o2 = __shfl_xor(t2, off);
        float o3 = __shfl_xor(t3, off), o4 = __shfl_xor(t4, off);
        INS5(o0); INS5(o1); INS5(o2); INS5(o3); INS5(o4);
    }
    if (lane == 0) {
        float iv = invr[row];
        conf5[0 * 4096 + row] = __expf(t0) * iv;
        conf5[1 * 4096 + row] = __expf(t1) * iv;
        conf5[2 * 4096 + row] = __expf(t2) * iv;
        conf5[3 * 4096 + row] = __expf(t3) * iv;
        conf5[4 * 4096 + row] = __expf(t4) * iv;
    }
}

// ---------- fp32 3x3 conv (head conv1, NCHW) ----------
__global__ void conv3x3_k(const float* __restrict__ in, const float* __restrict__ wgt,
                          const float* __restrict__ bias, float* __restrict__ out,
                          int Cin, int H, int W, int relu)
{
    int p = blockIdx.x * 256 + threadIdx.x;
    int HW = H * W;
    if (p >= HW) return;
    int co0 = blockIdx.y * 8;
    int y = p / W, x = p - y * W;
    float acc0 = bias[co0+0], acc1 = bias[co0+1], acc2 = bias[co0+2], acc3 = bias[co0+3];
    float acc4 = bias[co0+4], acc5 = bias[co0+5], acc6 = bias[co0+6], acc7 = bias[co0+7];
    bool ym = y > 0, yp = y < H-1, xm = x > 0, xp = x < W-1;
    for (int ci = 0; ci < Cin; ++ci) {
        const float* ip = in + (size_t)ci * HW + p;
        float v0 = (ym && xm) ? ip[-W-1] : 0.f;
        float v1 = (ym)       ? ip[-W]   : 0.f;
        float v2 = (ym && xp) ? ip[-W+1] : 0.f;
        float v3 = (xm)       ? ip[-1]   : 0.f;
        float v4 =              ip[0];
        float v5 = (xp)       ? ip[1]    : 0.f;
        float v6 = (yp && xm) ? ip[W-1]  : 0.f;
        float v7 = (yp)       ? ip[W]    : 0.f;
        float v8 = (yp && xp) ? ip[W+1]  : 0.f;
        const float* wp = wgt + ((size_t)co0 * Cin + ci) * 9;
        size_t ws = (size_t)Cin * 9;
#define CACC(q, a) { const float* wq = wp + q * ws; \
        a += wq[0]*v0 + wq[1]*v1 + wq[2]*v2 + wq[3]*v3 + wq[4]*v4 \
           + wq[5]*v5 + wq[6]*v6 + wq[7]*v7 + wq[8]*v8; }
        CACC(0, acc0) CACC(1, acc1) CACC(2, acc2) CACC(3, acc3)
        CACC(4, acc4) CACC(5, acc5) CACC(6, acc6) CACC(7, acc7)
#undef CACC
    }
#define CW(q, a) { float r = a; if (relu) r = fmaxf(r, 0.f); out[(size_t)(co0+q)*HW + p] = r; }
    CW(0, acc0) CW(1, acc1) CW(2, acc2) CW(3, acc3)
    CW(4, acc4) CW(5, acc5) CW(6, acc6) CW(7, acc7)
#undef CW
}

// ---------- head conv2 (8->8, relu) fused with 1x1 (8->1) ----------
__global__ void head2_k(const float* __restrict__ in, const float* __restrict__ wgt,
                        const float* __restrict__ bias, const float* __restrict__ w3,
                        const float* __restrict__ b3, float* __restrict__ out64)
{
    int p = blockIdx.x * 256 + threadIdx.x;
    int y = p >> 6, x = p & 63;
    float acc[8];
#pragma unroll
    for (int c = 0; c < 8; ++c) acc[c] = bias[c];
    bool ym = y > 0, yp = y < 63, xm = x > 0, xp = x < 63;
#pragma unroll
    for (int ci = 0; ci < 8; ++ci) {
        const float* ip = in + ci * 4096 + p;
        float v0 = (ym && xm) ? ip[-65] : 0.f;
        float v1 = (ym)       ? ip[-64] : 0.f;
        float v2 = (ym && xp) ? ip[-63] : 0.f;
        float v3 = (xm)       ? ip[-1]  : 0.f;
        float v4 =              ip[0];
        float v5 = (xp)       ? ip[1]   : 0.f;
        float v6 = (yp && xm) ? ip[63]  : 0.f;
        float v7 = (yp)       ? ip[64]  : 0.f;
        float v8 = (yp && xp) ? ip[65]  : 0.f;
#pragma unroll
        for (int co = 0; co < 8; ++co) {
            const float* wq = wgt + ((size_t)co * 8 + ci) * 9;
            acc[co] += wq[0]*v0 + wq[1]*v1 + wq[2]*v2 + wq[3]*v3 + wq[4]*v4
                     + wq[5]*v5 + wq[6]*v6 + wq[7]*v7 + wq[8]*v8;
        }
    }
    float o = b3[0];
#pragma unroll
    for (int c = 0; c < 8; ++c) o += w3[c] * fmaxf(acc[c], 0.f);
    out64[p] = o;
}

// ---------- fp32 bicubic (final output) ----------
__global__ void bicubic_k(const float* __restrict__ in, float* __restrict__ out,
                          int C, int Hin, int Win, int Hout, int Wout)
{
    int idx = blockIdx.x * 256 + threadIdx.x;
    int total = C * Hout * Wout;
    if (idx >= total) return;
    int X = idx % Wout;
    int Y = (idx / Wout) % Hout;
    int c = idx / (Wout * Hout);
    float sy = (float)Y * (float)(Hin - 1) / (float)(Hout - 1);
    float sx = (float)X * (float)(Win - 1) / (float)(Wout - 1);
    int fy = (int)floorf(sy), fx = (int)floorf(sx);
    float ty = sy - (float)fy, tx = sx - (float)fx;
    float wy[4], wx[4];
    cubw(ty, wy); cubw(tx, wx);
    const float* ip = in + (size_t)c * Hin * Win;
    float acc = 0.f;
#pragma unroll
    for (int i = 0; i < 4; ++i) {
        int yy = min(max(fy - 1 + i, 0), Hin - 1);
        float ra = 0.f;
#pragma unroll
        for (int j = 0; j < 4; ++j) {
            int xx = min(max(fx - 1 + j, 0), Win - 1);
            ra += wx[j] * ip[yy * Win + xx];
        }
        acc += wy[i] * ra;
    }
    out[idx] = acc;
}

// ---------- host ----------
extern "C" void kernel_launch(void* const* d_in, const int* in_sizes, int n_in,
                              void* d_out, int out_size, void* d_ws, size_t ws_size,
                              hipStream_t stream)
{
    const float* x_ref = (const float*)d_in[0];
    const float* x_tem = (const float*)d_in[1];
    const float* w0  = (const float*)d_in[2];   const float* b0  = (const float*)d_in[3];
    const float* w2  = (const float*)d_in[4];   const float* b2  = (const float*)d_in[5];
    const float* w5  = (const float*)d_in[6];   const float* b5  = (const float*)d_in[7];
    const float* w7  = (const float*)d_in[8];   const float* b7  = (const float*)d_in[9];
    const float* w10 = (const float*)d_in[10];  const float* b10 = (const float*)d_in[11];
    const float* w12 = (const float*)d_in[12];  const float* b12 = (const float*)d_in[13];
    const float* w14 = (const float*)d_in[14];  const float* b14 = (const float*)d_in[15];
    const float* coefr = (const float*)d_in[16];
    const float* coeft = (const float*)d_in[17];
    const float* fw1 = (const float*)d_in[18];  const float* fb1 = (const float*)d_in[19];
    const float* fw2 = (const float*)d_in[20];  const float* fb2 = (const float*)d_in[21];
    const float* fw3 = (const float*)d_in[22];  const float* fb3 = (const float*)d_in[23];
    float* out = (float*)d_out;

    char* wsp = (char*)d_ws;
    auto alloc = [&](size_t bytes) { char* p = wsp; wsp += (bytes + 255) & ~(size_t)255; return p; };
    ushort_t* F     = (ushort_t*)alloc(2 * FSTRIDE * 2);
    ushort_t* t0    = (ushort_t*)alloc(2 * TSTRIDE * 2);
    ushort_t* t1    = (ushort_t*)alloc(2 * TSTRIDE * 2);
    ushort_t* t2    = (ushort_t*)alloc(2 * TSTRIDE * 2);
    ushort_t* wT2   = (ushort_t*)alloc((size_t)64 * 64 * 9 * 2);
    ushort_t* wT5   = (ushort_t*)alloc((size_t)128 * 64 * 9 * 2);
    ushort_t* wT7   = (ushort_t*)alloc((size_t)128 * 128 * 9 * 2);
    ushort_t* wT10  = (ushort_t*)alloc((size_t)256 * 128 * 9 * 2);
    ushort_t* wT12  = (ushort_t*)alloc((size_t)256 * 256 * 9 * 2);
    ushort_t* wT14  = (ushort_t*)alloc((size_t)256 * 256 * 9 * 2);
    ushort_t* Abuf  = (ushort_t*)alloc((size_t)4096 * 320 * 2);
    char*     dist8 = (char*)alloc((size_t)4096 * 16384);
    float*    rpsum = (float*)alloc((size_t)128 * 4096 * 4);
    float*    cpsum = (float*)alloc((size_t)32 * 16384 * 4);
    float*    lc    = (float*)alloc(16384 * 4);
    float*    invr  = (float*)alloc(4096 * 4);
    float*    conf5 = (float*)alloc(5 * 4096 * 4);
    float*    h1    = (float*)alloc(8 * 4096 * 4);
    float*    out64 = (float*)alloc(4096 * 4);
    (void)ws_size; (void)n_in; (void)in_sizes; (void)out_size;

    // fused weight transforms
    WT6 wt;
    wt.src[0] = w2;  wt.dst[0] = wT2;  wt.co[0] = 64;  wt.ci[0] = 64;
    wt.src[1] = w5;  wt.dst[1] = wT5;  wt.co[1] = 128; wt.ci[1] = 64;
    wt.src[2] = w7;  wt.dst[2] = wT7;  wt.co[2] = 128; wt.ci[2] = 128;
    wt.src[3] = w10; wt.dst[3] = wT10; wt.co[3] = 256; wt.ci[3] = 128;
    wt.src[4] = w12; wt.dst[4] = wT12; wt.co[4] = 256; wt.ci[4] = 256;
    wt.src[5] = w14; wt.dst[5] = wT14; wt.co[5] = 256; wt.ci[5] = 256;
    int nblk = 0;
    for (int s = 0; s < 6; ++s) { wt.off[s] = nblk; nblk += (wt.co[s] * wt.ci[s] * 9 + 255) / 256; }
    wtrans6_k<<<nblk, 256, 0, stream>>>(wt);

    // batched feature extraction
    conv0_k<<<dim3(4096, 2), 256, 0, stream>>>(x_ref, x_tem, w0, b0, F, t0);
    conv_mfma_k<64><<<dim3(256, 1, 2), 256, 0, stream>>>(t0, 64, 0, TSTRIDE, wT2, b2, t1, 64, 0, TSTRIDE, 128, 128, 64);
    maxpool_nhwc_k<<<dim3(128, 2), 256, 0, stream>>>(t1, t2, 64, 128, 128);
    conv_mfma_k<64><<<dim3(64, 2, 2), 256, 0, stream>>>(t2, 64, 0, TSTRIDE, wT5, b5, t1, 128, 0, TSTRIDE, 64, 64, 128);
    conv_mfma_k<128><<<dim3(64, 2, 2), 256, 0, stream>>>(t1, 128, 0, TSTRIDE, wT7, b7, t2, 128, 0, TSTRIDE, 64, 64, 128);
    maxpool_nhwc_k<<<dim3(64, 2), 256, 0, stream>>>(t2, t1, 128, 64, 64);
    conv_mfma2w_k<128><<<dim3(32, 8, 2), 128, 0, stream>>>(t1, 128, TSTRIDE, wT10, b10, t2, 256, TSTRIDE, 32, 32, 256);
    conv_mfma2w_k<256><<<dim3(32, 8, 2), 128, 0, stream>>>(t2, 256, TSTRIDE, wT12, b12, t1, 256, TSTRIDE, 32, 32, 256);
    conv_mfma2w_k<256><<<dim3(32, 8, 2), 128, 0, stream>>>(t1, 256, TSTRIDE, wT14, b14, t2, 256, TSTRIDE, 32, 32, 256);
    upnorm_k<<<dim3(4096, 2), 256, 0, stream>>>(t2, F, Abuf);

    // m-fastest grid: x = m-block (32), y = n-block (128)
    gemm_corr_k<<<dim3(32, 128), 256, 0, stream>>>(Abuf, F + FSTRIDE, dist8, coefr, coeft, rpsum, cpsum);

    finboth_k<<<80, 256, 0, stream>>>(cpsum, rpsum, lc, invr);

    row_topk_k<<<1024, 256, 0, stream>>>(dist8, lc, invr, coefr, coeft, conf5);

    conv3x3_k<<<dim3(16, 1), 256, 0, stream>>>(conf5, fw1, fb1, h1, 5, 64, 64, 1);
    head2_k<<<16, 256, 0, stream>>>(h1, fw2, fb2, fw3, fb3, out64);
    bicubic_k<<<64, 256, 0, stream>>>(out64, out, 1, 64, 64, 128, 128);
}

// Round 14
// 380.957 us; speedup vs baseline: 1.0512x; 1.0019x over previous
//
#include <hip/hip_runtime.h>
#include <math.h>

typedef unsigned short ushort_t;
typedef unsigned int uint_t;
typedef __attribute__((ext_vector_type(8))) short bf16x8;
typedef __attribute__((ext_vector_type(4))) float f32x4;

#define FSTRIDE ((size_t)16384 * 320)
#define TSTRIDE ((size_t)16384 * 64)

// ---------- bf16 helpers ----------
__device__ inline ushort_t f2bf(float f) {
    union { float f; uint_t u; } x; x.f = f;
    uint_t r = x.u + 0x7fffu + ((x.u >> 16) & 1u);
    return (ushort_t)(r >> 16);
}
__device__ inline float bf2f(ushort_t h) {
    union { uint_t u; float f; } x; x.u = ((uint_t)h) << 16;
    return x.f;
}
__device__ inline float bflo(uint_t u) {
    union { uint_t u; float f; } x; x.u = u << 16; return x.f;
}
__device__ inline float bfhi(uint_t u) {
    union { uint_t u; float f; } x; x.u = u & 0xffff0000u; return x.f;
}

// ---------- fused weight transform: 6 conv layers, OIHW fp32 -> [tap][co][ci] bf16 ----------
struct WT6 {
    const float* src[6];
    ushort_t* dst[6];
    int co[6], ci[6];
    int off[6];
};
__global__ void wtrans6_k(WT6 a)
{
    int b = blockIdx.x, seg = 0;
#pragma unroll
    for (int s = 1; s < 6; ++s) if (b >= a.off[s]) seg = s;
    int idx = (b - a.off[seg]) * 256 + threadIdx.x;
    int CO = a.co[seg], CI = a.ci[seg];
    if (idx >= CO * CI * 9) return;
    int tap = idx % 9;
    int rem = idx / 9;
    int ci = rem % CI;
    int co = rem / CI;
    a.dst[seg][((size_t)tap * CO + co) * CI + ci] = f2bf(a.src[seg][idx]);
}

// ---------- conv0: 3->64 @128x128, NCHW fp32 in; writes F cols 0..63 AND compact t0 ----------
__global__ __launch_bounds__(256) void conv0_k(const float* __restrict__ x0, const float* __restrict__ x1,
                                               const float* __restrict__ w,
                                               const float* __restrict__ b, ushort_t* __restrict__ F,
                                               ushort_t* __restrict__ t0)
{
    const float* x = blockIdx.y ? x1 : x0;
    F += (size_t)blockIdx.y * FSTRIDE;
    t0 += (size_t)blockIdx.y * TSTRIDE;
    int co = threadIdx.x & 63;
    int p = blockIdx.x * 4 + (threadIdx.x >> 6);
    int y = p >> 7, xx = p & 127;
    float acc = b[co];
#pragma unroll
    for (int ci = 0; ci < 3; ++ci) {
#pragma unroll
        for (int t = 0; t < 9; ++t) {
            int dy = t / 3 - 1, dx = t % 3 - 1;
            int yy = y + dy, xc = xx + dx;
            if ((unsigned)yy < 128u && (unsigned)xc < 128u) {
                acc += x[ci * 16384 + yy * 128 + xc] * w[co * 27 + ci * 9 + t];
            }
        }
    }
    ushort_t r = f2bf(fmaxf(acc, 0.f));
    F[(size_t)p * 320 + co] = r;
    t0[(size_t)p * 64 + co] = r;
}

// ---------- implicit-GEMM MFMA conv 3x3 pad=1: NHWC bf16, relu (4-wave, batched) ----------
template<int CI>
__global__ __launch_bounds__(256) void conv_mfma_k(
    const ushort_t* __restrict__ in, int ldin, int inoff, size_t inImgStride,
    const ushort_t* __restrict__ wT, const float* __restrict__ bias,
    ushort_t* __restrict__ out, int ldout, int outoff, size_t outImgStride,
    int H, int W, int CO)
{
    in += (size_t)blockIdx.z * inImgStride;
    out += (size_t)blockIdx.z * outImgStride;
    const int tid = threadIdx.x;
    const int lane = tid & 63, wid = tid >> 6;
    const int wr = wid >> 1, wc = wid & 1;
    const int m0 = blockIdx.x * 64;
    const int n0 = blockIdx.y * 64;
    const int fr = lane & 15;
    const int fo = (lane >> 4) << 3;

    size_t abase[2];
    unsigned vmask[2];
#pragma unroll
    for (int mi = 0; mi < 2; ++mi) {
        int p = m0 + wr * 32 + mi * 16 + fr;
        int y = p / W, x = p % W;
        abase[mi] = (size_t)p * ldin + inoff + fo;
        unsigned vm = 0;
#pragma unroll
        for (int t = 0; t < 9; ++t) {
            int dy = t / 3 - 1, dx = t % 3 - 1;
            if ((unsigned)(y + dy) < (unsigned)H && (unsigned)(x + dx) < (unsigned)W) vm |= 1u << t;
        }
        vmask[mi] = vm;
    }

    f32x4 zero = {0.f, 0.f, 0.f, 0.f};
    f32x4 acc[2][2] = {{zero, zero}, {zero, zero}};
    const bf16x8 zz = {0, 0, 0, 0, 0, 0, 0, 0};

    for (int t = 0; t < 9; ++t) {
        int toff = ((t / 3 - 1) * W + (t % 3 - 1)) * ldin;
        bool v0 = (vmask[0] >> t) & 1u;
        bool v1 = (vmask[1] >> t) & 1u;
        const ushort_t* wp0 = wT + ((size_t)(t * CO + n0 + wc * 32 + fr)) * CI + fo;
        const ushort_t* wp1 = wp0 + (size_t)16 * CI;
#pragma unroll
        for (int kc = 0; kc < CI / 32; ++kc) {
            int k0 = kc * 32;
            bf16x8 a0 = v0 ? *(const bf16x8*)(in + abase[0] + toff + k0) : zz;
            bf16x8 a1 = v1 ? *(const bf16x8*)(in + abase[1] + toff + k0) : zz;
            bf16x8 b0 = *(const bf16x8*)(wp0 + k0);
            bf16x8 b1 = *(const bf16x8*)(wp1 + k0);
            acc[0][0] = __builtin_amdgcn_mfma_f32_16x16x32_bf16(b0, a0, acc[0][0], 0, 0, 0);
            acc[0][1] = __builtin_amdgcn_mfma_f32_16x16x32_bf16(b1, a0, acc[0][1], 0, 0, 0);
            acc[1][0] = __builtin_amdgcn_mfma_f32_16x16x32_bf16(b0, a1, acc[1][0], 0, 0, 0);
            acc[1][1] = __builtin_amdgcn_mfma_f32_16x16x32_bf16(b1, a1, acc[1][1], 0, 0, 0);
        }
    }

#pragma unroll
    for (int mi = 0; mi < 2; ++mi) {
#pragma unroll
        for (int ni = 0; ni < 2; ++ni) {
            int pix = m0 + wr * 32 + mi * 16 + (lane & 15);
            int ch = n0 + wc * 32 + ni * 16 + ((lane >> 4) << 2);
            float4 bv = *(const float4*)(bias + ch);
            float r0 = fmaxf(acc[mi][ni][0] + bv.x, 0.f);
            float r1 = fmaxf(acc[mi][ni][1] + bv.y, 0.f);
            float r2 = fmaxf(acc[mi][ni][2] + bv.z, 0.f);
            float r3 = fmaxf(acc[mi][ni][3] + bv.w, 0.f);
            uint2 pk;
            pk.x = (uint_t)f2bf(r0) | ((uint_t)f2bf(r1) << 16);
            pk.y = (uint_t)f2bf(r2) | ((uint_t)f2bf(r3) << 16);
            *(uint2*)(out + (size_t)pix * ldout + outoff + ch) = pk;
        }
    }
}

// ---------- 2-wave split-tap variant (32x32 tile) for deep low-res layers ----------
template<int CI>
__global__ __launch_bounds__(128) void conv_mfma2w_k(
    const ushort_t* __restrict__ in, int ldin, size_t inImgStride,
    const ushort_t* __restrict__ wT, const float* __restrict__ bias,
    ushort_t* __restrict__ out, int ldout, size_t outImgStride,
    int H, int W, int CO)
{
    __shared__ float red[64][17];
    in += (size_t)blockIdx.z * inImgStride;
    out += (size_t)blockIdx.z * outImgStride;
    const int lane = threadIdx.x & 63;
    const int wv = threadIdx.x >> 6;
    const int m0 = blockIdx.x * 32;
    const int n0 = blockIdx.y * 32;
    const int fr = lane & 15;
    const int fo = (lane >> 4) << 3;

    size_t abase[2];
    unsigned vmask[2];
#pragma unroll
    for (int mi = 0; mi < 2; ++mi) {
        int p = m0 + mi * 16 + fr;
        int y = p / W, x = p % W;
        abase[mi] = (size_t)p * ldin + fo;
        unsigned vm = 0;
#pragma unroll
        for (int t = 0; t < 9; ++t) {
            int dy = t / 3 - 1, dx = t % 3 - 1;
            if ((unsigned)(y + dy) < (unsigned)H && (unsigned)(x + dx) < (unsigned)W) vm |= 1u << t;
        }
        vmask[mi] = vm;
    }

    f32x4 zero = {0.f, 0.f, 0.f, 0.f};
    f32x4 acc[2][2] = {{zero, zero}, {zero, zero}};
    const bf16x8 zz = {0, 0, 0, 0, 0, 0, 0, 0};

    const int tb = wv ? 5 : 0;
    const int te = wv ? 9 : 5;
    for (int t = tb; t < te; ++t) {
        int toff = ((t / 3 - 1) * W + (t % 3 - 1)) * ldin;
        bool v0 = (vmask[0] >> t) & 1u;
        bool v1 = (vmask[1] >> t) & 1u;
        const ushort_t* wp0 = wT + ((size_t)(t * CO + n0 + fr)) * CI + fo;
        const ushort_t* wp1 = wp0 + (size_t)16 * CI;
#pragma unroll
        for (int kc = 0; kc < CI / 32; ++kc) {
            int k0 = kc * 32;
            bf16x8 a0 = v0 ? *(const bf16x8*)(in + abase[0] + toff + k0) : zz;
            bf16x8 a1 = v1 ? *(const bf16x8*)(in + abase[1] + toff + k0) : zz;
            bf16x8 b0 = *(const bf16x8*)(wp0 + k0);
            bf16x8 b1 = *(const bf16x8*)(wp1 + k0);
            acc[0][0] = __builtin_amdgcn_mfma_f32_16x16x32_bf16(b0, a0, acc[0][0], 0, 0, 0);
            acc[0][1] = __builtin_amdgcn_mfma_f32_16x16x32_bf16(b1, a0, acc[0][1], 0, 0, 0);
            acc[1][0] = __builtin_amdgcn_mfma_f32_16x16x32_bf16(b0, a1, acc[1][0], 0, 0, 0);
            acc[1][1] = __builtin_amdgcn_mfma_f32_16x16x32_bf16(b1, a1, acc[1][1], 0, 0, 0);
        }
    }

    if (wv == 1) {
#pragma unroll
        for (int mi = 0; mi < 2; ++mi)
#pragma unroll
            for (int ni = 0; ni < 2; ++ni)
#pragma unroll
                for (int r = 0; r < 4; ++r)
                    red[lane][mi * 8 + ni * 4 + r] = acc[mi][ni][r];
    }
    __syncthreads();
    if (wv == 0) {
#pragma unroll
        for (int mi = 0; mi < 2; ++mi) {
#pragma unroll
            for (int ni = 0; ni < 2; ++ni) {
                int pix = m0 + mi * 16 + (lane & 15);
                int ch = n0 + ni * 16 + ((lane >> 4) << 2);
                float4 bv = *(const float4*)(bias + ch);
                float r0 = fmaxf(acc[mi][ni][0] + red[lane][mi * 8 + ni * 4 + 0] + bv.x, 0.f);
                float r1 = fmaxf(acc[mi][ni][1] + red[lane][mi * 8 + ni * 4 + 1] + bv.y, 0.f);
                float r2 = fmaxf(acc[mi][ni][2] + red[lane][mi * 8 + ni * 4 + 2] + bv.z, 0.f);
                float r3 = fmaxf(acc[mi][ni][3] + red[lane][mi * 8 + ni * 4 + 3] + bv.w, 0.f);
                uint2 pk;
                pk.x = (uint_t)f2bf(r0) | ((uint_t)f2bf(r1) << 16);
                pk.y = (uint_t)f2bf(r2) | ((uint_t)f2bf(r3) << 16);
                *(uint2*)(out + (size_t)pix * ldout + ch) = pk;
            }
        }
    }
}

// ---------- 2x2 maxpool NHWC bf16 (batched via blockIdx.y) ----------
__global__ void maxpool_nhwc_k(const ushort_t* __restrict__ in, ushort_t* __restrict__ out,
                               int C, int Hi, int Wi)
{
    in += (size_t)blockIdx.y * TSTRIDE;
    out += (size_t)blockIdx.y * TSTRIDE;
    int idx = blockIdx.x * 256 + threadIdx.x;
    int CG = C >> 3;
    int Wo = Wi >> 1, Ho = Hi >> 1;
    if (idx >= Ho * Wo * CG) return;
    int cg = idx % CG;
    int p = idx / CG;
    int y = p / Wo, x = p % Wo;
    const ushort_t* ip = in + ((size_t)(2 * y) * Wi + 2 * x) * C + cg * 8;
    bf16x8 v0 = *(const bf16x8*)(ip);
    bf16x8 v1 = *(const bf16x8*)(ip + C);
    bf16x8 v2 = *(const bf16x8*)(ip + (size_t)Wi * C);
    bf16x8 v3 = *(const bf16x8*)(ip + (size_t)Wi * C + C);
    bf16x8 r;
#pragma unroll
    for (int j = 0; j < 8; ++j) {
        float m = fmaxf(fmaxf(bf2f((ushort_t)v0[j]), bf2f((ushort_t)v1[j])),
                        fmaxf(bf2f((ushort_t)v2[j]), bf2f((ushort_t)v3[j])));
        r[j] = (short)f2bf(m);
    }
    *(bf16x8*)(out + (size_t)p * C + cg * 8) = r;
}

// ---------- bicubic weights (align_corners=True), PyTorch A=-0.75 ----------
__device__ inline void cubw(float t, float* w) {
    float x0 = 1.f + t, x2 = 1.f - t, x3 = 2.f - t;
    w[0] = ((-0.75f*x0 + 3.75f)*x0 - 6.f)*x0 + 3.f;
    w[1] = (1.25f*t - 2.25f)*t*t + 1.f;
    w[2] = (1.25f*x2 - 2.25f)*x2*x2 + 1.f;
    w[3] = ((-0.75f*x3 + 3.75f)*x3 - 6.f)*x3 + 3.f;
}

// ---------- fused: bicubic 32->128 + L2 norm; img0 additionally 2x2-mean-pools into Abuf ----------
__global__ __launch_bounds__(256) void upnorm_k(const ushort_t* __restrict__ in, ushort_t* __restrict__ F,
                                                ushort_t* __restrict__ Abuf)
{
    __shared__ float sm[4][320];
    in += (size_t)blockIdx.y * TSTRIDE;
    F += (size_t)blockIdx.y * FSTRIDE;
    int wid = threadIdx.x >> 6, lane = threadIdx.x & 63;
    int pb = blockIdx.x;
    int py = pb >> 6, px = pb & 63;
    int p = (2 * py + (wid >> 1)) * 128 + 2 * px + (wid & 1);
    int Y = p >> 7, X = p & 127;
    float sy = (float)Y * (31.f / 127.f);
    float sx = (float)X * (31.f / 127.f);
    int fy = (int)floorf(sy), fx = (int)floorf(sx);
    float ty = sy - (float)fy, tx = sx - (float)fx;
    float wy[4], wx[4];
    cubw(ty, wy); cubw(tx, wx);
    float a0 = 0.f, a1 = 0.f, a2 = 0.f, a3 = 0.f;
#pragma unroll
    for (int i = 0; i < 4; ++i) {
        int yy = min(max(fy - 1 + i, 0), 31);
#pragma unroll
        for (int j = 0; j < 4; ++j) {
            int xx = min(max(fx - 1 + j, 0), 31);
            float w = wy[i] * wx[j];
            uint2 v = *(const uint2*)(in + ((size_t)yy * 32 + xx) * 256 + lane * 4);
            a0 += w * bflo(v.x); a1 += w * bfhi(v.x);
            a2 += w * bflo(v.y); a3 += w * bfhi(v.y);
        }
    }
    float v0 = bf2f(f2bf(a0)), v1 = bf2f(f2bf(a1)), v2 = bf2f(f2bf(a2)), v3 = bf2f(f2bf(a3));
    float c0 = bf2f(F[(size_t)p * 320 + lane]);
    float ss = c0 * c0 + v0 * v0 + v1 * v1 + v2 * v2 + v3 * v3;
#pragma unroll
    for (int off = 32; off > 0; off >>= 1) ss += __shfl_xor(ss, off);
    float inv = 1.f / (1e-8f + sqrtf(ss));
    if (blockIdx.y == 1) {
        F[(size_t)p * 320 + lane] = f2bf(c0 * inv);
        uint2 pk;
        pk.x = (uint_t)f2bf(v0 * inv) | ((uint_t)f2bf(v1 * inv) << 16);
        pk.y = (uint_t)f2bf(v2 * inv) | ((uint_t)f2bf(v3 * inv) << 16);
        *(uint2*)(F + (size_t)p * 320 + 64 + lane * 4) = pk;
    } else {
        sm[wid][lane] = bf2f(f2bf(c0 * inv));
        sm[wid][64 + lane * 4 + 0] = bf2f(f2bf(v0 * inv));
        sm[wid][64 + lane * 4 + 1] = bf2f(f2bf(v1 * inv));
        sm[wid][64 + lane * 4 + 2] = bf2f(f2bf(v2 * inv));
        sm[wid][64 + lane * 4 + 3] = bf2f(f2bf(v3 * inv));
        __syncthreads();
        for (int ch = threadIdx.x; ch < 320; ch += 256) {
            float a = 0.25f * (sm[0][ch] + sm[1][ch] + sm[2][ch] + sm[3][ch]);
            Abuf[(size_t)pb * 320 + ch] = f2bf(a);
        }
    }
}

// ---------- correlation GEMM + fused softmax-denominator partials ----------
// r10 config (best measured): named ping-pong reg staging, n-fastest grid.
__global__ __launch_bounds__(256) void gemm_corr_k(
    const ushort_t* __restrict__ A, const ushort_t* __restrict__ B, char* __restrict__ D8,
    const float* __restrict__ coefr, const float* __restrict__ coeft,
    float* __restrict__ rpsum, float* __restrict__ cpsum)
{
    __shared__ ushort_t lA[128 * 32];
    __shared__ ushort_t lB[128 * 32];
    __shared__ float cl[2][128];
    __shared__ float rl[2][128];
    const int tid = threadIdx.x;
    const int lane = tid & 63;
    const int wid = tid >> 6;
    const int wr = wid >> 1, wc = wid & 1;
    const int m0 = blockIdx.y * 128, n0 = blockIdx.x * 128;
    const int fr = lane & 15;
    const int fo = (lane >> 4) << 3;
    const int srow = tid >> 2;
    const int scol = (tid & 3) << 3;

    const ushort_t* Ag0 = A + (size_t)(m0 + srow) * 320 + scol;
    const ushort_t* Ag1 = Ag0 + (size_t)64 * 320;
    const ushort_t* Bg0 = B + (size_t)(n0 + srow) * 320 + scol;
    const ushort_t* Bg1 = Bg0 + (size_t)64 * 320;

    f32x4 zero = {0.f, 0.f, 0.f, 0.f};
    f32x4 acc[4][4];
#pragma unroll
    for (int i = 0; i < 4; ++i)
#pragma unroll
        for (int j = 0; j < 4; ++j) acc[i][j] = zero;

    uint4 pA0, pA1, pB0, pB1;
    uint4 qA0, qA1, qB0, qB1;
    pA0 = *(const uint4*)(Ag0);
    pA1 = *(const uint4*)(Ag1);
    pB0 = *(const uint4*)(Bg0);
    pB1 = *(const uint4*)(Bg1);

#define DSWRITE(rA0, rA1, rB0, rB1) { \
        *(uint4*)&lA[srow * 32 + scol] = rA0; \
        *(uint4*)&lA[(64 + srow) * 32 + scol] = rA1; \
        *(uint4*)&lB[srow * 32 + scol] = rB0; \
        *(uint4*)&lB[(64 + srow) * 32 + scol] = rB1; }

#define GLOAD(rA0, rA1, rB0, rB1, kk) { \
        rA0 = *(const uint4*)(Ag0 + (kk)); \
        rA1 = *(const uint4*)(Ag1 + (kk)); \
        rB0 = *(const uint4*)(Bg0 + (kk)); \
        rB1 = *(const uint4*)(Bg1 + (kk)); }

#define COMPUTE() { \
        bf16x8 af[4], bfr[4]; \
        _Pragma("unroll") \
        for (int mi = 0; mi < 4; ++mi) \
            af[mi] = *(const bf16x8*)&lA[(wr * 64 + mi * 16 + fr) * 32 + fo]; \
        _Pragma("unroll") \
        for (int ni = 0; ni < 4; ++ni) \
            bfr[ni] = *(const bf16x8*)&lB[(wc * 64 + ni * 16 + fr) * 32 + fo]; \
        _Pragma("unroll") \
        for (int mi = 0; mi < 4; ++mi) \
            _Pragma("unroll") \
            for (int ni = 0; ni < 4; ++ni) \
                acc[mi][ni] = __builtin_amdgcn_mfma_f32_16x16x32_bf16(bfr[ni], af[mi], acc[mi][ni], 0, 0, 0); }

#pragma unroll
    for (int tt = 0; tt < 5; ++tt) {
        __syncthreads();
        DSWRITE(pA0, pA1, pB0, pB1)
        GLOAD(qA0, qA1, qB0, qB1, 32 * (2 * tt + 1))
        __syncthreads();
        COMPUTE()
        __syncthreads();
        DSWRITE(qA0, qA1, qB0, qB1)
        if (tt < 4) { GLOAD(pA0, pA1, pB0, pB1, 32 * (2 * tt + 2)) }
        __syncthreads();
        COMPUTE()
    }
#undef DSWRITE
#undef GLOAD
#undef COMPUTE

    const float s = 1.0f / 320.0f;
    const float cr = coefr[0], ct = coeft[0];
    const bool sameCoef = (cr == ct);
    float rpx[4] = {0.f, 0.f, 0.f, 0.f};
    float cpx[4][4];
#pragma unroll
    for (int ni = 0; ni < 4; ++ni)
#pragma unroll
        for (int r = 0; r < 4; ++r) cpx[ni][r] = 0.f;

    const int mrow = lane & 15;
    const int ng = (lane >> 4) << 2;
#pragma unroll
    for (int mi = 0; mi < 4; ++mi) {
        int m = m0 + wr * 64 + mi * 16 + mrow;
        char* drow = D8 + (size_t)m * 16384;
#pragma unroll
        for (int ni = 0; ni < 4; ++ni) {
            int n = n0 + wc * 64 + ni * 16 + ng;
            float d0 = acc[mi][ni][0] * s;
            float d1 = acc[mi][ni][1] * s;
            float d2 = acc[mi][ni][2] * s;
            float d3 = acc[mi][ni][3] * s;
            int q0 = __float2int_rn(fminf(fmaxf(d0 * 40640.f, -127.f), 127.f));
            int q1 = __float2int_rn(fminf(fmaxf(d1 * 40640.f, -127.f), 127.f));
            int q2 = __float2int_rn(fminf(fmaxf(d2 * 40640.f, -127.f), 127.f));
            int q3 = __float2int_rn(fminf(fmaxf(d3 * 40640.f, -127.f), 127.f));
            uint_t pk8 = (uint_t)(q0 & 255) | ((uint_t)(q1 & 255) << 8)
                       | ((uint_t)(q2 & 255) << 16) | ((uint_t)(q3 & 255) << 24);
            *(uint_t*)(drow + n) = pk8;
            float e0 = __expf(cr * d0), e1 = __expf(cr * d1);
            float e2 = __expf(cr * d2), e3 = __expf(cr * d3);
            cpx[ni][0] += e0; cpx[ni][1] += e1; cpx[ni][2] += e2; cpx[ni][3] += e3;
            if (sameCoef) {
                rpx[mi] += e0 + e1 + e2 + e3;
            } else {
                rpx[mi] += __expf(ct * d0) + __expf(ct * d1) + __expf(ct * d2) + __expf(ct * d3);
            }
        }
    }
#pragma unroll
    for (int mi = 0; mi < 4; ++mi) {
        rpx[mi] += __shfl_xor(rpx[mi], 16);
        rpx[mi] += __shfl_xor(rpx[mi], 32);
    }
    if (lane < 16) {
#pragma unroll
        for (int mi = 0; mi < 4; ++mi)
            rl[wc][wr * 64 + mi * 16 + lane] = rpx[mi];
    }
#pragma unroll
    for (int ni = 0; ni < 4; ++ni)
#pragma unroll
        for (int r = 0; r < 4; ++r) {
            cpx[ni][r] += __shfl_xor(cpx[ni][r], 1);
            cpx[ni][r] += __shfl_xor(cpx[ni][r], 2);
            cpx[ni][r] += __shfl_xor(cpx[ni][r], 4);
            cpx[ni][r] += __shfl_xor(cpx[ni][r], 8);
        }
    if ((lane & 15) == 0) {
        int g = lane >> 4;
#pragma unroll
        for (int ni = 0; ni < 4; ++ni)
#pragma unroll
            for (int r = 0; r < 4; ++r)
                cl[wr][wc * 64 + ni * 16 + g * 4 + r] = cpx[ni][r];
    }
    __syncthreads();
    if (tid < 128) {
        cpsum[(size_t)blockIdx.y * 16384 + n0 + tid] = cl[0][tid] + cl[1][tid];
        rpsum[(size_t)blockIdx.x * 4096 + m0 + tid] = rl[0][tid] + rl[1][tid];
    }
}

// ---------- fused finalize: lc[j] = -0.5*log(colsum); invr[m] = rsqrt(rowsum) ----------
__global__ void finboth_k(const float* __restrict__ cpsum, const float* __restrict__ rpsum,
                          float* __restrict__ lc, float* __restrict__ invr)
{
    int b = blockIdx.x;
    if (b < 64) {
        int j = b * 256 + threadIdx.x;
        float s = 0.f;
#pragma unroll
        for (int k = 0; k < 32; ++k) s += cpsum[(size_t)k * 16384 + j];
        lc[j] = -0.5f * __logf(s);
    } else {
        int m = (b - 64) * 256 + threadIdx.x;
        float s = 0.f;
#pragma unroll
        for (int k = 0; k < 128; ++k) s += rpsum[(size_t)k * 4096 + m];
        invr[m] = rsqrtf(s);
    }
}

// ---------- per-row top-5 on int8 dist: 2 waves per row, LDS pair-merge ----------
#define INS5(w_) { float w = (w_); float mx; \
    mx = fmaxf(w, t0); w = fminf(w, t0); t0 = mx; \
    mx = fmaxf(w, t1); w = fminf(w, t1); t1 = mx; \
    mx = fmaxf(w, t2); w = fminf(w, t2); t2 = mx; \
    mx = fmaxf(w, t3); w = fminf(w, t3); t3 = mx; \
    t4 = fmaxf(w, t4); }
#define SB(w, sft) ((float)(int)(signed char)(((w) >> (sft)) & 0xffu))

__global__ __launch_bounds__(256) void row_topk_k(
    const char* __restrict__ D8, const float* __restrict__ lc,
    const float* __restrict__ invr,
    const float* __restrict__ coefr, const float* __restrict__ coeft,
    float* __restrict__ conf5)
{
    __shared__ float sm5[4][5];
    int wid = threadIdx.x >> 6, lane = threadIdx.x & 63;
    int row = blockIdx.x * 2 + (wid >> 1);      // 2 rows per block
    int half = wid & 1;                          // each row: 2 waves
    float hc = 0.5f * (coefr[0] + coeft[0]);
    float hq = hc * (1.0f / 40640.f);
    const char* rp = D8 + (size_t)row * 16384;

    float t0 = -1e30f, t1 = -1e30f, t2 = -1e30f, t3 = -1e30f, t4 = -1e30f;
    for (int i = 0; i < 8; ++i) {
        int cw = half * 512 + i * 64 + lane;     // 16B chunk index (0..1023)
        uint4 u = *(const uint4*)(rp + cw * 16);
        int col = cw * 16;
        float4 l0 = *(const float4*)(lc + col);
        float4 l1 = *(const float4*)(lc + col + 4);
        float4 l2 = *(const float4*)(lc + col + 8);
        float4 l3 = *(const float4*)(lc + col + 12);
        float k0  = fmaf(hq, SB(u.x, 0),  l0.x);
        float k1  = fmaf(hq, SB(u.x, 8),  l0.y);
        float k2  = fmaf(hq, SB(u.x, 16), l0.z);
        float k3  = fmaf(hq, SB(u.x, 24), l0.w);
        float k4  = fmaf(hq, SB(u.y, 0),  l1.x);
        float k5  = fmaf(hq, SB(u.y, 8),  l1.y);
        float k6  = fmaf(hq, SB(u.y, 16), l1.z);
        float k7  = fmaf(hq, SB(u.y, 24), l1.w);
        float k8  = fmaf(hq, SB(u.z, 0),  l2.x);
        float k9  = fmaf(hq, SB(u.z, 8),  l2.y);
        float k10 = fmaf(hq, SB(u.z, 16), l2.z);
        float k11 = fmaf(hq, SB(u.z, 24), l2.w);
        float k12 = fmaf(hq, SB(u.w, 0),  l3.x);
        float k13 = fmaf(hq, SB(u.w, 8),  l3.y);
        float k14 = fmaf(hq, SB(u.w, 16), l3.z);
        float k15 = fmaf(hq, SB(u.w, 24), l3.w);
        float ma = fmaxf(fmaxf(fmaxf(k0, k1), fmaxf(k2, k3)),
                         fmaxf(fmaxf(k4, k5), fmaxf(k6, k7)));
        float mb = fmaxf(fmaxf(fmaxf(k8, k9), fmaxf(k10, k11)),
                         fmaxf(fmaxf(k12, k13), fmaxf(k14, k15)));
        if (fmaxf(ma, mb) > t4) {
            INS5(k0);  INS5(k1);  INS5(k2);  INS5(k3);
            INS5(k4);  INS5(k5);  INS5(k6);  INS5(k7);
            INS5(k8);  INS5(k9);  INS5(k10); INS5(k11);
            INS5(k12); INS5(k13); INS5(k14); INS5(k15);
        }
    }
#pragma unroll
    for (int off = 1; off < 64; off <<= 1) {
        float o0 = __shfl_xor(t0, off), o1 = __shfl_xor(t1, off), o2 = __shfl_xor(t2, off);
        float o3 = __shfl_xor(t3, off), o4 = __shfl_xor(t4, off);
        INS5(o0); INS5(o1); INS5(o2); INS5(o3); INS5(o4);
    }
    if (lane == 0) {
        sm5[wid][0] = t0; sm5[wid][1] = t1; sm5[wid][2] = t2; sm5[wid][3] = t3; sm5[wid][4] = t4;
    }
    __syncthreads();
    if (half == 0 && lane == 0) {
        int ow = wid + 1;                        // partner wave's list
        INS5(sm5[ow][0]); INS5(sm5[ow][1]); INS5(sm5[ow][2]); INS5(sm5[ow][3]); INS5(sm5[ow][4]);
        float iv = invr[row];
        conf5[0 * 4096 + row] = __expf(t0) * iv;
        conf5[1 * 4096 + row] = __expf(t1) * iv;
        conf5[2 * 4096 + row] = __expf(t2) * iv;
        conf5[3 * 4096 + row] = __expf(t3) * iv;
        conf5[4 * 4096 + row] = __expf(t4) * iv;
    }
}

// ---------- fp32 3x3 conv (head conv1, NCHW) ----------
__global__ void conv3x3_k(const float* __restrict__ in, const float* __restrict__ wgt,
                          const float* __restrict__ bias, float* __restrict__ out,
                          int Cin, int H, int W, int relu)
{
    int p = blockIdx.x * 256 + threadIdx.x;
    int HW = H * W;
    if (p >= HW) return;
    int co0 = blockIdx.y * 8;
    int y = p / W, x = p - y * W;
    float acc0 = bias[co0+0], acc1 = bias[co0+1], acc2 = bias[co0+2], acc3 = bias[co0+3];
    float acc4 = bias[co0+4], acc5 = bias[co0+5], acc6 = bias[co0+6], acc7 = bias[co0+7];
    bool ym = y > 0, yp = y < H-1, xm = x > 0, xp = x < W-1;
    for (int ci = 0; ci < Cin; ++ci) {
        const float* ip = in + (size_t)ci * HW + p;
        float v0 = (ym && xm) ? ip[-W-1] : 0.f;
        float v1 = (ym)       ? ip[-W]   : 0.f;
        float v2 = (ym && xp) ? ip[-W+1] : 0.f;
        float v3 = (xm)       ? ip[-1]   : 0.f;
        float v4 =              ip[0];
        float v5 = (xp)       ? ip[1]    : 0.f;
        float v6 = (yp && xm) ? ip[W-1]  : 0.f;
        float v7 = (yp)       ? ip[W]    : 0.f;
        float v8 = (yp && xp) ? ip[W+1]  : 0.f;
        const float* wp = wgt + ((size_t)co0 * Cin + ci) * 9;
        size_t ws = (size_t)Cin * 9;
#define CACC(q, a) { const float* wq = wp + q * ws; \
        a += wq[0]*v0 + wq[1]*v1 + wq[2]*v2 + wq[3]*v3 + wq[4]*v4 \
           + wq[5]*v5 + wq[6]*v6 + wq[7]*v7 + wq[8]*v8; }
        CACC(0, acc0) CACC(1, acc1) CACC(2, acc2) CACC(3, acc3)
        CACC(4, acc4) CACC(5, acc5) CACC(6, acc6) CACC(7, acc7)
#undef CACC
    }
#define CW(q, a) { float r = a; if (relu) r = fmaxf(r, 0.f); out[(size_t)(co0+q)*HW + p] = r; }
    CW(0, acc0) CW(1, acc1) CW(2, acc2) CW(3, acc3)
    CW(4, acc4) CW(5, acc5) CW(6, acc6) CW(7, acc7)
#undef CW
}

// ---------- head conv2 (8->8, relu) fused with 1x1 (8->1) ----------
__global__ void head2_k(const float* __restrict__ in, const float* __restrict__ wgt,
                        const float* __restrict__ bias, const float* __restrict__ w3,
                        const float* __restrict__ b3, float* __restrict__ out64)
{
    int p = blockIdx.x * 256 + threadIdx.x;
    int y = p >> 6, x = p & 63;
    float acc[8];
#pragma unroll
    for (int c = 0; c < 8; ++c) acc[c] = bias[c];
    bool ym = y > 0, yp = y < 63, xm = x > 0, xp = x < 63;
#pragma unroll
    for (int ci = 0; ci < 8; ++ci) {
        const float* ip = in + ci * 4096 + p;
        float v0 = (ym && xm) ? ip[-65] : 0.f;
        float v1 = (ym)       ? ip[-64] : 0.f;
        float v2 = (ym && xp) ? ip[-63] : 0.f;
        float v3 = (xm)       ? ip[-1]  : 0.f;
        float v4 =              ip[0];
        float v5 = (xp)       ? ip[1]   : 0.f;
        float v6 = (yp && xm) ? ip[63]  : 0.f;
        float v7 = (yp)       ? ip[64]  : 0.f;
        float v8 = (yp && xp) ? ip[65]  : 0.f;
#pragma unroll
        for (int co = 0; co < 8; ++co) {
            const float* wq = wgt + ((size_t)co * 8 + ci) * 9;
            acc[co] += wq[0]*v0 + wq[1]*v1 + wq[2]*v2 + wq[3]*v3 + wq[4]*v4
                     + wq[5]*v5 + wq[6]*v6 + wq[7]*v7 + wq[8]*v8;
        }
    }
    float o = b3[0];
#pragma unroll
    for (int c = 0; c < 8; ++c) o += w3[c] * fmaxf(acc[c], 0.f);
    out64[p] = o;
}

// ---------- fp32 bicubic (final output) ----------
__global__ void bicubic_k(const float* __restrict__ in, float* __restrict__ out,
                          int C, int Hin, int Win, int Hout, int Wout)
{
    int idx = blockIdx.x * 256 + threadIdx.x;
    int total = C * Hout * Wout;
    if (idx >= total) return;
    int X = idx % Wout;
    int Y = (idx / Wout) % Hout;
    int c = idx / (Wout * Hout);
    float sy = (float)Y * (float)(Hin - 1) / (float)(Hout - 1);
    float sx = (float)X * (float)(Win - 1) / (float)(Wout - 1);
    int fy = (int)floorf(sy), fx = (int)floorf(sx);
    float ty = sy - (float)fy, tx = sx - (float)fx;
    float wy[4], wx[4];
    cubw(ty, wy); cubw(tx, wx);
    const float* ip = in + (size_t)c * Hin * Win;
    float acc = 0.f;
#pragma unroll
    for (int i = 0; i < 4; ++i) {
        int yy = min(max(fy - 1 + i, 0), Hin - 1);
        float ra = 0.f;
#pragma unroll
        for (int j = 0; j < 4; ++j) {
            int xx = min(max(fx - 1 + j, 0), Win - 1);
            ra += wx[j] * ip[yy * Win + xx];
        }
        acc += wy[i] * ra;
    }
    out[idx] = acc;
}

// ---------- host ----------
extern "C" void kernel_launch(void* const* d_in, const int* in_sizes, int n_in,
                              void* d_out, int out_size, void* d_ws, size_t ws_size,
                              hipStream_t stream)
{
    const float* x_ref = (const float*)d_in[0];
    const float* x_tem = (const float*)d_in[1];
    const float* w0  = (const float*)d_in[2];   const float* b0  = (const float*)d_in[3];
    const float* w2  = (const float*)d_in[4];   const float* b2  = (const float*)d_in[5];
    const float* w5  = (const float*)d_in[6];   const float* b5  = (const float*)d_in[7];
    const float* w7  = (const float*)d_in[8];   const float* b7  = (const float*)d_in[9];
    const float* w10 = (const float*)d_in[10];  const float* b10 = (const float*)d_in[11];
    const float* w12 = (const float*)d_in[12];  const float* b12 = (const float*)d_in[13];
    const float* w14 = (const float*)d_in[14];  const float* b14 = (const float*)d_in[15];
    const float* coefr = (const float*)d_in[16];
    const float* coeft = (const float*)d_in[17];
    const float* fw1 = (const float*)d_in[18];  const float* fb1 = (const float*)d_in[19];
    const float* fw2 = (const float*)d_in[20];  const float* fb2 = (const float*)d_in[21];
    const float* fw3 = (const float*)d_in[22];  const float* fb3 = (const float*)d_in[23];
    float* out = (float*)d_out;

    char* wsp = (char*)d_ws;
    auto alloc = [&](size_t bytes) { char* p = wsp; wsp += (bytes + 255) & ~(size_t)255; return p; };
    ushort_t* F     = (ushort_t*)alloc(2 * FSTRIDE * 2);
    ushort_t* t0    = (ushort_t*)alloc(2 * TSTRIDE * 2);
    ushort_t* t1    = (ushort_t*)alloc(2 * TSTRIDE * 2);
    ushort_t* t2    = (ushort_t*)alloc(2 * TSTRIDE * 2);
    ushort_t* wT2   = (ushort_t*)alloc((size_t)64 * 64 * 9 * 2);
    ushort_t* wT5   = (ushort_t*)alloc((size_t)128 * 64 * 9 * 2);
    ushort_t* wT7   = (ushort_t*)alloc((size_t)128 * 128 * 9 * 2);
    ushort_t* wT10  = (ushort_t*)alloc((size_t)256 * 128 * 9 * 2);
    ushort_t* wT12  = (ushort_t*)alloc((size_t)256 * 256 * 9 * 2);
    ushort_t* wT14  = (ushort_t*)alloc((size_t)256 * 256 * 9 * 2);
    ushort_t* Abuf  = (ushort_t*)alloc((size_t)4096 * 320 * 2);
    char*     dist8 = (char*)alloc((size_t)4096 * 16384);
    float*    rpsum = (float*)alloc((size_t)128 * 4096 * 4);
    float*    cpsum = (float*)alloc((size_t)32 * 16384 * 4);
    float*    lc    = (float*)alloc(16384 * 4);
    float*    invr  = (float*)alloc(4096 * 4);
    float*    conf5 = (float*)alloc(5 * 4096 * 4);
    float*    h1    = (float*)alloc(8 * 4096 * 4);
    float*    out64 = (float*)alloc(4096 * 4);
    (void)ws_size; (void)n_in; (void)in_sizes; (void)out_size;

    // fused weight transforms
    WT6 wt;
    wt.src[0] = w2;  wt.dst[0] = wT2;  wt.co[0] = 64;  wt.ci[0] = 64;
    wt.src[1] = w5;  wt.dst[1] = wT5;  wt.co[1] = 128; wt.ci[1] = 64;
    wt.src[2] = w7;  wt.dst[2] = wT7;  wt.co[2] = 128; wt.ci[2] = 128;
    wt.src[3] = w10; wt.dst[3] = wT10; wt.co[3] = 256; wt.ci[3] = 128;
    wt.src[4] = w12; wt.dst[4] = wT12; wt.co[4] = 256; wt.ci[4] = 256;
    wt.src[5] = w14; wt.dst[5] = wT14; wt.co[5] = 256; wt.ci[5] = 256;
    int nblk = 0;
    for (int s = 0; s < 6; ++s) { wt.off[s] = nblk; nblk += (wt.co[s] * wt.ci[s] * 9 + 255) / 256; }
    wtrans6_k<<<nblk, 256, 0, stream>>>(wt);

    // batched feature extraction
    conv0_k<<<dim3(4096, 2), 256, 0, stream>>>(x_ref, x_tem, w0, b0, F, t0);
    conv_mfma_k<64><<<dim3(256, 1, 2), 256, 0, stream>>>(t0, 64, 0, TSTRIDE, wT2, b2, t1, 64, 0, TSTRIDE, 128, 128, 64);
    maxpool_nhwc_k<<<dim3(128, 2), 256, 0, stream>>>(t1, t2, 64, 128, 128);
    conv_mfma_k<64><<<dim3(64, 2, 2), 256, 0, stream>>>(t2, 64, 0, TSTRIDE, wT5, b5, t1, 128, 0, TSTRIDE, 64, 64, 128);
    conv_mfma_k<128><<<dim3(64, 2, 2), 256, 0, stream>>>(t1, 128, 0, TSTRIDE, wT7, b7, t2, 128, 0, TSTRIDE, 64, 64, 128);
    maxpool_nhwc_k<<<dim3(64, 2), 256, 0, stream>>>(t2, t1, 128, 64, 64);
    conv_mfma2w_k<128><<<dim3(32, 8, 2), 128, 0, stream>>>(t1, 128, TSTRIDE, wT10, b10, t2, 256, TSTRIDE, 32, 32, 256);
    conv_mfma2w_k<256><<<dim3(32, 8, 2), 128, 0, stream>>>(t2, 256, TSTRIDE, wT12, b12, t1, 256, TSTRIDE, 32, 32, 256);
    conv_mfma2w_k<256><<<dim3(32, 8, 2), 128, 0, stream>>>(t1, 256, TSTRIDE, wT14, b14, t2, 256, TSTRIDE, 32, 32, 256);
    upnorm_k<<<dim3(4096, 2), 256, 0, stream>>>(t2, F, Abuf);

    // n-fastest grid (best measured config, r10)
    gemm_corr_k<<<dim3(128, 32), 256, 0, stream>>>(Abuf, F + FSTRIDE, dist8, coefr, coeft, rpsum, cpsum);

    finboth_k<<<80, 256, 0, stream>>>(cpsum, rpsum, lc, invr);

    // top-5: 2 rows per block, 2 waves per row
    row_topk_k<<<2048, 256, 0, stream>>>(dist8, lc, invr, coefr, coeft, conf5);

    conv3x3_k<<<dim3(16, 1), 256, 0, stream>>>(conf5, fw1, fb1, h1, 5, 64, 64, 1);
    head2_k<<<16, 256, 0, stream>>>(h1, fw2, fb2, fw3, fb3, out64);
    bicubic_k<<<64, 256, 0, stream>>>(out64, out, 1, 64, 64, 128, 128);
}

// Round 15
// 377.568 us; speedup vs baseline: 1.0606x; 1.0090x over previous
//
#include <hip/hip_runtime.h>
#include <math.h>

typedef unsigned short ushort_t;
typedef unsigned int uint_t;
typedef __attribute__((ext_vector_type(8))) short bf16x8;
typedef __attribute__((ext_vector_type(4))) float f32x4;

#define FSTRIDE ((size_t)16384 * 320)
#define TSTRIDE ((size_t)16384 * 64)

// ---------- bf16 helpers ----------
__device__ inline ushort_t f2bf(float f) {
    union { float f; uint_t u; } x; x.f = f;
    uint_t r = x.u + 0x7fffu + ((x.u >> 16) & 1u);
    return (ushort_t)(r >> 16);
}
__device__ inline float bf2f(ushort_t h) {
    union { uint_t u; float f; } x; x.u = ((uint_t)h) << 16;
    return x.f;
}
__device__ inline float bflo(uint_t u) {
    union { uint_t u; float f; } x; x.u = u << 16; return x.f;
}
__device__ inline float bfhi(uint_t u) {
    union { uint_t u; float f; } x; x.u = u & 0xffff0000u; return x.f;
}

// ---------- fused weight transform: 6 conv layers, OIHW fp32 -> [tap][co][ci] bf16 ----------
struct WT6 {
    const float* src[6];
    ushort_t* dst[6];
    int co[6], ci[6];
    int off[6];
};
__global__ void wtrans6_k(WT6 a)
{
    int b = blockIdx.x, seg = 0;
#pragma unroll
    for (int s = 1; s < 6; ++s) if (b >= a.off[s]) seg = s;
    int idx = (b - a.off[seg]) * 256 + threadIdx.x;
    int CO = a.co[seg], CI = a.ci[seg];
    if (idx >= CO * CI * 9) return;
    int tap = idx % 9;
    int rem = idx / 9;
    int ci = rem % CI;
    int co = rem / CI;
    a.dst[seg][((size_t)tap * CO + co) * CI + ci] = f2bf(a.src[seg][idx]);
}

// ---------- conv0: 3->64 @128x128, NCHW fp32 in; writes F cols 0..63 AND compact t0 ----------
__global__ __launch_bounds__(256) void conv0_k(const float* __restrict__ x0, const float* __restrict__ x1,
                                               const float* __restrict__ w,
                                               const float* __restrict__ b, ushort_t* __restrict__ F,
                                               ushort_t* __restrict__ t0)
{
    const float* x = blockIdx.y ? x1 : x0;
    F += (size_t)blockIdx.y * FSTRIDE;
    t0 += (size_t)blockIdx.y * TSTRIDE;
    int co = threadIdx.x & 63;
    int p = blockIdx.x * 4 + (threadIdx.x >> 6);
    int y = p >> 7, xx = p & 127;
    float acc = b[co];
#pragma unroll
    for (int ci = 0; ci < 3; ++ci) {
#pragma unroll
        for (int t = 0; t < 9; ++t) {
            int dy = t / 3 - 1, dx = t % 3 - 1;
            int yy = y + dy, xc = xx + dx;
            if ((unsigned)yy < 128u && (unsigned)xc < 128u) {
                acc += x[ci * 16384 + yy * 128 + xc] * w[co * 27 + ci * 9 + t];
            }
        }
    }
    ushort_t r = f2bf(fmaxf(acc, 0.f));
    F[(size_t)p * 320 + co] = r;
    t0[(size_t)p * 64 + co] = r;
}

// ---------- 2-wave split-tap implicit-GEMM MFMA conv 3x3 pad=1 (32x32 tile) ----------
// wave0 accumulates taps 0..4, wave1 taps 5..8; LDS reduce; wave0 does epilogue.
template<int CI>
__global__ __launch_bounds__(128) void conv_mfma2w_k(
    const ushort_t* __restrict__ in, int ldin, size_t inImgStride,
    const ushort_t* __restrict__ wT, const float* __restrict__ bias,
    ushort_t* __restrict__ out, int ldout, size_t outImgStride,
    int H, int W, int CO)
{
    __shared__ float red[64][17];
    in += (size_t)blockIdx.z * inImgStride;
    out += (size_t)blockIdx.z * outImgStride;
    const int lane = threadIdx.x & 63;
    const int wv = threadIdx.x >> 6;
    const int m0 = blockIdx.x * 32;
    const int n0 = blockIdx.y * 32;
    const int fr = lane & 15;
    const int fo = (lane >> 4) << 3;

    size_t abase[2];
    unsigned vmask[2];
#pragma unroll
    for (int mi = 0; mi < 2; ++mi) {
        int p = m0 + mi * 16 + fr;
        int y = p / W, x = p % W;
        abase[mi] = (size_t)p * ldin + fo;
        unsigned vm = 0;
#pragma unroll
        for (int t = 0; t < 9; ++t) {
            int dy = t / 3 - 1, dx = t % 3 - 1;
            if ((unsigned)(y + dy) < (unsigned)H && (unsigned)(x + dx) < (unsigned)W) vm |= 1u << t;
        }
        vmask[mi] = vm;
    }

    f32x4 zero = {0.f, 0.f, 0.f, 0.f};
    f32x4 acc[2][2] = {{zero, zero}, {zero, zero}};
    const bf16x8 zz = {0, 0, 0, 0, 0, 0, 0, 0};

    const int tb = wv ? 5 : 0;
    const int te = wv ? 9 : 5;
    for (int t = tb; t < te; ++t) {
        int toff = ((t / 3 - 1) * W + (t % 3 - 1)) * ldin;
        bool v0 = (vmask[0] >> t) & 1u;
        bool v1 = (vmask[1] >> t) & 1u;
        const ushort_t* wp0 = wT + ((size_t)(t * CO + n0 + fr)) * CI + fo;
        const ushort_t* wp1 = wp0 + (size_t)16 * CI;
#pragma unroll
        for (int kc = 0; kc < CI / 32; ++kc) {
            int k0 = kc * 32;
            bf16x8 a0 = v0 ? *(const bf16x8*)(in + abase[0] + toff + k0) : zz;
            bf16x8 a1 = v1 ? *(const bf16x8*)(in + abase[1] + toff + k0) : zz;
            bf16x8 b0 = *(const bf16x8*)(wp0 + k0);
            bf16x8 b1 = *(const bf16x8*)(wp1 + k0);
            acc[0][0] = __builtin_amdgcn_mfma_f32_16x16x32_bf16(b0, a0, acc[0][0], 0, 0, 0);
            acc[0][1] = __builtin_amdgcn_mfma_f32_16x16x32_bf16(b1, a0, acc[0][1], 0, 0, 0);
            acc[1][0] = __builtin_amdgcn_mfma_f32_16x16x32_bf16(b0, a1, acc[1][0], 0, 0, 0);
            acc[1][1] = __builtin_amdgcn_mfma_f32_16x16x32_bf16(b1, a1, acc[1][1], 0, 0, 0);
        }
    }

    if (wv == 1) {
#pragma unroll
        for (int mi = 0; mi < 2; ++mi)
#pragma unroll
            for (int ni = 0; ni < 2; ++ni)
#pragma unroll
                for (int r = 0; r < 4; ++r)
                    red[lane][mi * 8 + ni * 4 + r] = acc[mi][ni][r];
    }
    __syncthreads();
    if (wv == 0) {
#pragma unroll
        for (int mi = 0; mi < 2; ++mi) {
#pragma unroll
            for (int ni = 0; ni < 2; ++ni) {
                int pix = m0 + mi * 16 + (lane & 15);
                int ch = n0 + ni * 16 + ((lane >> 4) << 2);
                float4 bv = *(const float4*)(bias + ch);
                float r0 = fmaxf(acc[mi][ni][0] + red[lane][mi * 8 + ni * 4 + 0] + bv.x, 0.f);
                float r1 = fmaxf(acc[mi][ni][1] + red[lane][mi * 8 + ni * 4 + 1] + bv.y, 0.f);
                float r2 = fmaxf(acc[mi][ni][2] + red[lane][mi * 8 + ni * 4 + 2] + bv.z, 0.f);
                float r3 = fmaxf(acc[mi][ni][3] + red[lane][mi * 8 + ni * 4 + 3] + bv.w, 0.f);
                uint2 pk;
                pk.x = (uint_t)f2bf(r0) | ((uint_t)f2bf(r1) << 16);
                pk.y = (uint_t)f2bf(r2) | ((uint_t)f2bf(r3) << 16);
                *(uint2*)(out + (size_t)pix * ldout + ch) = pk;
            }
        }
    }
}

// ---------- 2x2 maxpool NHWC bf16 (batched via blockIdx.y) ----------
__global__ void maxpool_nhwc_k(const ushort_t* __restrict__ in, ushort_t* __restrict__ out,
                               int C, int Hi, int Wi)
{
    in += (size_t)blockIdx.y * TSTRIDE;
    out += (size_t)blockIdx.y * TSTRIDE;
    int idx = blockIdx.x * 256 + threadIdx.x;
    int CG = C >> 3;
    int Wo = Wi >> 1, Ho = Hi >> 1;
    if (idx >= Ho * Wo * CG) return;
    int cg = idx % CG;
    int p = idx / CG;
    int y = p / Wo, x = p % Wo;
    const ushort_t* ip = in + ((size_t)(2 * y) * Wi + 2 * x) * C + cg * 8;
    bf16x8 v0 = *(const bf16x8*)(ip);
    bf16x8 v1 = *(const bf16x8*)(ip + C);
    bf16x8 v2 = *(const bf16x8*)(ip + (size_t)Wi * C);
    bf16x8 v3 = *(const bf16x8*)(ip + (size_t)Wi * C + C);
    bf16x8 r;
#pragma unroll
    for (int j = 0; j < 8; ++j) {
        float m = fmaxf(fmaxf(bf2f((ushort_t)v0[j]), bf2f((ushort_t)v1[j])),
                        fmaxf(bf2f((ushort_t)v2[j]), bf2f((ushort_t)v3[j])));
        r[j] = (short)f2bf(m);
    }
    *(bf16x8*)(out + (size_t)p * C + cg * 8) = r;
}

// ---------- bicubic weights (align_corners=True), PyTorch A=-0.75 ----------
__device__ inline void cubw(float t, float* w) {
    float x0 = 1.f + t, x2 = 1.f - t, x3 = 2.f - t;
    w[0] = ((-0.75f*x0 + 3.75f)*x0 - 6.f)*x0 + 3.f;
    w[1] = (1.25f*t - 2.25f)*t*t + 1.f;
    w[2] = (1.25f*x2 - 2.25f)*x2*x2 + 1.f;
    w[3] = ((-0.75f*x3 + 3.75f)*x3 - 6.f)*x3 + 3.f;
}

// ---------- fused: bicubic 32->128 + L2 norm; img0 additionally 2x2-mean-pools into Abuf ----------
__global__ __launch_bounds__(256) void upnorm_k(const ushort_t* __restrict__ in, ushort_t* __restrict__ F,
                                                ushort_t* __restrict__ Abuf)
{
    __shared__ float sm[4][320];
    in += (size_t)blockIdx.y * TSTRIDE;
    F += (size_t)blockIdx.y * FSTRIDE;
    int wid = threadIdx.x >> 6, lane = threadIdx.x & 63;
    int pb = blockIdx.x;
    int py = pb >> 6, px = pb & 63;
    int p = (2 * py + (wid >> 1)) * 128 + 2 * px + (wid & 1);
    int Y = p >> 7, X = p & 127;
    float sy = (float)Y * (31.f / 127.f);
    float sx = (float)X * (31.f / 127.f);
    int fy = (int)floorf(sy), fx = (int)floorf(sx);
    float ty = sy - (float)fy, tx = sx - (float)fx;
    float wy[4], wx[4];
    cubw(ty, wy); cubw(tx, wx);
    float a0 = 0.f, a1 = 0.f, a2 = 0.f, a3 = 0.f;
#pragma unroll
    for (int i = 0; i < 4; ++i) {
        int yy = min(max(fy - 1 + i, 0), 31);
#pragma unroll
        for (int j = 0; j < 4; ++j) {
            int xx = min(max(fx - 1 + j, 0), 31);
            float w = wy[i] * wx[j];
            uint2 v = *(const uint2*)(in + ((size_t)yy * 32 + xx) * 256 + lane * 4);
            a0 += w * bflo(v.x); a1 += w * bfhi(v.x);
            a2 += w * bflo(v.y); a3 += w * bfhi(v.y);
        }
    }
    float v0 = bf2f(f2bf(a0)), v1 = bf2f(f2bf(a1)), v2 = bf2f(f2bf(a2)), v3 = bf2f(f2bf(a3));
    float c0 = bf2f(F[(size_t)p * 320 + lane]);
    float ss = c0 * c0 + v0 * v0 + v1 * v1 + v2 * v2 + v3 * v3;
#pragma unroll
    for (int off = 32; off > 0; off >>= 1) ss += __shfl_xor(ss, off);
    float inv = 1.f / (1e-8f + sqrtf(ss));
    if (blockIdx.y == 1) {
        F[(size_t)p * 320 + lane] = f2bf(c0 * inv);
        uint2 pk;
        pk.x = (uint_t)f2bf(v0 * inv) | ((uint_t)f2bf(v1 * inv) << 16);
        pk.y = (uint_t)f2bf(v2 * inv) | ((uint_t)f2bf(v3 * inv) << 16);
        *(uint2*)(F + (size_t)p * 320 + 64 + lane * 4) = pk;
    } else {
        sm[wid][lane] = bf2f(f2bf(c0 * inv));
        sm[wid][64 + lane * 4 + 0] = bf2f(f2bf(v0 * inv));
        sm[wid][64 + lane * 4 + 1] = bf2f(f2bf(v1 * inv));
        sm[wid][64 + lane * 4 + 2] = bf2f(f2bf(v2 * inv));
        sm[wid][64 + lane * 4 + 3] = bf2f(f2bf(v3 * inv));
        __syncthreads();
        for (int ch = threadIdx.x; ch < 320; ch += 256) {
            float a = 0.25f * (sm[0][ch] + sm[1][ch] + sm[2][ch] + sm[3][ch]);
            Abuf[(size_t)pb * 320 + ch] = f2bf(a);
        }
    }
}

// ---------- correlation GEMM + fused softmax-denominator partials ----------
// r10 config (best measured): named ping-pong reg staging, n-fastest grid.
__global__ __launch_bounds__(256) void gemm_corr_k(
    const ushort_t* __restrict__ A, const ushort_t* __restrict__ B, char* __restrict__ D8,
    const float* __restrict__ coefr, const float* __restrict__ coeft,
    float* __restrict__ rpsum, float* __restrict__ cpsum)
{
    __shared__ ushort_t lA[128 * 32];
    __shared__ ushort_t lB[128 * 32];
    __shared__ float cl[2][128];
    __shared__ float rl[2][128];
    const int tid = threadIdx.x;
    const int lane = tid & 63;
    const int wid = tid >> 6;
    const int wr = wid >> 1, wc = wid & 1;
    const int m0 = blockIdx.y * 128, n0 = blockIdx.x * 128;
    const int fr = lane & 15;
    const int fo = (lane >> 4) << 3;
    const int srow = tid >> 2;
    const int scol = (tid & 3) << 3;

    const ushort_t* Ag0 = A + (size_t)(m0 + srow) * 320 + scol;
    const ushort_t* Ag1 = Ag0 + (size_t)64 * 320;
    const ushort_t* Bg0 = B + (size_t)(n0 + srow) * 320 + scol;
    const ushort_t* Bg1 = Bg0 + (size_t)64 * 320;

    f32x4 zero = {0.f, 0.f, 0.f, 0.f};
    f32x4 acc[4][4];
#pragma unroll
    for (int i = 0; i < 4; ++i)
#pragma unroll
        for (int j = 0; j < 4; ++j) acc[i][j] = zero;

    uint4 pA0, pA1, pB0, pB1;
    uint4 qA0, qA1, qB0, qB1;
    pA0 = *(const uint4*)(Ag0);
    pA1 = *(const uint4*)(Ag1);
    pB0 = *(const uint4*)(Bg0);
    pB1 = *(const uint4*)(Bg1);

#define DSWRITE(rA0, rA1, rB0, rB1) { \
        *(uint4*)&lA[srow * 32 + scol] = rA0; \
        *(uint4*)&lA[(64 + srow) * 32 + scol] = rA1; \
        *(uint4*)&lB[srow * 32 + scol] = rB0; \
        *(uint4*)&lB[(64 + srow) * 32 + scol] = rB1; }

#define GLOAD(rA0, rA1, rB0, rB1, kk) { \
        rA0 = *(const uint4*)(Ag0 + (kk)); \
        rA1 = *(const uint4*)(Ag1 + (kk)); \
        rB0 = *(const uint4*)(Bg0 + (kk)); \
        rB1 = *(const uint4*)(Bg1 + (kk)); }

#define COMPUTE() { \
        bf16x8 af[4], bfr[4]; \
        _Pragma("unroll") \
        for (int mi = 0; mi < 4; ++mi) \
            af[mi] = *(const bf16x8*)&lA[(wr * 64 + mi * 16 + fr) * 32 + fo]; \
        _Pragma("unroll") \
        for (int ni = 0; ni < 4; ++ni) \
            bfr[ni] = *(const bf16x8*)&lB[(wc * 64 + ni * 16 + fr) * 32 + fo]; \
        _Pragma("unroll") \
        for (int mi = 0; mi < 4; ++mi) \
            _Pragma("unroll") \
            for (int ni = 0; ni < 4; ++ni) \
                acc[mi][ni] = __builtin_amdgcn_mfma_f32_16x16x32_bf16(bfr[ni], af[mi], acc[mi][ni], 0, 0, 0); }

#pragma unroll
    for (int tt = 0; tt < 5; ++tt) {
        __syncthreads();
        DSWRITE(pA0, pA1, pB0, pB1)
        GLOAD(qA0, qA1, qB0, qB1, 32 * (2 * tt + 1))
        __syncthreads();
        COMPUTE()
        __syncthreads();
        DSWRITE(qA0, qA1, qB0, qB1)
        if (tt < 4) { GLOAD(pA0, pA1, pB0, pB1, 32 * (2 * tt + 2)) }
        __syncthreads();
        COMPUTE()
    }
#undef DSWRITE
#undef GLOAD
#undef COMPUTE

    const float s = 1.0f / 320.0f;
    const float cr = coefr[0], ct = coeft[0];
    const bool sameCoef = (cr == ct);
    float rpx[4] = {0.f, 0.f, 0.f, 0.f};
    float cpx[4][4];
#pragma unroll
    for (int ni = 0; ni < 4; ++ni)
#pragma unroll
        for (int r = 0; r < 4; ++r) cpx[ni][r] = 0.f;

    const int mrow = lane & 15;
    const int ng = (lane >> 4) << 2;
#pragma unroll
    for (int mi = 0; mi < 4; ++mi) {
        int m = m0 + wr * 64 + mi * 16 + mrow;
        char* drow = D8 + (size_t)m * 16384;
#pragma unroll
        for (int ni = 0; ni < 4; ++ni) {
            int n = n0 + wc * 64 + ni * 16 + ng;
            float d0 = acc[mi][ni][0] * s;
            float d1 = acc[mi][ni][1] * s;
            float d2 = acc[mi][ni][2] * s;
            float d3 = acc[mi][ni][3] * s;
            int q0 = __float2int_rn(fminf(fmaxf(d0 * 40640.f, -127.f), 127.f));
            int q1 = __float2int_rn(fminf(fmaxf(d1 * 40640.f, -127.f), 127.f));
            int q2 = __float2int_rn(fminf(fmaxf(d2 * 40640.f, -127.f), 127.f));
            int q3 = __float2int_rn(fminf(fmaxf(d3 * 40640.f, -127.f), 127.f));
            uint_t pk8 = (uint_t)(q0 & 255) | ((uint_t)(q1 & 255) << 8)
                       | ((uint_t)(q2 & 255) << 16) | ((uint_t)(q3 & 255) << 24);
            *(uint_t*)(drow + n) = pk8;
            float e0 = __expf(cr * d0), e1 = __expf(cr * d1);
            float e2 = __expf(cr * d2), e3 = __expf(cr * d3);
            cpx[ni][0] += e0; cpx[ni][1] += e1; cpx[ni][2] += e2; cpx[ni][3] += e3;
            if (sameCoef) {
                rpx[mi] += e0 + e1 + e2 + e3;
            } else {
                rpx[mi] += __expf(ct * d0) + __expf(ct * d1) + __expf(ct * d2) + __expf(ct * d3);
            }
        }
    }
#pragma unroll
    for (int mi = 0; mi < 4; ++mi) {
        rpx[mi] += __shfl_xor(rpx[mi], 16);
        rpx[mi] += __shfl_xor(rpx[mi], 32);
    }
    if (lane < 16) {
#pragma unroll
        for (int mi = 0; mi < 4; ++mi)
            rl[wc][wr * 64 + mi * 16 + lane] = rpx[mi];
    }
#pragma unroll
    for (int ni = 0; ni < 4; ++ni)
#pragma unroll
        for (int r = 0; r < 4; ++r) {
            cpx[ni][r] += __shfl_xor(cpx[ni][r], 1);
            cpx[ni][r] += __shfl_xor(cpx[ni][r], 2);
            cpx[ni][r] += __shfl_xor(cpx[ni][r], 4);
            cpx[ni][r] += __shfl_xor(cpx[ni][r], 8);
        }
    if ((lane & 15) == 0) {
        int g = lane >> 4;
#pragma unroll
        for (int ni = 0; ni < 4; ++ni)
#pragma unroll
            for (int r = 0; r < 4; ++r)
                cl[wr][wc * 64 + ni * 16 + g * 4 + r] = cpx[ni][r];
    }
    __syncthreads();
    if (tid < 128) {
        cpsum[(size_t)blockIdx.y * 16384 + n0 + tid] = cl[0][tid] + cl[1][tid];
        rpsum[(size_t)blockIdx.x * 4096 + m0 + tid] = rl[0][tid] + rl[1][tid];
    }
}

// ---------- fused finalize: lc[j] = -0.5*log(colsum); invr[m] = rsqrt(rowsum) ----------
__global__ void finboth_k(const float* __restrict__ cpsum, const float* __restrict__ rpsum,
                          float* __restrict__ lc, float* __restrict__ invr)
{
    int b = blockIdx.x;
    if (b < 64) {
        int j = b * 256 + threadIdx.x;
        float s = 0.f;
#pragma unroll
        for (int k = 0; k < 32; ++k) s += cpsum[(size_t)k * 16384 + j];
        lc[j] = -0.5f * __logf(s);
    } else {
        int m = (b - 64) * 256 + threadIdx.x;
        float s = 0.f;
#pragma unroll
        for (int k = 0; k < 128; ++k) s += rpsum[(size_t)k * 4096 + m];
        invr[m] = rsqrtf(s);
    }
}

// ---------- per-row top-5 on int8 dist: 2 waves per row, LDS pair-merge ----------
#define INS5(w_) { float w = (w_); float mx; \
    mx = fmaxf(w, t0); w = fminf(w, t0); t0 = mx; \
    mx = fmaxf(w, t1); w = fminf(w, t1); t1 = mx; \
    mx = fmaxf(w, t2); w = fminf(w, t2); t2 = mx; \
    mx = fmaxf(w, t3); w = fminf(w, t3); t3 = mx; \
    t4 = fmaxf(w, t4); }
#define SB(w, sft) ((float)(int)(signed char)(((w) >> (sft)) & 0xffu))

__global__ __launch_bounds__(256) void row_topk_k(
    const char* __restrict__ D8, const float* __restrict__ lc,
    const float* __restrict__ invr,
    const float* __restrict__ coefr, const float* __restrict__ coeft,
    float* __restrict__ conf5)
{
    __shared__ float sm5[4][5];
    int wid = threadIdx.x >> 6, lane = threadIdx.x & 63;
    int row = blockIdx.x * 2 + (wid >> 1);
    int half = wid & 1;
    float hc = 0.5f * (coefr[0] + coeft[0]);
    float hq = hc * (1.0f / 40640.f);
    const char* rp = D8 + (size_t)row * 16384;

    float t0 = -1e30f, t1 = -1e30f, t2 = -1e30f, t3 = -1e30f, t4 = -1e30f;
    for (int i = 0; i < 8; ++i) {
        int cw = half * 512 + i * 64 + lane;
        uint4 u = *(const uint4*)(rp + cw * 16);
        int col = cw * 16;
        float4 l0 = *(const float4*)(lc + col);
        float4 l1 = *(const float4*)(lc + col + 4);
        float4 l2 = *(const float4*)(lc + col + 8);
        float4 l3 = *(const float4*)(lc + col + 12);
        float k0  = fmaf(hq, SB(u.x, 0),  l0.x);
        float k1  = fmaf(hq, SB(u.x, 8),  l0.y);
        float k2  = fmaf(hq, SB(u.x, 16), l0.z);
        float k3  = fmaf(hq, SB(u.x, 24), l0.w);
        float k4  = fmaf(hq, SB(u.y, 0),  l1.x);
        float k5  = fmaf(hq, SB(u.y, 8),  l1.y);
        float k6  = fmaf(hq, SB(u.y, 16), l1.z);
        float k7  = fmaf(hq, SB(u.y, 24), l1.w);
        float k8  = fmaf(hq, SB(u.z, 0),  l2.x);
        float k9  = fmaf(hq, SB(u.z, 8),  l2.y);
        float k10 = fmaf(hq, SB(u.z, 16), l2.z);
        float k11 = fmaf(hq, SB(u.z, 24), l2.w);
        float k12 = fmaf(hq, SB(u.w, 0),  l3.x);
        float k13 = fmaf(hq, SB(u.w, 8),  l3.y);
        float k14 = fmaf(hq, SB(u.w, 16), l3.z);
        float k15 = fmaf(hq, SB(u.w, 24), l3.w);
        float ma = fmaxf(fmaxf(fmaxf(k0, k1), fmaxf(k2, k3)),
                         fmaxf(fmaxf(k4, k5), fmaxf(k6, k7)));
        float mb = fmaxf(fmaxf(fmaxf(k8, k9), fmaxf(k10, k11)),
                         fmaxf(fmaxf(k12, k13), fmaxf(k14, k15)));
        if (fmaxf(ma, mb) > t4) {
            INS5(k0);  INS5(k1);  INS5(k2);  INS5(k3);
            INS5(k4);  INS5(k5);  INS5(k6);  INS5(k7);
            INS5(k8);  INS5(k9);  INS5(k10); INS5(k11);
            INS5(k12); INS5(k13); INS5(k14); INS5(k15);
        }
    }
#pragma unroll
    for (int off = 1; off < 64; off <<= 1) {
        float o0 = __shfl_xor(t0, off), o1 = __shfl_xor(t1, off), o2 = __shfl_xor(t2, off);
        float o3 = __shfl_xor(t3, off), o4 = __shfl_xor(t4, off);
        INS5(o0); INS5(o1); INS5(o2); INS5(o3); INS5(o4);
    }
    if (lane == 0) {
        sm5[wid][0] = t0; sm5[wid][1] = t1; sm5[wid][2] = t2; sm5[wid][3] = t3; sm5[wid][4] = t4;
    }
    __syncthreads();
    if (half == 0 && lane == 0) {
        int ow = wid + 1;
        INS5(sm5[ow][0]); INS5(sm5[ow][1]); INS5(sm5[ow][2]); INS5(sm5[ow][3]); INS5(sm5[ow][4]);
        float iv = invr[row];
        conf5[0 * 4096 + row] = __expf(t0) * iv;
        conf5[1 * 4096 + row] = __expf(t1) * iv;
        conf5[2 * 4096 + row] = __expf(t2) * iv;
        conf5[3 * 4096 + row] = __expf(t3) * iv;
        conf5[4 * 4096 + row] = __expf(t4) * iv;
    }
}

// ---------- fp32 3x3 conv (head conv1, NCHW) ----------
__global__ void conv3x3_k(const float* __restrict__ in, const float* __restrict__ wgt,
                          const float* __restrict__ bias, float* __restrict__ out,
                          int Cin, int H, int W, int relu)
{
    int p = blockIdx.x * 256 + threadIdx.x;
    int HW = H * W;
    if (p >= HW) return;
    int co0 = blockIdx.y * 8;
    int y = p / W, x = p - y * W;
    float acc0 = bias[co0+0], acc1 = bias[co0+1], acc2 = bias[co0+2], acc3 = bias[co0+3];
    float acc4 = bias[co0+4], acc5 = bias[co0+5], acc6 = bias[co0+6], acc7 = bias[co0+7];
    bool ym = y > 0, yp = y < H-1, xm = x > 0, xp = x < W-1;
    for (int ci = 0; ci < Cin; ++ci) {
        const float* ip = in + (size_t)ci * HW + p;
        float v0 = (ym && xm) ? ip[-W-1] : 0.f;
        float v1 = (ym)       ? ip[-W]   : 0.f;
        float v2 = (ym && xp) ? ip[-W+1] : 0.f;
        float v3 = (xm)       ? ip[-1]   : 0.f;
        float v4 =              ip[0];
        float v5 = (xp)       ? ip[1]    : 0.f;
        float v6 = (yp && xm) ? ip[W-1]  : 0.f;
        float v7 = (yp)       ? ip[W]    : 0.f;
        float v8 = (yp && xp) ? ip[W+1]  : 0.f;
        const float* wp = wgt + ((size_t)co0 * Cin + ci) * 9;
        size_t ws = (size_t)Cin * 9;
#define CACC(q, a) { const float* wq = wp + q * ws; \
        a += wq[0]*v0 + wq[1]*v1 + wq[2]*v2 + wq[3]*v3 + wq[4]*v4 \
           + wq[5]*v5 + wq[6]*v6 + wq[7]*v7 + wq[8]*v8; }
        CACC(0, acc0) CACC(1, acc1) CACC(2, acc2) CACC(3, acc3)
        CACC(4, acc4) CACC(5, acc5) CACC(6, acc6) CACC(7, acc7)
#undef CACC
    }
#define CW(q, a) { float r = a; if (relu) r = fmaxf(r, 0.f); out[(size_t)(co0+q)*HW + p] = r; }
    CW(0, acc0) CW(1, acc1) CW(2, acc2) CW(3, acc3)
    CW(4, acc4) CW(5, acc5) CW(6, acc6) CW(7, acc7)
#undef CW
}

// ---------- head conv2 (8->8, relu) fused with 1x1 (8->1) ----------
__global__ void head2_k(const float* __restrict__ in, const float* __restrict__ wgt,
                        const float* __restrict__ bias, const float* __restrict__ w3,
                        const float* __restrict__ b3, float* __restrict__ out64)
{
    int p = blockIdx.x * 256 + threadIdx.x;
    int y = p >> 6, x = p & 63;
    float acc[8];
#pragma unroll
    for (int c = 0; c < 8; ++c) acc[c] = bias[c];
    bool ym = y > 0, yp = y < 63, xm = x > 0, xp = x < 63;
#pragma unroll
    for (int ci = 0; ci < 8; ++ci) {
        const float* ip = in + ci * 4096 + p;
        float v0 = (ym && xm) ? ip[-65] : 0.f;
        float v1 = (ym)       ? ip[-64] : 0.f;
        float v2 = (ym && xp) ? ip[-63] : 0.f;
        float v3 = (xm)       ? ip[-1]  : 0.f;
        float v4 =              ip[0];
        float v5 = (xp)       ? ip[1]   : 0.f;
        float v6 = (yp && xm) ? ip[63]  : 0.f;
        float v7 = (yp)       ? ip[64]  : 0.f;
        float v8 = (yp && xp) ? ip[65]  : 0.f;
#pragma unroll
        for (int co = 0; co < 8; ++co) {
            const float* wq = wgt + ((size_t)co * 8 + ci) * 9;
            acc[co] += wq[0]*v0 + wq[1]*v1 + wq[2]*v2 + wq[3]*v3 + wq[4]*v4
                     + wq[5]*v5 + wq[6]*v6 + wq[7]*v7 + wq[8]*v8;
        }
    }
    float o = b3[0];
#pragma unroll
    for (int c = 0; c < 8; ++c) o += w3[c] * fmaxf(acc[c], 0.f);
    out64[p] = o;
}

// ---------- fp32 bicubic (final output) ----------
__global__ void bicubic_k(const float* __restrict__ in, float* __restrict__ out,
                          int C, int Hin, int Win, int Hout, int Wout)
{
    int idx = blockIdx.x * 256 + threadIdx.x;
    int total = C * Hout * Wout;
    if (idx >= total) return;
    int X = idx % Wout;
    int Y = (idx / Wout) % Hout;
    int c = idx / (Wout * Hout);
    float sy = (float)Y * (float)(Hin - 1) / (float)(Hout - 1);
    float sx = (float)X * (float)(Win - 1) / (float)(Wout - 1);
    int fy = (int)floorf(sy), fx = (int)floorf(sx);
    float ty = sy - (float)fy, tx = sx - (float)fx;
    float wy[4], wx[4];
    cubw(ty, wy); cubw(tx, wx);
    const float* ip = in + (size_t)c * Hin * Win;
    float acc = 0.f;
#pragma unroll
    for (int i = 0; i < 4; ++i) {
        int yy = min(max(fy - 1 + i, 0), Hin - 1);
        float ra = 0.f;
#pragma unroll
        for (int j = 0; j < 4; ++j) {
            int xx = min(max(fx - 1 + j, 0), Win - 1);
            ra += wx[j] * ip[yy * Win + xx];
        }
        acc += wy[i] * ra;
    }
    out[idx] = acc;
}

// ---------- host ----------
extern "C" void kernel_launch(void* const* d_in, const int* in_sizes, int n_in,
                              void* d_out, int out_size, void* d_ws, size_t ws_size,
                              hipStream_t stream)
{
    const float* x_ref = (const float*)d_in[0];
    const float* x_tem = (const float*)d_in[1];
    const float* w0  = (const float*)d_in[2];   const float* b0  = (const float*)d_in[3];
    const float* w2  = (const float*)d_in[4];   const float* b2  = (const float*)d_in[5];
    const float* w5  = (const float*)d_in[6];   const float* b5  = (const float*)d_in[7];
    const float* w7  = (const float*)d_in[8];   const float* b7  = (const float*)d_in[9];
    const float* w10 = (const float*)d_in[10];  const float* b10 = (const float*)d_in[11];
    const float* w12 = (const float*)d_in[12];  const float* b12 = (const float*)d_in[13];
    const float* w14 = (const float*)d_in[14];  const float* b14 = (const float*)d_in[15];
    const float* coefr = (const float*)d_in[16];
    const float* coeft = (const float*)d_in[17];
    const float* fw1 = (const float*)d_in[18];  const float* fb1 = (const float*)d_in[19];
    const float* fw2 = (const float*)d_in[20];  const float* fb2 = (const float*)d_in[21];
    const float* fw3 = (const float*)d_in[22];  const float* fb3 = (const float*)d_in[23];
    float* out = (float*)d_out;

    char* wsp = (char*)d_ws;
    auto alloc = [&](size_t bytes) { char* p = wsp; wsp += (bytes + 255) & ~(size_t)255; return p; };
    ushort_t* F     = (ushort_t*)alloc(2 * FSTRIDE * 2);
    ushort_t* t0    = (ushort_t*)alloc(2 * TSTRIDE * 2);
    ushort_t* t1    = (ushort_t*)alloc(2 * TSTRIDE * 2);
    ushort_t* t2    = (ushort_t*)alloc(2 * TSTRIDE * 2);
    ushort_t* wT2   = (ushort_t*)alloc((size_t)64 * 64 * 9 * 2);
    ushort_t* wT5   = (ushort_t*)alloc((size_t)128 * 64 * 9 * 2);
    ushort_t* wT7   = (ushort_t*)alloc((size_t)128 * 128 * 9 * 2);
    ushort_t* wT10  = (ushort_t*)alloc((size_t)256 * 128 * 9 * 2);
    ushort_t* wT12  = (ushort_t*)alloc((size_t)256 * 256 * 9 * 2);
    ushort_t* wT14  = (ushort_t*)alloc((size_t)256 * 256 * 9 * 2);
    ushort_t* Abuf  = (ushort_t*)alloc((size_t)4096 * 320 * 2);
    char*     dist8 = (char*)alloc((size_t)4096 * 16384);
    float*    rpsum = (float*)alloc((size_t)128 * 4096 * 4);
    float*    cpsum = (float*)alloc((size_t)32 * 16384 * 4);
    float*    lc    = (float*)alloc(16384 * 4);
    float*    invr  = (float*)alloc(4096 * 4);
    float*    conf5 = (float*)alloc(5 * 4096 * 4);
    float*    h1    = (float*)alloc(8 * 4096 * 4);
    float*    out64 = (float*)alloc(4096 * 4);
    (void)ws_size; (void)n_in; (void)in_sizes; (void)out_size;

    // fused weight transforms
    WT6 wt;
    wt.src[0] = w2;  wt.dst[0] = wT2;  wt.co[0] = 64;  wt.ci[0] = 64;
    wt.src[1] = w5;  wt.dst[1] = wT5;  wt.co[1] = 128; wt.ci[1] = 64;
    wt.src[2] = w7;  wt.dst[2] = wT7;  wt.co[2] = 128; wt.ci[2] = 128;
    wt.src[3] = w10; wt.dst[3] = wT10; wt.co[3] = 256; wt.ci[3] = 128;
    wt.src[4] = w12; wt.dst[4] = wT12; wt.co[4] = 256; wt.ci[4] = 256;
    wt.src[5] = w14; wt.dst[5] = wT14; wt.co[5] = 256; wt.ci[5] = 256;
    int nblk = 0;
    for (int s = 0; s < 6; ++s) { wt.off[s] = nblk; nblk += (wt.co[s] * wt.ci[s] * 9 + 255) / 256; }
    wtrans6_k<<<nblk, 256, 0, stream>>>(wt);

    // batched feature extraction — ALL conv layers on 2-wave split-tap kernel
    conv0_k<<<dim3(4096, 2), 256, 0, stream>>>(x_ref, x_tem, w0, b0, F, t0);
    // conv2: 64->64 @128^2 (4096 waves)
    conv_mfma2w_k<64><<<dim3(512, 2, 2), 128, 0, stream>>>(t0, 64, TSTRIDE, wT2, b2, t1, 64, TSTRIDE, 128, 128, 64);
    maxpool_nhwc_k<<<dim3(128, 2), 256, 0, stream>>>(t1, t2, 64, 128, 128);
    // conv5: 64->128 @64^2 (2048 waves)
    conv_mfma2w_k<64><<<dim3(128, 4, 2), 128, 0, stream>>>(t2, 64, TSTRIDE, wT5, b5, t1, 128, TSTRIDE, 64, 64, 128);
    // conv7: 128->128 @64^2 (2048 waves)
    conv_mfma2w_k<128><<<dim3(128, 4, 2), 128, 0, stream>>>(t1, 128, TSTRIDE, wT7, b7, t2, 128, TSTRIDE, 64, 64, 128);
    maxpool_nhwc_k<<<dim3(64, 2), 256, 0, stream>>>(t2, t1, 128, 64, 64);
    conv_mfma2w_k<128><<<dim3(32, 8, 2), 128, 0, stream>>>(t1, 128, TSTRIDE, wT10, b10, t2, 256, TSTRIDE, 32, 32, 256);
    conv_mfma2w_k<256><<<dim3(32, 8, 2), 128, 0, stream>>>(t2, 256, TSTRIDE, wT12, b12, t1, 256, TSTRIDE, 32, 32, 256);
    conv_mfma2w_k<256><<<dim3(32, 8, 2), 128, 0, stream>>>(t1, 256, TSTRIDE, wT14, b14, t2, 256, TSTRIDE, 32, 32, 256);
    upnorm_k<<<dim3(4096, 2), 256, 0, stream>>>(t2, F, Abuf);

    gemm_corr_k<<<dim3(128, 32), 256, 0, stream>>>(Abuf, F + FSTRIDE, dist8, coefr, coeft, rpsum, cpsum);

    finboth_k<<<80, 256, 0, stream>>>(cpsum, rpsum, lc, invr);

    row_topk_k<<<2048, 256, 0, stream>>>(dist8, lc, invr, coefr, coeft, conf5);

    conv3x3_k<<<dim3(16, 1), 256, 0, stream>>>(conf5, fw1, fb1, h1, 5, 64, 64, 1);
    head2_k<<<16, 256, 0, stream>>>(h1, fw2, fb2, fw3, fb3, out64);
    bicubic_k<<<64, 256, 0, stream>>>(out64, out, 1, 64, 64, 128, 128);
}

// Round 16
// 374.704 us; speedup vs baseline: 1.0687x; 1.0076x over previous
//
#include <hip/hip_runtime.h>
#include <math.h>

typedef unsigned short ushort_t;
typedef unsigned int uint_t;
typedef __attribute__((ext_vector_type(8))) short bf16x8;
typedef __attribute__((ext_vector_type(4))) float f32x4;

#define FSTRIDE ((size_t)16384 * 320)
#define TSTRIDE ((size_t)16384 * 64)

// ---------- bf16 helpers ----------
__device__ inline ushort_t f2bf(float f) {
    union { float f; uint_t u; } x; x.f = f;
    uint_t r = x.u + 0x7fffu + ((x.u >> 16) & 1u);
    return (ushort_t)(r >> 16);
}
__device__ inline float bf2f(ushort_t h) {
    union { uint_t u; float f; } x; x.u = ((uint_t)h) << 16;
    return x.f;
}
__device__ inline float bflo(uint_t u) {
    union { uint_t u; float f; } x; x.u = u << 16; return x.f;
}
__device__ inline float bfhi(uint_t u) {
    union { uint_t u; float f; } x; x.u = u & 0xffff0000u; return x.f;
}

// ---------- fused weight transform: 6 conv layers, OIHW fp32 -> [tap][co][ci] bf16 ----------
struct WT6 {
    const float* src[6];
    ushort_t* dst[6];
    int co[6], ci[6];
    int off[6];
};
__global__ void wtrans6_k(WT6 a)
{
    int b = blockIdx.x, seg = 0;
#pragma unroll
    for (int s = 1; s < 6; ++s) if (b >= a.off[s]) seg = s;
    int idx = (b - a.off[seg]) * 256 + threadIdx.x;
    int CO = a.co[seg], CI = a.ci[seg];
    if (idx >= CO * CI * 9) return;
    int tap = idx % 9;
    int rem = idx / 9;
    int ci = rem % CI;
    int co = rem / CI;
    a.dst[seg][((size_t)tap * CO + co) * CI + ci] = f2bf(a.src[seg][idx]);
}

// ---------- conv0: 3->64 @128x128, NCHW fp32 in; writes F cols 0..63 AND compact t0 ----------
__global__ __launch_bounds__(256) void conv0_k(const float* __restrict__ x0, const float* __restrict__ x1,
                                               const float* __restrict__ w,
                                               const float* __restrict__ b, ushort_t* __restrict__ F,
                                               ushort_t* __restrict__ t0)
{
    const float* x = blockIdx.y ? x1 : x0;
    F += (size_t)blockIdx.y * FSTRIDE;
    t0 += (size_t)blockIdx.y * TSTRIDE;
    int co = threadIdx.x & 63;
    int p = blockIdx.x * 4 + (threadIdx.x >> 6);
    int y = p >> 7, xx = p & 127;
    float acc = b[co];
#pragma unroll
    for (int ci = 0; ci < 3; ++ci) {
#pragma unroll
        for (int t = 0; t < 9; ++t) {
            int dy = t / 3 - 1, dx = t % 3 - 1;
            int yy = y + dy, xc = xx + dx;
            if ((unsigned)yy < 128u && (unsigned)xc < 128u) {
                acc += x[ci * 16384 + yy * 128 + xc] * w[co * 27 + ci * 9 + t];
            }
        }
    }
    ushort_t r = f2bf(fmaxf(acc, 0.f));
    F[(size_t)p * 320 + co] = r;
    t0[(size_t)p * 64 + co] = r;
}

// ---------- 2-wave split-tap implicit-GEMM MFMA conv 3x3 pad=1 (32x32 tile) ----------
template<int CI>
__global__ __launch_bounds__(128) void conv_mfma2w_k(
    const ushort_t* __restrict__ in, int ldin, size_t inImgStride,
    const ushort_t* __restrict__ wT, const float* __restrict__ bias,
    ushort_t* __restrict__ out, int ldout, size_t outImgStride,
    int H, int W, int CO)
{
    __shared__ float red[64][17];
    in += (size_t)blockIdx.z * inImgStride;
    out += (size_t)blockIdx.z * outImgStride;
    const int lane = threadIdx.x & 63;
    const int wv = threadIdx.x >> 6;
    const int m0 = blockIdx.x * 32;
    const int n0 = blockIdx.y * 32;
    const int fr = lane & 15;
    const int fo = (lane >> 4) << 3;

    size_t abase[2];
    unsigned vmask[2];
#pragma unroll
    for (int mi = 0; mi < 2; ++mi) {
        int p = m0 + mi * 16 + fr;
        int y = p / W, x = p % W;
        abase[mi] = (size_t)p * ldin + fo;
        unsigned vm = 0;
#pragma unroll
        for (int t = 0; t < 9; ++t) {
            int dy = t / 3 - 1, dx = t % 3 - 1;
            if ((unsigned)(y + dy) < (unsigned)H && (unsigned)(x + dx) < (unsigned)W) vm |= 1u << t;
        }
        vmask[mi] = vm;
    }

    f32x4 zero = {0.f, 0.f, 0.f, 0.f};
    f32x4 acc[2][2] = {{zero, zero}, {zero, zero}};
    const bf16x8 zz = {0, 0, 0, 0, 0, 0, 0, 0};

    const int tb = wv ? 5 : 0;
    const int te = wv ? 9 : 5;
    for (int t = tb; t < te; ++t) {
        int toff = ((t / 3 - 1) * W + (t % 3 - 1)) * ldin;
        bool v0 = (vmask[0] >> t) & 1u;
        bool v1 = (vmask[1] >> t) & 1u;
        const ushort_t* wp0 = wT + ((size_t)(t * CO + n0 + fr)) * CI + fo;
        const ushort_t* wp1 = wp0 + (size_t)16 * CI;
#pragma unroll
        for (int kc = 0; kc < CI / 32; ++kc) {
            int k0 = kc * 32;
            bf16x8 a0 = v0 ? *(const bf16x8*)(in + abase[0] + toff + k0) : zz;
            bf16x8 a1 = v1 ? *(const bf16x8*)(in + abase[1] + toff + k0) : zz;
            bf16x8 b0 = *(const bf16x8*)(wp0 + k0);
            bf16x8 b1 = *(const bf16x8*)(wp1 + k0);
            acc[0][0] = __builtin_amdgcn_mfma_f32_16x16x32_bf16(b0, a0, acc[0][0], 0, 0, 0);
            acc[0][1] = __builtin_amdgcn_mfma_f32_16x16x32_bf16(b1, a0, acc[0][1], 0, 0, 0);
            acc[1][0] = __builtin_amdgcn_mfma_f32_16x16x32_bf16(b0, a1, acc[1][0], 0, 0, 0);
            acc[1][1] = __builtin_amdgcn_mfma_f32_16x16x32_bf16(b1, a1, acc[1][1], 0, 0, 0);
        }
    }

    if (wv == 1) {
#pragma unroll
        for (int mi = 0; mi < 2; ++mi)
#pragma unroll
            for (int ni = 0; ni < 2; ++ni)
#pragma unroll
                for (int r = 0; r < 4; ++r)
                    red[lane][mi * 8 + ni * 4 + r] = acc[mi][ni][r];
    }
    __syncthreads();
    if (wv == 0) {
#pragma unroll
        for (int mi = 0; mi < 2; ++mi) {
#pragma unroll
            for (int ni = 0; ni < 2; ++ni) {
                int pix = m0 + mi * 16 + (lane & 15);
                int ch = n0 + ni * 16 + ((lane >> 4) << 2);
                float4 bv = *(const float4*)(bias + ch);
                float r0 = fmaxf(acc[mi][ni][0] + red[lane][mi * 8 + ni * 4 + 0] + bv.x, 0.f);
                float r1 = fmaxf(acc[mi][ni][1] + red[lane][mi * 8 + ni * 4 + 1] + bv.y, 0.f);
                float r2 = fmaxf(acc[mi][ni][2] + red[lane][mi * 8 + ni * 4 + 2] + bv.z, 0.f);
                float r3 = fmaxf(acc[mi][ni][3] + red[lane][mi * 8 + ni * 4 + 3] + bv.w, 0.f);
                uint2 pk;
                pk.x = (uint_t)f2bf(r0) | ((uint_t)f2bf(r1) << 16);
                pk.y = (uint_t)f2bf(r2) | ((uint_t)f2bf(r3) << 16);
                *(uint2*)(out + (size_t)pix * ldout + ch) = pk;
            }
        }
    }
}

// ---------- 2x2 maxpool NHWC bf16 (batched via blockIdx.y) ----------
__global__ void maxpool_nhwc_k(const ushort_t* __restrict__ in, ushort_t* __restrict__ out,
                               int C, int Hi, int Wi)
{
    in += (size_t)blockIdx.y * TSTRIDE;
    out += (size_t)blockIdx.y * TSTRIDE;
    int idx = blockIdx.x * 256 + threadIdx.x;
    int CG = C >> 3;
    int Wo = Wi >> 1, Ho = Hi >> 1;
    if (idx >= Ho * Wo * CG) return;
    int cg = idx % CG;
    int p = idx / CG;
    int y = p / Wo, x = p % Wo;
    const ushort_t* ip = in + ((size_t)(2 * y) * Wi + 2 * x) * C + cg * 8;
    bf16x8 v0 = *(const bf16x8*)(ip);
    bf16x8 v1 = *(const bf16x8*)(ip + C);
    bf16x8 v2 = *(const bf16x8*)(ip + (size_t)Wi * C);
    bf16x8 v3 = *(const bf16x8*)(ip + (size_t)Wi * C + C);
    bf16x8 r;
#pragma unroll
    for (int j = 0; j < 8; ++j) {
        float m = fmaxf(fmaxf(bf2f((ushort_t)v0[j]), bf2f((ushort_t)v1[j])),
                        fmaxf(bf2f((ushort_t)v2[j]), bf2f((ushort_t)v3[j])));
        r[j] = (short)f2bf(m);
    }
    *(bf16x8*)(out + (size_t)p * C + cg * 8) = r;
}

// ---------- bicubic weights (align_corners=True), PyTorch A=-0.75 ----------
__device__ inline void cubw(float t, float* w) {
    float x0 = 1.f + t, x2 = 1.f - t, x3 = 2.f - t;
    w[0] = ((-0.75f*x0 + 3.75f)*x0 - 6.f)*x0 + 3.f;
    w[1] = (1.25f*t - 2.25f)*t*t + 1.f;
    w[2] = (1.25f*x2 - 2.25f)*x2*x2 + 1.f;
    w[3] = ((-0.75f*x3 + 3.75f)*x3 - 6.f)*x3 + 3.f;
}

// ---------- fused: bicubic 32->128 + L2 norm; img0 additionally 2x2-mean-pools into Abuf ----------
__global__ __launch_bounds__(256) void upnorm_k(const ushort_t* __restrict__ in, ushort_t* __restrict__ F,
                                                ushort_t* __restrict__ Abuf)
{
    __shared__ float sm[4][320];
    in += (size_t)blockIdx.y * TSTRIDE;
    F += (size_t)blockIdx.y * FSTRIDE;
    int wid = threadIdx.x >> 6, lane = threadIdx.x & 63;
    int pb = blockIdx.x;
    int py = pb >> 6, px = pb & 63;
    int p = (2 * py + (wid >> 1)) * 128 + 2 * px + (wid & 1);
    int Y = p >> 7, X = p & 127;
    float sy = (float)Y * (31.f / 127.f);
    float sx = (float)X * (31.f / 127.f);
    int fy = (int)floorf(sy), fx = (int)floorf(sx);
    float ty = sy - (float)fy, tx = sx - (float)fx;
    float wy[4], wx[4];
    cubw(ty, wy); cubw(tx, wx);
    float a0 = 0.f, a1 = 0.f, a2 = 0.f, a3 = 0.f;
#pragma unroll
    for (int i = 0; i < 4; ++i) {
        int yy = min(max(fy - 1 + i, 0), 31);
#pragma unroll
        for (int j = 0; j < 4; ++j) {
            int xx = min(max(fx - 1 + j, 0), 31);
            float w = wy[i] * wx[j];
            uint2 v = *(const uint2*)(in + ((size_t)yy * 32 + xx) * 256 + lane * 4);
            a0 += w * bflo(v.x); a1 += w * bfhi(v.x);
            a2 += w * bflo(v.y); a3 += w * bfhi(v.y);
        }
    }
    float v0 = bf2f(f2bf(a0)), v1 = bf2f(f2bf(a1)), v2 = bf2f(f2bf(a2)), v3 = bf2f(f2bf(a3));
    float c0 = bf2f(F[(size_t)p * 320 + lane]);
    float ss = c0 * c0 + v0 * v0 + v1 * v1 + v2 * v2 + v3 * v3;
#pragma unroll
    for (int off = 32; off > 0; off >>= 1) ss += __shfl_xor(ss, off);
    float inv = 1.f / (1e-8f + sqrtf(ss));
    if (blockIdx.y == 1) {
        F[(size_t)p * 320 + lane] = f2bf(c0 * inv);
        uint2 pk;
        pk.x = (uint_t)f2bf(v0 * inv) | ((uint_t)f2bf(v1 * inv) << 16);
        pk.y = (uint_t)f2bf(v2 * inv) | ((uint_t)f2bf(v3 * inv) << 16);
        *(uint2*)(F + (size_t)p * 320 + 64 + lane * 4) = pk;
    } else {
        sm[wid][lane] = bf2f(f2bf(c0 * inv));
        sm[wid][64 + lane * 4 + 0] = bf2f(f2bf(v0 * inv));
        sm[wid][64 + lane * 4 + 1] = bf2f(f2bf(v1 * inv));
        sm[wid][64 + lane * 4 + 2] = bf2f(f2bf(v2 * inv));
        sm[wid][64 + lane * 4 + 3] = bf2f(f2bf(v3 * inv));
        __syncthreads();
        for (int ch = threadIdx.x; ch < 320; ch += 256) {
            float a = 0.25f * (sm[0][ch] + sm[1][ch] + sm[2][ch] + sm[3][ch]);
            Abuf[(size_t)pb * 320 + ch] = f2bf(a);
        }
    }
}

// ---------- correlation GEMM + fused softmax-denominator partials ----------
// BK=64 pairing: 2 K-tiles per barrier round (10 barriers instead of 20,
// 32 MFMA per compute phase). Named ping-pong reg sets (rule #20).
__global__ __launch_bounds__(256) void gemm_corr_k(
    const ushort_t* __restrict__ A, const ushort_t* __restrict__ B, char* __restrict__ D8,
    const float* __restrict__ coefr, const float* __restrict__ coeft,
    float* __restrict__ rpsum, float* __restrict__ cpsum)
{
    __shared__ ushort_t lA[2][128 * 32];
    __shared__ ushort_t lB[2][128 * 32];
    __shared__ float cl[2][128];
    __shared__ float rl[2][128];
    const int tid = threadIdx.x;
    const int lane = tid & 63;
    const int wid = tid >> 6;
    const int wr = wid >> 1, wc = wid & 1;
    const int m0 = blockIdx.y * 128, n0 = blockIdx.x * 128;
    const int fr = lane & 15;
    const int fo = (lane >> 4) << 3;
    const int srow = tid >> 2;
    const int scol = (tid & 3) << 3;

    const ushort_t* Ag0 = A + (size_t)(m0 + srow) * 320 + scol;
    const ushort_t* Ag1 = Ag0 + (size_t)64 * 320;
    const ushort_t* Bg0 = B + (size_t)(n0 + srow) * 320 + scol;
    const ushort_t* Bg1 = Bg0 + (size_t)64 * 320;

    f32x4 zero = {0.f, 0.f, 0.f, 0.f};
    f32x4 acc[4][4];
#pragma unroll
    for (int i = 0; i < 4; ++i)
#pragma unroll
        for (int j = 0; j < 4; ++j) acc[i][j] = zero;

    uint4 pA0, pA1, pB0, pB1;   // tile 2tt
    uint4 qA0, qA1, qB0, qB1;   // tile 2tt+1

#define GLOAD(rA0, rA1, rB0, rB1, kk) { \
        rA0 = *(const uint4*)(Ag0 + (kk)); \
        rA1 = *(const uint4*)(Ag1 + (kk)); \
        rB0 = *(const uint4*)(Bg0 + (kk)); \
        rB1 = *(const uint4*)(Bg1 + (kk)); }

#define DSW(buf, rA0, rA1, rB0, rB1) { \
        *(uint4*)&lA[buf][srow * 32 + scol] = rA0; \
        *(uint4*)&lA[buf][(64 + srow) * 32 + scol] = rA1; \
        *(uint4*)&lB[buf][srow * 32 + scol] = rB0; \
        *(uint4*)&lB[buf][(64 + srow) * 32 + scol] = rB1; }

#define CMP(buf) { \
        bf16x8 af[4], bfr[4]; \
        _Pragma("unroll") \
        for (int mi = 0; mi < 4; ++mi) \
            af[mi] = *(const bf16x8*)&lA[buf][(wr * 64 + mi * 16 + fr) * 32 + fo]; \
        _Pragma("unroll") \
        for (int ni = 0; ni < 4; ++ni) \
            bfr[ni] = *(const bf16x8*)&lB[buf][(wc * 64 + ni * 16 + fr) * 32 + fo]; \
        _Pragma("unroll") \
        for (int mi = 0; mi < 4; ++mi) \
            _Pragma("unroll") \
            for (int ni = 0; ni < 4; ++ni) \
                acc[mi][ni] = __builtin_amdgcn_mfma_f32_16x16x32_bf16(bfr[ni], af[mi], acc[mi][ni], 0, 0, 0); }

    GLOAD(pA0, pA1, pB0, pB1, 0)
    GLOAD(qA0, qA1, qB0, qB1, 32)
#pragma unroll
    for (int tt = 0; tt < 5; ++tt) {
        __syncthreads();                     // round tt-1's reads done
        DSW(0, pA0, pA1, pB0, pB1)
        DSW(1, qA0, qA1, qB0, qB1)
        if (tt < 4) {                        // prefetch next pair (lives in VGPRs)
            GLOAD(pA0, pA1, pB0, pB1, 64 * tt + 64)
            GLOAD(qA0, qA1, qB0, qB1, 64 * tt + 96)
        }
        __syncthreads();                     // publish both tiles
        CMP(0)
        CMP(1)
    }
#undef GLOAD
#undef DSW
#undef CMP

    const float s = 1.0f / 320.0f;
    const float cr = coefr[0], ct = coeft[0];
    const bool sameCoef = (cr == ct);
    float rpx[4] = {0.f, 0.f, 0.f, 0.f};
    float cpx[4][4];
#pragma unroll
    for (int ni = 0; ni < 4; ++ni)
#pragma unroll
        for (int r = 0; r < 4; ++r) cpx[ni][r] = 0.f;

    const int mrow = lane & 15;
    const int ng = (lane >> 4) << 2;
#pragma unroll
    for (int mi = 0; mi < 4; ++mi) {
        int m = m0 + wr * 64 + mi * 16 + mrow;
        char* drow = D8 + (size_t)m * 16384;
#pragma unroll
        for (int ni = 0; ni < 4; ++ni) {
            int n = n0 + wc * 64 + ni * 16 + ng;
            float d0 = acc[mi][ni][0] * s;
            float d1 = acc[mi][ni][1] * s;
            float d2 = acc[mi][ni][2] * s;
            float d3 = acc[mi][ni][3] * s;
            int q0 = __float2int_rn(fminf(fmaxf(d0 * 40640.f, -127.f), 127.f));
            int q1 = __float2int_rn(fminf(fmaxf(d1 * 40640.f, -127.f), 127.f));
            int q2 = __float2int_rn(fminf(fmaxf(d2 * 40640.f, -127.f), 127.f));
            int q3 = __float2int_rn(fminf(fmaxf(d3 * 40640.f, -127.f), 127.f));
            uint_t pk8 = (uint_t)(q0 & 255) | ((uint_t)(q1 & 255) << 8)
                       | ((uint_t)(q2 & 255) << 16) | ((uint_t)(q3 & 255) << 24);
            *(uint_t*)(drow + n) = pk8;
            float e0 = __expf(cr * d0), e1 = __expf(cr * d1);
            float e2 = __expf(cr * d2), e3 = __expf(cr * d3);
            cpx[ni][0] += e0; cpx[ni][1] += e1; cpx[ni][2] += e2; cpx[ni][3] += e3;
            if (sameCoef) {
                rpx[mi] += e0 + e1 + e2 + e3;
            } else {
                rpx[mi] += __expf(ct * d0) + __expf(ct * d1) + __expf(ct * d2) + __expf(ct * d3);
            }
        }
    }
#pragma unroll
    for (int mi = 0; mi < 4; ++mi) {
        rpx[mi] += __shfl_xor(rpx[mi], 16);
        rpx[mi] += __shfl_xor(rpx[mi], 32);
    }
    if (lane < 16) {
#pragma unroll
        for (int mi = 0; mi < 4; ++mi)
            rl[wc][wr * 64 + mi * 16 + lane] = rpx[mi];
    }
#pragma unroll
    for (int ni = 0; ni < 4; ++ni)
#pragma unroll
        for (int r = 0; r < 4; ++r) {
            cpx[ni][r] += __shfl_xor(cpx[ni][r], 1);
            cpx[ni][r] += __shfl_xor(cpx[ni][r], 2);
            cpx[ni][r] += __shfl_xor(cpx[ni][r], 4);
            cpx[ni][r] += __shfl_xor(cpx[ni][r], 8);
        }
    if ((lane & 15) == 0) {
        int g = lane >> 4;
#pragma unroll
        for (int ni = 0; ni < 4; ++ni)
#pragma unroll
            for (int r = 0; r < 4; ++r)
                cl[wr][wc * 64 + ni * 16 + g * 4 + r] = cpx[ni][r];
    }
    __syncthreads();
    if (tid < 128) {
        cpsum[(size_t)blockIdx.y * 16384 + n0 + tid] = cl[0][tid] + cl[1][tid];
        rpsum[(size_t)blockIdx.x * 4096 + m0 + tid] = rl[0][tid] + rl[1][tid];
    }
}

// ---------- fused finalize: lc[j] = -0.5*log(colsum); invr[m] = rsqrt(rowsum) ----------
__global__ void finboth_k(const float* __restrict__ cpsum, const float* __restrict__ rpsum,
                          float* __restrict__ lc, float* __restrict__ invr)
{
    int b = blockIdx.x;
    if (b < 64) {
        int j = b * 256 + threadIdx.x;
        float s = 0.f;
#pragma unroll
        for (int k = 0; k < 32; ++k) s += cpsum[(size_t)k * 16384 + j];
        lc[j] = -0.5f * __logf(s);
    } else {
        int m = (b - 64) * 256 + threadIdx.x;
        float s = 0.f;
#pragma unroll
        for (int k = 0; k < 128; ++k) s += rpsum[(size_t)k * 4096 + m];
        invr[m] = rsqrtf(s);
    }
}

// ---------- per-row top-5 on int8 dist: 2 waves per row, LDS pair-merge ----------
#define INS5(w_) { float w = (w_); float mx; \
    mx = fmaxf(w, t0); w = fminf(w, t0); t0 = mx; \
    mx = fmaxf(w, t1); w = fminf(w, t1); t1 = mx; \
    mx = fmaxf(w, t2); w = fminf(w, t2); t2 = mx; \
    mx = fmaxf(w, t3); w = fminf(w, t3); t3 = mx; \
    t4 = fmaxf(w, t4); }
#define SB(w, sft) ((float)(int)(signed char)(((w) >> (sft)) & 0xffu))

__global__ __launch_bounds__(256) void row_topk_k(
    const char* __restrict__ D8, const float* __restrict__ lc,
    const float* __restrict__ invr,
    const float* __restrict__ coefr, const float* __restrict__ coeft,
    float* __restrict__ conf5)
{
    __shared__ float sm5[4][5];
    int wid = threadIdx.x >> 6, lane = threadIdx.x & 63;
    int row = blockIdx.x * 2 + (wid >> 1);
    int half = wid & 1;
    float hc = 0.5f * (coefr[0] + coeft[0]);
    float hq = hc * (1.0f / 40640.f);
    const char* rp = D8 + (size_t)row * 16384;

    float t0 = -1e30f, t1 = -1e30f, t2 = -1e30f, t3 = -1e30f, t4 = -1e30f;
    for (int i = 0; i < 8; ++i) {
        int cw = half * 512 + i * 64 + lane;
        uint4 u = *(const uint4*)(rp + cw * 16);
        int col = cw * 16;
        float4 l0 = *(const float4*)(lc + col);
        float4 l1 = *(const float4*)(lc + col + 4);
        float4 l2 = *(const float4*)(lc + col + 8);
        float4 l3 = *(const float4*)(lc + col + 12);
        float k0  = fmaf(hq, SB(u.x, 0),  l0.x);
        float k1  = fmaf(hq, SB(u.x, 8),  l0.y);
        float k2  = fmaf(hq, SB(u.x, 16), l0.z);
        float k3  = fmaf(hq, SB(u.x, 24), l0.w);
        float k4  = fmaf(hq, SB(u.y, 0),  l1.x);
        float k5  = fmaf(hq, SB(u.y, 8),  l1.y);
        float k6  = fmaf(hq, SB(u.y, 16), l1.z);
        float k7  = fmaf(hq, SB(u.y, 24), l1.w);
        float k8  = fmaf(hq, SB(u.z, 0),  l2.x);
        float k9  = fmaf(hq, SB(u.z, 8),  l2.y);
        float k10 = fmaf(hq, SB(u.z, 16), l2.z);
        float k11 = fmaf(hq, SB(u.z, 24), l2.w);
        float k12 = fmaf(hq, SB(u.w, 0),  l3.x);
        float k13 = fmaf(hq, SB(u.w, 8),  l3.y);
        float k14 = fmaf(hq, SB(u.w, 16), l3.z);
        float k15 = fmaf(hq, SB(u.w, 24), l3.w);
        float ma = fmaxf(fmaxf(fmaxf(k0, k1), fmaxf(k2, k3)),
                         fmaxf(fmaxf(k4, k5), fmaxf(k6, k7)));
        float mb = fmaxf(fmaxf(fmaxf(k8, k9), fmaxf(k10, k11)),
                         fmaxf(fmaxf(k12, k13), fmaxf(k14, k15)));
        if (fmaxf(ma, mb) > t4) {
            INS5(k0);  INS5(k1);  INS5(k2);  INS5(k3);
            INS5(k4);  INS5(k5);  INS5(k6);  INS5(k7);
            INS5(k8);  INS5(k9);  INS5(k10); INS5(k11);
            INS5(k12); INS5(k13); INS5(k14); INS5(k15);
        }
    }
#pragma unroll
    for (int off = 1; off < 64; off <<= 1) {
        float o0 = __shfl_xor(t0, off), o1 = __shfl_xor(t1, off), o2 = __shfl_xor(t2, off);
        float o3 = __shfl_xor(t3, off), o4 = __shfl_xor(t4, off);
        INS5(o0); INS5(o1); INS5(o2); INS5(o3); INS5(o4);
    }
    if (lane == 0) {
        sm5[wid][0] = t0; sm5[wid][1] = t1; sm5[wid][2] = t2; sm5[wid][3] = t3; sm5[wid][4] = t4;
    }
    __syncthreads();
    if (half == 0 && lane == 0) {
        int ow = wid + 1;
        INS5(sm5[ow][0]); INS5(sm5[ow][1]); INS5(sm5[ow][2]); INS5(sm5[ow][3]); INS5(sm5[ow][4]);
        float iv = invr[row];
        conf5[0 * 4096 + row] = __expf(t0) * iv;
        conf5[1 * 4096 + row] = __expf(t1) * iv;
        conf5[2 * 4096 + row] = __expf(t2) * iv;
        conf5[3 * 4096 + row] = __expf(t3) * iv;
        conf5[4 * 4096 + row] = __expf(t4) * iv;
    }
}

// ---------- fp32 3x3 conv (head conv1, NCHW) ----------
__global__ void conv3x3_k(const float* __restrict__ in, const float* __restrict__ wgt,
                          const float* __restrict__ bias, float* __restrict__ out,
                          int Cin, int H, int W, int relu)
{
    int p = blockIdx.x * 256 + threadIdx.x;
    int HW = H * W;
    if (p >= HW) return;
    int co0 = blockIdx.y * 8;
    int y = p / W, x = p - y * W;
    float acc0 = bias[co0+0], acc1 = bias[co0+1], acc2 = bias[co0+2], acc3 = bias[co0+3];
    float acc4 = bias[co0+4], acc5 = bias[co0+5], acc6 = bias[co0+6], acc7 = bias[co0+7];
    bool ym = y > 0, yp = y < H-1, xm = x > 0, xp = x < W-1;
    for (int ci = 0; ci < Cin; ++ci) {
        const float* ip = in + (size_t)ci * HW + p;
        float v0 = (ym && xm) ? ip[-W-1] : 0.f;
        float v1 = (ym)       ? ip[-W]   : 0.f;
        float v2 = (ym && xp) ? ip[-W+1] : 0.f;
        float v3 = (xm)       ? ip[-1]   : 0.f;
        float v4 =              ip[0];
        float v5 = (xp)       ? ip[1]    : 0.f;
        float v6 = (yp && xm) ? ip[W-1]  : 0.f;
        float v7 = (yp)       ? ip[W]    : 0.f;
        float v8 = (yp && xp) ? ip[W+1]  : 0.f;
        const float* wp = wgt + ((size_t)co0 * Cin + ci) * 9;
        size_t ws = (size_t)Cin * 9;
#define CACC(q, a) { const float* wq = wp + q * ws; \
        a += wq[0]*v0 + wq[1]*v1 + wq[2]*v2 + wq[3]*v3 + wq[4]*v4 \
           + wq[5]*v5 + wq[6]*v6 + wq[7]*v7 + wq[8]*v8; }
        CACC(0, acc0) CACC(1, acc1) CACC(2, acc2) CACC(3, acc3)
        CACC(4, acc4) CACC(5, acc5) CACC(6, acc6) CACC(7, acc7)
#undef CACC
    }
#define CW(q, a) { float r = a; if (relu) r = fmaxf(r, 0.f); out[(size_t)(co0+q)*HW + p] = r; }
    CW(0, acc0) CW(1, acc1) CW(2, acc2) CW(3, acc3)
    CW(4, acc4) CW(5, acc5) CW(6, acc6) CW(7, acc7)
#undef CW
}

// ---------- head conv2 (8->8, relu) fused with 1x1 (8->1) ----------
__global__ void head2_k(const float* __restrict__ in, const float* __restrict__ wgt,
                        const float* __restrict__ bias, const float* __restrict__ w3,
                        const float* __restrict__ b3, float* __restrict__ out64)
{
    int p = blockIdx.x * 256 + threadIdx.x;
    int y = p >> 6, x = p & 63;
    float acc[8];
#pragma unroll
    for (int c = 0; c < 8; ++c) acc[c] = bias[c];
    bool ym = y > 0, yp = y < 63, xm = x > 0, xp = x < 63;
#pragma unroll
    for (int ci = 0; ci < 8; ++ci) {
        const float* ip = in + ci * 4096 + p;
        float v0 = (ym && xm) ? ip[-65] : 0.f;
        float v1 = (ym)       ? ip[-64] : 0.f;
        float v2 = (ym && xp) ? ip[-63] : 0.f;
        float v3 = (xm)       ? ip[-1]  : 0.f;
        float v4 =              ip[0];
        float v5 = (xp)       ? ip[1]   : 0.f;
        float v6 = (yp && xm) ? ip[63]  : 0.f;
        float v7 = (yp)       ? ip[64]  : 0.f;
        float v8 = (yp && xp) ? ip[65]  : 0.f;
#pragma unroll
        for (int co = 0; co < 8; ++co) {
            const float* wq = wgt + ((size_t)co * 8 + ci) * 9;
            acc[co] += wq[0]*v0 + wq[1]*v1 + wq[2]*v2 + wq[3]*v3 + wq[4]*v4
                     + wq[5]*v5 + wq[6]*v6 + wq[7]*v7 + wq[8]*v8;
        }
    }
    float o = b3[0];
#pragma unroll
    for (int c = 0; c < 8; ++c) o += w3[c] * fmaxf(acc[c], 0.f);
    out64[p] = o;
}

// ---------- fp32 bicubic (final output) ----------
__global__ void bicubic_k(const float* __restrict__ in, float* __restrict__ out,
                          int C, int Hin, int Win, int Hout, int Wout)
{
    int idx = blockIdx.x * 256 + threadIdx.x;
    int total = C * Hout * Wout;
    if (idx >= total) return;
    int X = idx % Wout;
    int Y = (idx / Wout) % Hout;
    int c = idx / (Wout * Hout);
    float sy = (float)Y * (float)(Hin - 1) / (float)(Hout - 1);
    float sx = (float)X * (float)(Win - 1) / (float)(Wout - 1);
    int fy = (int)floorf(sy), fx = (int)floorf(sx);
    float ty = sy - (float)fy, tx = sx - (float)fx;
    float wy[4], wx[4];
    cubw(ty, wy); cubw(tx, wx);
    const float* ip = in + (size_t)c * Hin * Win;
    float acc = 0.f;
#pragma unroll
    for (int i = 0; i < 4; ++i) {
        int yy = min(max(fy - 1 + i, 0), Hin - 1);
        float ra = 0.f;
#pragma unroll
        for (int j = 0; j < 4; ++j) {
            int xx = min(max(fx - 1 + j, 0), Win - 1);
            ra += wx[j] * ip[yy * Win + xx];
        }
        acc += wy[i] * ra;
    }
    out[idx] = acc;
}

// ---------- host ----------
extern "C" void kernel_launch(void* const* d_in, const int* in_sizes, int n_in,
                              void* d_out, int out_size, void* d_ws, size_t ws_size,
                              hipStream_t stream)
{
    const float* x_ref = (const float*)d_in[0];
    const float* x_tem = (const float*)d_in[1];
    const float* w0  = (const float*)d_in[2];   const float* b0  = (const float*)d_in[3];
    const float* w2  = (const float*)d_in[4];   const float* b2  = (const float*)d_in[5];
    const float* w5  = (const float*)d_in[6];   const float* b5  = (const float*)d_in[7];
    const float* w7  = (const float*)d_in[8];   const float* b7  = (const float*)d_in[9];
    const float* w10 = (const float*)d_in[10];  const float* b10 = (const float*)d_in[11];
    const float* w12 = (const float*)d_in[12];  const float* b12 = (const float*)d_in[13];
    const float* w14 = (const float*)d_in[14];  const float* b14 = (const float*)d_in[15];
    const float* coefr = (const float*)d_in[16];
    const float* coeft = (const float*)d_in[17];
    const float* fw1 = (const float*)d_in[18];  const float* fb1 = (const float*)d_in[19];
    const float* fw2 = (const float*)d_in[20];  const float* fb2 = (const float*)d_in[21];
    const float* fw3 = (const float*)d_in[22];  const float* fb3 = (const float*)d_in[23];
    float* out = (float*)d_out;

    char* wsp = (char*)d_ws;
    auto alloc = [&](size_t bytes) { char* p = wsp; wsp += (bytes + 255) & ~(size_t)255; return p; };
    ushort_t* F     = (ushort_t*)alloc(2 * FSTRIDE * 2);
    ushort_t* t0    = (ushort_t*)alloc(2 * TSTRIDE * 2);
    ushort_t* t1    = (ushort_t*)alloc(2 * TSTRIDE * 2);
    ushort_t* t2    = (ushort_t*)alloc(2 * TSTRIDE * 2);
    ushort_t* wT2   = (ushort_t*)alloc((size_t)64 * 64 * 9 * 2);
    ushort_t* wT5   = (ushort_t*)alloc((size_t)128 * 64 * 9 * 2);
    ushort_t* wT7   = (ushort_t*)alloc((size_t)128 * 128 * 9 * 2);
    ushort_t* wT10  = (ushort_t*)alloc((size_t)256 * 128 * 9 * 2);
    ushort_t* wT12  = (ushort_t*)alloc((size_t)256 * 256 * 9 * 2);
    ushort_t* wT14  = (ushort_t*)alloc((size_t)256 * 256 * 9 * 2);
    ushort_t* Abuf  = (ushort_t*)alloc((size_t)4096 * 320 * 2);
    char*     dist8 = (char*)alloc((size_t)4096 * 16384);
    float*    rpsum = (float*)alloc((size_t)128 * 4096 * 4);
    float*    cpsum = (float*)alloc((size_t)32 * 16384 * 4);
    float*    lc    = (float*)alloc(16384 * 4);
    float*    invr  = (float*)alloc(4096 * 4);
    float*    conf5 = (float*)alloc(5 * 4096 * 4);
    float*    h1    = (float*)alloc(8 * 4096 * 4);
    float*    out64 = (float*)alloc(4096 * 4);
    (void)ws_size; (void)n_in; (void)in_sizes; (void)out_size;

    // fused weight transforms
    WT6 wt;
    wt.src[0] = w2;  wt.dst[0] = wT2;  wt.co[0] = 64;  wt.ci[0] = 64;
    wt.src[1] = w5;  wt.dst[1] = wT5;  wt.co[1] = 128; wt.ci[1] = 64;
    wt.src[2] = w7;  wt.dst[2] = wT7;  wt.co[2] = 128; wt.ci[2] = 128;
    wt.src[3] = w10; wt.dst[3] = wT10; wt.co[3] = 256; wt.ci[3] = 128;
    wt.src[4] = w12; wt.dst[4] = wT12; wt.co[4] = 256; wt.ci[4] = 256;
    wt.src[5] = w14; wt.dst[5] = wT14; wt.co[5] = 256; wt.ci[5] = 256;
    int nblk = 0;
    for (int s = 0; s < 6; ++s) { wt.off[s] = nblk; nblk += (wt.co[s] * wt.ci[s] * 9 + 255) / 256; }
    wtrans6_k<<<nblk, 256, 0, stream>>>(wt);

    // batched feature extraction — ALL conv layers on 2-wave split-tap kernel
    conv0_k<<<dim3(4096, 2), 256, 0, stream>>>(x_ref, x_tem, w0, b0, F, t0);
    conv_mfma2w_k<64><<<dim3(512, 2, 2), 128, 0, stream>>>(t0, 64, TSTRIDE, wT2, b2, t1, 64, TSTRIDE, 128, 128, 64);
    maxpool_nhwc_k<<<dim3(128, 2), 256, 0, stream>>>(t1, t2, 64, 128, 128);
    conv_mfma2w_k<64><<<dim3(128, 4, 2), 128, 0, stream>>>(t2, 64, TSTRIDE, wT5, b5, t1, 128, TSTRIDE, 64, 64, 128);
    conv_mfma2w_k<128><<<dim3(128, 4, 2), 128, 0, stream>>>(t1, 128, TSTRIDE, wT7, b7, t2, 128, TSTRIDE, 64, 64, 128);
    maxpool_nhwc_k<<<dim3(64, 2), 256, 0, stream>>>(t2, t1, 128, 64, 64);
    conv_mfma2w_k<128><<<dim3(32, 8, 2), 128, 0, stream>>>(t1, 128, TSTRIDE, wT10, b10, t2, 256, TSTRIDE, 32, 32, 256);
    conv_mfma2w_k<256><<<dim3(32, 8, 2), 128, 0, stream>>>(t2, 256, TSTRIDE, wT12, b12, t1, 256, TSTRIDE, 32, 32, 256);
    conv_mfma2w_k<256><<<dim3(32, 8, 2), 128, 0, stream>>>(t1, 256, TSTRIDE, wT14, b14, t2, 256, TSTRIDE, 32, 32, 256);
    upnorm_k<<<dim3(4096, 2), 256, 0, stream>>>(t2, F, Abuf);

    gemm_corr_k<<<dim3(128, 32), 256, 0, stream>>>(Abuf, F + FSTRIDE, dist8, coefr, coeft, rpsum, cpsum);

    finboth_k<<<80, 256, 0, stream>>>(cpsum, rpsum, lc, invr);

    row_topk_k<<<2048, 256, 0, stream>>>(dist8, lc, invr, coefr, coeft, conf5);

    conv3x3_k<<<dim3(16, 1), 256, 0, stream>>>(conf5, fw1, fb1, h1, 5, 64, 64, 1);
    head2_k<<<16, 256, 0, stream>>>(h1, fw2, fb2, fw3, fb3, out64);
    bicubic_k<<<64, 256, 0, stream>>>(out64, out, 1, 64, 64, 128, 128);
}